// Round 4
// baseline (5870.848 us; speedup 1.0000x reference)
//
#include <hip/hip_runtime.h>

#define N_NODES 100000
#define NPAD    100032      // multiple of 64 for unguarded GEMM tiles
#define NBLK    1563        // NPAD/64
#define NEDGE   800000
#define NGRP    128
#define EPS     1e-5f

typedef unsigned int   u32;
typedef unsigned short u16;
typedef short bf16x8 __attribute__((ext_vector_type(8)));
typedef float f32x4  __attribute__((ext_vector_type(4)));

__device__ __forceinline__ float bf2f(u32 u){ return __uint_as_float(u << 16); }
__device__ __forceinline__ u16 f2bf(float f){
  u32 x = __float_as_uint(f);
  x += 0x7fffu + ((x >> 16) & 1u);      // round-to-nearest-even
  return (u16)(x >> 16);
}

// ---------------- x (f32) -> bf16 staging buffer ----------------
__global__ void k_cvt(const float* __restrict__ x, u32* __restrict__ dst){
  int i = blockIdx.x * 256 + threadIdx.x;        // grid covers N_NODES*64 pairs exactly
  float2 v = ((const float2*)x)[i];
  dst[i] = (u32)f2bf(v.x) | ((u32)f2bf(v.y) << 16);
}

// ---------------- preprocessing ----------------
__global__ void k_init(float* deg, int* cnt, int* fill, float* gbuf){
  int i = blockIdx.x * 256 + threadIdx.x;
  if (i < NPAD){ deg[i] = 1.0f; cnt[i] = 0; fill[i] = 0; }   // deg starts at 1 (self-loop)
  if (i < 4 * NGRP * 128) gbuf[i] = 0.f;
}

__global__ void k_deg(const int* __restrict__ col, const float* __restrict__ ew,
                      float* __restrict__ deg, int* __restrict__ cnt){
  int e = blockIdx.x * 256 + threadIdx.x;
  if (e < NEDGE){
    int c = col[e];
    atomicAdd(&deg[c], ew[e]);
    atomicAdd(&cnt[c], 1);
  }
}

__global__ void k_dinv(const float* __restrict__ deg, float* __restrict__ dinv, float* __restrict__ srow){
  int i = blockIdx.x * 256 + threadIdx.x;
  if (i < N_NODES){
    float d = deg[i];
    float v = d > 0.f ? rsqrtf(fmaxf(d, EPS)) : 0.f;
    dinv[i] = v; srow[i] = v * v;       // srow starts with self-loop norm
  }
}

__global__ void k_srow(const int* __restrict__ row, const int* __restrict__ col,
                       const float* __restrict__ ew, const float* __restrict__ dinv,
                       float* __restrict__ srow){
  int e = blockIdx.x * 256 + threadIdx.x;
  if (e < NEDGE){
    int r = row[e], c = col[e];
    atomicAdd(&srow[c], dinv[r] * ew[e] * dinv[c]);
  }
}

__global__ __launch_bounds__(256) void k_chunksum(const int* __restrict__ cnt, int* __restrict__ csum){
  int b = blockIdx.x, t = threadIdx.x;
  int s = 0;
  for (int i = t; i < 1024; i += 256){ int idx = b * 1024 + i; if (idx < N_NODES) s += cnt[idx]; }
  __shared__ int red[256];
  red[t] = s; __syncthreads();
  for (int o = 128; o > 0; o >>= 1){ if (t < o) red[t] += red[t + o]; __syncthreads(); }
  if (t == 0) csum[b] = red[0];
}

__global__ __launch_bounds__(128) void k_chunkscan(const int* __restrict__ csum, int* __restrict__ coff,
                                                   int* __restrict__ ptrA){
  int t = threadIdx.x;
  __shared__ int s[128];
  int v = (t < 98) ? csum[t] : 0;
  s[t] = v; __syncthreads();
  for (int o = 1; o < 128; o <<= 1){
    int x = (t >= o) ? s[t - o] : 0;
    __syncthreads(); s[t] += x; __syncthreads();
  }
  if (t < 98) coff[t] = s[t] - v;       // exclusive chunk offsets
  if (t == 0) ptrA[N_NODES] = NEDGE;
}

__global__ __launch_bounds__(256) void k_scan2(const int* __restrict__ cnt, const int* __restrict__ coff,
                                               int* __restrict__ ptrA){
  int b = blockIdx.x, t = threadIdx.x;
  int base = b * 1024 + t * 4;
  int v[4], tot = 0;
  #pragma unroll
  for (int k = 0; k < 4; k++){ int idx = base + k; v[k] = (idx < N_NODES) ? cnt[idx] : 0; tot += v[k]; }
  __shared__ int sc[256];
  sc[t] = tot; __syncthreads();
  for (int o = 1; o < 256; o <<= 1){
    int x = (t >= o) ? sc[t - o] : 0;
    __syncthreads(); sc[t] += x; __syncthreads();
  }
  int off = coff[b] + sc[t] - tot;
  #pragma unroll
  for (int k = 0; k < 4; k++){ int idx = base + k; if (idx < N_NODES) ptrA[idx] = off; off += v[k]; }
}

__global__ void k_fill(const int* __restrict__ row, const int* __restrict__ col,
                       const float* __restrict__ ew, const float* __restrict__ dinv,
                       const int* __restrict__ ptrA, int* __restrict__ fill, int2* __restrict__ adj){
  int e = blockIdx.x * 256 + threadIdx.x;
  if (e < NEDGE){
    int r = row[e], c = col[e];
    float w = dinv[r] * ew[e] * dinv[c];
    int pos = ptrA[c] + atomicAdd(&fill[c], 1);
    adj[pos] = make_int2(r, __float_as_int(w));
  }
}

// per-block LDS histogram -> partials (no global atomics)
__global__ __launch_bounds__(256) void k_bhist(const int* __restrict__ batch, int* __restrict__ bpart){
  __shared__ int loc[128];
  int t = threadIdx.x;
  if (t < 128) loc[t] = 0;
  __syncthreads();
  int i = blockIdx.x * 256 + t;
  if (i < N_NODES) atomicAdd(&loc[batch[i]], 1);
  __syncthreads();
  if (t < 128) bpart[blockIdx.x * 128 + t] = loc[t];
}

__global__ __launch_bounds__(128) void k_bscan(const int* __restrict__ bpart, int* __restrict__ gptr){
  int t = threadIdx.x;
  int v = 0;
  for (int p = 0; p < 391; p++) v += bpart[p * 128 + t];
  __shared__ int s[128];
  s[t] = v; __syncthreads();
  for (int o = 1; o < 128; o <<= 1){
    int x = (t >= o) ? s[t - o] : 0;
    __syncthreads(); s[t] += x; __syncthreads();
  }
  gptr[t + 1] = s[t];
  if (t == 0) gptr[0] = 0;
}

// ---------------- column stats of f32 x -> partials [196][256] ----------------
__global__ __launch_bounds__(256) void k_statsx(const float* __restrict__ x, float* __restrict__ part){
  int t = threadIdx.x, col = t & 127, half = t >> 7;
  int r0 = blockIdx.x * 512;
  int rend = min(r0 + 512, N_NODES);
  float s = 0.f, q = 0.f;
  for (int r = r0 + half; r < rend; r += 2){
    float v = x[(size_t)r * 128 + col];
    s += v; q += v * v;
  }
  __shared__ float ls[256], lq[256];
  ls[t] = s; lq[t] = q;
  __syncthreads();
  if (half == 0){
    part[blockIdx.x * 256 + col]       = s + ls[t + 128];
    part[blockIdx.x * 256 + 128 + col] = q + lq[t + 128];
  }
}

// reduce per-block partials [n][256] -> sums[256]
__global__ __launch_bounds__(256) void k_red(const float* __restrict__ part, int n, float* __restrict__ sums){
  int t = threadIdx.x;
  float s = 0.f;
  for (int p = 0; p < n; p++) s += part[p * 256 + t];
  sums[t] = s;
}

// ---------------- fold BN into GEMM weights (hi/lo split), f32 params ----------------
__global__ __launch_bounds__(256) void k_fold(const float* __restrict__ part, int nparts,
    const float* __restrict__ bw, const float* __restrict__ bb,
    const float* __restrict__ W, const float* __restrict__ bias,
    u16* __restrict__ Wh, u16* __restrict__ Wl, float* __restrict__ rb){
  __shared__ float scl[128], shf[128], red[256], redp[256];
  int t = threadIdx.x;
  float s = 0.f;
  for (int p = 0; p < nparts; p++) s += part[p * 256 + t];
  red[t] = s;
  __syncthreads();
  if (t < 128){
    float mu  = red[t] * (1.f / N_NODES);
    float var = red[128 + t] * (1.f / N_NODES) - mu * mu;
    float sc  = bw[t] * rsqrtf(var + EPS);
    scl[t] = sc; shf[t] = bb[t] - mu * sc;
  }
  __syncthreads();
  int j = t & 127, hf = (t >> 7) * 64;
  float acc = 0.f;
  for (int f0 = 0; f0 < 64; f0++){
    int f = hf + f0;
    float wv = W[f * 128 + j];
    acc += shf[f] * wv;
    float x = scl[f] * wv;
    u16 hh = f2bf(x);
    Wh[j * 128 + f] = hh;
    Wl[j * 128 + f] = f2bf(x - bf2f(hh));
  }
  redp[t] = acc;
  __syncthreads();
  if (t < 128){
    rb[t] = redp[t] + redp[t + 128];
    rb[128 + t] = bias[t];
  }
}

// ---------------- SpMM: z = S @ h (bf16 gather, f32 out, 4-way unrolled) ----------------
__global__ __launch_bounds__(256) void k_spmm(const u16* __restrict__ h,
    const int* __restrict__ ptrA, const int2* __restrict__ adj,
    const float* __restrict__ dinv, float* __restrict__ z){
  int lane = threadIdx.x & 63;
  int i = blockIdx.x * 4 + (threadIdx.x >> 6);
  if (i >= N_NODES) return;
  float di = dinv[i], sw = di * di;
  u32 hv = *(const u32*)(h + (size_t)i * 128 + lane * 2);
  float a0 = sw * bf2f(hv & 0xffffu), a1 = sw * bf2f(hv >> 16);
  float b0 = 0.f, b1 = 0.f, c0 = 0.f, c1 = 0.f, d0 = 0.f, d1 = 0.f;
  int b = ptrA[i], e = ptrA[i + 1];
  int k = b;
  for (; k + 4 <= e; k += 4){
    int2 w0 = adj[k], w1 = adj[k + 1], w2 = adj[k + 2], w3 = adj[k + 3];
    u32 v0 = *(const u32*)(h + (size_t)w0.x * 128 + lane * 2);
    u32 v1 = *(const u32*)(h + (size_t)w1.x * 128 + lane * 2);
    u32 v2 = *(const u32*)(h + (size_t)w2.x * 128 + lane * 2);
    u32 v3 = *(const u32*)(h + (size_t)w3.x * 128 + lane * 2);
    float f0 = __int_as_float(w0.y), f1 = __int_as_float(w1.y);
    float f2 = __int_as_float(w2.y), f3 = __int_as_float(w3.y);
    a0 += f0 * bf2f(v0 & 0xffffu); a1 += f0 * bf2f(v0 >> 16);
    b0 += f1 * bf2f(v1 & 0xffffu); b1 += f1 * bf2f(v1 >> 16);
    c0 += f2 * bf2f(v2 & 0xffffu); c1 += f2 * bf2f(v2 >> 16);
    d0 += f3 * bf2f(v3 & 0xffffu); d1 += f3 * bf2f(v3 >> 16);
  }
  for (; k < e; k++){
    int2 aw = adj[k];
    float w = __int_as_float(aw.y);
    u32 v = *(const u32*)(h + (size_t)aw.x * 128 + lane * 2);
    a0 += w * bf2f(v & 0xffffu); a1 += w * bf2f(v >> 16);
  }
  a0 = (a0 + b0) + (c0 + d0);
  a1 = (a1 + b1) + (c1 + d1);
  *(float2*)(z + (size_t)i * 128 + lane * 2) = make_float2(a0, a1);
}

// ---------------- GEMM: hout = relu(z @ W' + srow*r + bias), hi/lo bf16 MFMA; fused stats ----------------
__global__ __launch_bounds__(256) void k_gemm(const float* __restrict__ z,
    const u16* __restrict__ Wh_g, const u16* __restrict__ Wl_g,
    const float* __restrict__ srow, const float* __restrict__ rb,
    u16* __restrict__ hout, float* __restrict__ spart){
  __shared__ alignas(16) u16 WL[32768];   // [0:16384) hi frags, [16384:32768) lo frags; 64 KB
  int t = threadIdx.x;
  for (int idx = t; idx < 2048; idx += 256){
    int lane_ = idx & 63, slot = idx >> 6;        // slot = nt*4 + ks
    int nt = slot >> 2, ks = slot & 3;
    int n_ = nt * 16 + (lane_ & 15);
    int kb = ks * 32 + (lane_ >> 4) * 8;
    *(uint4*)&WL[idx * 8]         = *(const uint4*)(Wh_g + n_ * 128 + kb);
    *(uint4*)&WL[16384 + idx * 8] = *(const uint4*)(Wl_g + n_ * 128 + kb);
  }
  __syncthreads();
  int wave = t >> 6, lane = t & 63, m = lane & 15, q = lane >> 4;
  int row0 = blockIdx.x * 64 + wave * 16;
  const float* zr = z + (size_t)(row0 + m) * 128;
  f32x4 acc[8];
  #pragma unroll
  for (int i = 0; i < 8; i++) acc[i] = f32x4{0.f, 0.f, 0.f, 0.f};
  #pragma unroll
  for (int ks = 0; ks < 4; ks++){
    float4 z0 = *(const float4*)(zr + ks * 32 + q * 8);
    float4 z1 = *(const float4*)(zr + ks * 32 + q * 8 + 4);
    float zz[8] = {z0.x, z0.y, z0.z, z0.w, z1.x, z1.y, z1.z, z1.w};
    bf16x8 ah, al;
    #pragma unroll
    for (int j = 0; j < 8; j++){
      u16 hh = f2bf(zz[j]);
      ah[j] = (short)hh;
      al[j] = (short)f2bf(zz[j] - bf2f(hh));
    }
    #pragma unroll
    for (int nt = 0; nt < 8; nt++){
      bf16x8 bh = *(const bf16x8*)&WL[((nt * 4 + ks) * 64 + lane) * 8];
      bf16x8 bl = *(const bf16x8*)&WL[16384 + ((nt * 4 + ks) * 64 + lane) * 8];
      acc[nt] = __builtin_amdgcn_mfma_f32_16x16x32_bf16(ah, bh, acc[nt], 0, 0, 0);
      acc[nt] = __builtin_amdgcn_mfma_f32_16x16x32_bf16(al, bh, acc[nt], 0, 0, 0);
      acc[nt] = __builtin_amdgcn_mfma_f32_16x16x32_bf16(ah, bl, acc[nt], 0, 0, 0);
    }
  }
  __syncthreads();                 // done with W frags; reuse LDS for stats
  float* sred = (float*)WL;        // 256 floats: [0:128) col sums, [128:256) col sumsq
  if (t < 256) sred[t] = 0.f;
  __syncthreads();
  #pragma unroll
  for (int nt = 0; nt < 8; nt++){
    int colc = nt * 16 + m;
    float rv = rb[colc], bv = rb[128 + colc];
    float s = 0.f, qq = 0.f;
    #pragma unroll
    for (int r = 0; r < 4; r++){
      int rown = row0 + q * 4 + r;                // C/D: col=lane&15, row=quad*4+reg
      float v = acc[nt][r] + srow[rown] * rv + bv;
      v = fmaxf(v, 0.f);
      u16 sv = f2bf(v);
      hout[(size_t)rown * 128 + colc] = sv;
      if (rown < N_NODES){ float vv = bf2f(sv); s += vv; qq += vv * vv; }
    }
    atomicAdd(&sred[colc], s);
    atomicAdd(&sred[128 + colc], qq);
  }
  __syncthreads();
  if (t < 256) spart[(size_t)blockIdx.x * 256 + t] = sred[t];
}

// ---------------- branch-4 elementwise: out = relu(bn(h)); fused stats partials ----------------
__global__ __launch_bounds__(256) void k_normrelu(const u16* __restrict__ h, const float* __restrict__ sums,
    const float* __restrict__ bw, const float* __restrict__ bb, u16* __restrict__ o,
    float* __restrict__ npart){
  __shared__ float scl[128], shf[128], R[1024];
  int t = threadIdx.x;
  if (t < 128){
    float mu  = sums[t] * (1.f / N_NODES);
    float var = sums[128 + t] * (1.f / N_NODES) - mu * mu;
    float sc  = bw[t] * rsqrtf(var + EPS);
    scl[t] = sc; shf[t] = bb[t] - mu * sc;
  }
  __syncthreads();
  int c0 = (t & 63) * 2;
  float sc0 = scl[c0], sh0 = shf[c0], sc1 = scl[c0 + 1], sh1 = shf[c0 + 1];
  float s0 = 0.f, q0 = 0.f, s1 = 0.f, q1 = 0.f;
  size_t base = (size_t)blockIdx.x * 4096 + t;
  #pragma unroll
  for (int it = 0; it < 16; it++){
    size_t idx = base + (size_t)it * 256;
    if (idx < (size_t)N_NODES * 64){
      u32 v = ((const u32*)h)[idx];
      float x0 = fmaxf(bf2f(v & 0xffffu) * sc0 + sh0, 0.f);
      float x1 = fmaxf(bf2f(v >> 16) * sc1 + sh1, 0.f);
      u16 r0 = f2bf(x0), r1 = f2bf(x1);
      ((u32*)o)[idx] = (u32)r0 | ((u32)r1 << 16);
      float y0 = bf2f(r0), y1 = bf2f(r1);
      s0 += y0; q0 += y0 * y0; s1 += y1; q1 += y1 * y1;
    }
  }
  R[t] = s0; R[256 + t] = q0; R[512 + t] = s1; R[768 + t] = q1;
  __syncthreads();
  if (t < 64){
    float S0 = 0.f, Q0 = 0.f, S1 = 0.f, Q1 = 0.f;
    #pragma unroll
    for (int g = 0; g < 4; g++){
      S0 += R[g * 64 + t];       Q0 += R[256 + g * 64 + t];
      S1 += R[512 + g * 64 + t]; Q1 += R[768 + g * 64 + t];
    }
    float* np = npart + (size_t)blockIdx.x * 256;
    np[2 * t] = S0; np[2 * t + 1] = S1;
    np[128 + 2 * t] = Q0; np[128 + 2 * t + 1] = Q1;
  }
}

// ---------------- global_add_pool ----------------
__global__ __launch_bounds__(128) void k_pool(const u16* __restrict__ h, const int* __restrict__ gptr,
                                              float* __restrict__ gdst){
  int g = blockIdx.x >> 3, s = blockIdx.x & 7, t = threadIdx.x;
  int b = gptr[g], e = gptr[g + 1];
  int len = e - b, per = (len + 7) >> 3;
  int r0 = b + s * per, r1 = min(r0 + per, e);
  float acc = 0.f;
  for (int r = r0; r < r1; r++) acc += bf2f(h[(size_t)r * 128 + t]);
  atomicAdd(&gdst[g * 128 + t], acc);
}

// ---------------- head: all-f32, LDS-staged, static acc indexing, f32 output ----------------
__global__ __launch_bounds__(256) void k_head(const float* __restrict__ gbuf,
    const float* __restrict__ fcw, const float* __restrict__ fcb,
    const float* __restrict__ Wfc, const float* __restrict__ bfc,
    const float* __restrict__ bhw, const float* __restrict__ bhb,
    const float* __restrict__ Wcl, const float* __restrict__ bcl,
    float* __restrict__ out){
  __shared__ float Gs[128 * 66];          // stride 66: float2-aligned
  __shared__ float scl[128], shf[128], reds[256], redq[256];
  __shared__ float scl2[128], shf2[128];
  int t = threadIdx.x, br = blockIdx.x;
  int slot = (br == 1) ? 1 : (br == 3 ? 3 : 0);   // branch3 == branch1 (slot 0)
  const float* G = gbuf + slot * 16384;
  if (t < 128){
    float s = 0.f, q = 0.f;
    for (int g = 0; g < 128; g++){ float v = G[g * 128 + t]; s += v; q += v * v; }
    float mu = s * (1.f / 128), var = q * (1.f / 128) - mu * mu;
    float sc = fcw[t] * rsqrtf(var + EPS);
    scl[t] = sc; shf[t] = fcb[t] - mu * sc;
  }
  __syncthreads();
  int jo = t & 127, ih = (t >> 7) * 64;
  float acc[64];
  #pragma unroll
  for (int k = 0; k < 64; k++) acc[k] = 0.f;
  for (int half = 0; half < 2; half++){
    for (int idx = t; idx < 8192; idx += 256){
      int r = idx >> 6, fj = idx & 63, f = half * 64 + fj;
      Gs[r * 66 + fj] = G[r * 128 + f] * scl[f] + shf[f];
    }
    __syncthreads();
    for (int fj2 = 0; fj2 < 32; fj2++){
      int f = half * 64 + fj2 * 2;
      float w0 = Wfc[f * 128 + jo];
      float w1 = Wfc[(f + 1) * 128 + jo];
      #pragma unroll
      for (int k = 0; k < 64; k++){
        float2 g2 = *(const float2*)&Gs[(ih + k) * 66 + fj2 * 2];
        acc[k] += g2.x * w0 + g2.y * w1;
      }
    }
    __syncthreads();
  }
  {
    float bb = bfc[jo];
    float s = 0.f, q = 0.f;
    #pragma unroll
    for (int k = 0; k < 64; k++){ acc[k] = fmaxf(acc[k] + bb, 0.f); s += acc[k]; q += acc[k] * acc[k]; }
    reds[t] = s; redq[t] = q;
  }
  __syncthreads();
  if (t < 128){
    float s = reds[t] + reds[t + 128], q = redq[t] + redq[t + 128];
    float mu = s * (1.f / 128), var = q * (1.f / 128) - mu * mu;
    float sc = bhw[t] * rsqrtf(var + EPS);
    scl2[t] = sc; shf2[t] = bhb[t] - mu * sc;
  }
  __syncthreads();
  float l[10];
  #pragma unroll
  for (int c = 0; c < 10; c++) l[c] = bcl[c];
  float sc2 = scl2[jo], sh2 = shf2[jo];
  for (int p = 0; p < 2; p++){
    if ((jo >> 6) == p){
      int cj = jo & 63;
      #pragma unroll
      for (int k = 0; k < 64; k++) Gs[(ih + k) * 66 + cj] = acc[k] * sc2 + sh2;
    }
    __syncthreads();
    if (t < 128){
      for (int f02 = 0; f02 < 32; f02++){
        float2 g2 = *(const float2*)&Gs[t * 66 + f02 * 2];
        int f = p * 64 + f02 * 2;
        #pragma unroll
        for (int c = 0; c < 10; c++)
          l[c] += g2.x * Wcl[f * 10 + c] + g2.y * Wcl[(f + 1) * 10 + c];
      }
    }
    __syncthreads();
  }
  if (t < 128){
    float m = l[0];
    #pragma unroll
    for (int c = 1; c < 10; c++) m = fmaxf(m, l[c]);
    float se = 0.f;
    #pragma unroll
    for (int c = 0; c < 10; c++) se += expf(l[c] - m);
    float lse = m + logf(se);
    #pragma unroll
    for (int c = 0; c < 10; c++) out[br * 1280 + t * 10 + c] = l[c] - lse;
  }
}

extern "C" void kernel_launch(void* const* d_in, const int* in_sizes, int n_in,
                              void* d_out, int out_size, void* d_ws, size_t ws_size,
                              hipStream_t stream){
  const float* x    = (const float*)d_in[0];
  const int*  ei    = (const int*)d_in[1];      // [2,E]: rows then cols
  const int*  batch = (const int*)d_in[2];
  const float* ew   = (const float*)d_in[3];
  const float* bnfw = (const float*)d_in[4];
  const float* bnfb = (const float*)d_in[5];
  const float* cfW  = (const float*)d_in[6];
  const float* cfb  = (const float*)d_in[7];
  const float* bnsw = (const float*)d_in[8];
  const float* bnsb = (const float*)d_in[9];
  const float* cvW  = (const float*)d_in[10];
  const float* cvb  = (const float*)d_in[11];
  const float* fcw  = (const float*)d_in[12];
  const float* fcb  = (const float*)d_in[13];
  const float* Wfc  = (const float*)d_in[14];
  const float* bfc  = (const float*)d_in[15];
  const float* bhw  = (const float*)d_in[16];
  const float* bhb  = (const float*)d_in[17];
  const float* Wcl  = (const float*)d_in[18];
  const float* bcl  = (const float*)d_in[19];
  float* out = (float*)d_out;

  char* p = (char*)d_ws;
  auto carve = [&](size_t bytes)->void*{ void* r = (void*)p; p += (bytes + 255) & ~(size_t)255; return r; };
  float* deg  = (float*)carve((size_t)NPAD * 4);
  float* dinv = (float*)carve((size_t)NPAD * 4);
  float* srow = (float*)carve((size_t)NPAD * 4);
  int*   ptrA = (int*)carve((size_t)(NPAD + 1) * 4);
  int*   csum = (int*)carve(512);
  int*   coff = (int*)carve(512);
  int*   gptr = (int*)carve(1024);
  float* sums = (float*)carve(1024);
  float* rb   = (float*)carve(1024);
  u16*   Wh   = (u16*)carve(128 * 128 * 2);
  u16*   Wl   = (u16*)carve(128 * 128 * 2);
  float* gbuf = (float*)carve(4 * 128 * 128 * 4);
  float* spA  = (float*)carve((size_t)NBLK * 256 * 4);
  float* spB  = (float*)carve((size_t)NBLK * 256 * 4);
  float* z    = (float*)carve((size_t)NPAD * 128 * 4);
  u16*   B0   = (u16*)carve((size_t)NPAD * 256);
  u16*   B1   = (u16*)carve((size_t)NPAD * 256);
  u16*   B2   = (u16*)carve((size_t)NPAD * 256);
  u16*   B3   = (u16*)carve((size_t)NPAD * 256);
  int2*  adj  = (int2*)carve((size_t)NEDGE * 8);
  // aliases (lifetimes verified against the schedule below)
  int* cnt   = (int*)spA;            // cnt used only during CSR build (before spA's first real use)
  int* fill  = (int*)spB;            // fill used only during k_fill (before spB's first real use)
  int* bpart = (int*)spB + NPAD;     // bhist partials, also pre-spB
  u16* Xb    = B3;                   // bf16 x staging; B3's first real write (d2) is after layer-0 spmm

  // preprocessing: degrees, norms, CSR, group offsets
  k_init<<<392, 256, 0, stream>>>(deg, cnt, fill, gbuf);
  k_deg<<<3125, 256, 0, stream>>>(ei + NEDGE, ew, deg, cnt);
  k_dinv<<<391, 256, 0, stream>>>(deg, dinv, srow);
  k_srow<<<3125, 256, 0, stream>>>(ei, ei + NEDGE, ew, dinv, srow);
  k_chunksum<<<98, 256, 0, stream>>>(cnt, csum);
  k_chunkscan<<<1, 128, 0, stream>>>(csum, coff, ptrA);
  k_scan2<<<98, 256, 0, stream>>>(cnt, coff, ptrA);
  k_fill<<<3125, 256, 0, stream>>>(ei, ei + NEDGE, ew, dinv, ptrA, fill, adj);
  k_bhist<<<391, 256, 0, stream>>>(batch, bpart);
  k_bscan<<<1, 128, 0, stream>>>(bpart, gptr);
  k_cvt<<<25000, 256, 0, stream>>>(x, (u32*)Xb);
  k_statsx<<<196, 256, 0, stream>>>(x, spA);     // after k_scan2 (cnt alias released)

  auto spmm = [&](const u16* hin){ k_spmm<<<25000, 256, 0, stream>>>(hin, ptrA, adj, dinv, z); };
  auto conv = [&](const float* part, int nparts, const float* bw, const float* bb,
                  const float* W, const float* bias, u16* hout, float* spart_out){
    k_fold<<<1, 256, 0, stream>>>(part, nparts, bw, bb, W, bias, Wh, Wl, rb);
    k_gemm<<<NBLK, 256, 0, stream>>>(z, Wh, Wl, srow, rb, hout, spart_out);
  };

  // layer 0: h_init = relu(conv(bn_feat(x)))
  spmm(Xb);
  conv(spA, 196, bnfw, bnfb, cfW, cfb, B0, spA);           // B0 = h_init; spA = stats(h_init)
  // a1 = step(h_init, bn0/W0)  (== branch2 c1)
  spmm(B0);
  conv(spA, NBLK, bnsw, bnsb, cvW, cvb, B1, spB);          // B1 = a1; spB = stats(a1)
  // branch 4: d1,d2,d3 (d1 uses stats(h_init))
  k_red<<<1, 256, 0, stream>>>(spA, NBLK, sums);
  k_normrelu<<<NBLK, 256, 0, stream>>>(B0, sums, bnsw, bnsb, B2, spA);             // d1 -> B2
  k_red<<<1, 256, 0, stream>>>(spA, NBLK, sums);
  k_normrelu<<<NBLK, 256, 0, stream>>>(B2, sums, bnsw + 128, bnsb + 128, B3, spA); // d2 -> B3
  k_red<<<1, 256, 0, stream>>>(spA, NBLK, sums);
  k_normrelu<<<NBLK, 256, 0, stream>>>(B3, sums, bnsw + 256, bnsb + 256, B2, spA); // d3 -> B2
  k_pool<<<1024, 128, 0, stream>>>(B2, gptr, gbuf + 3 * 16384);
  // z = S@a1 serves a2 AND c2
  spmm(B1);
  conv(spB, NBLK, bnsw + 128, bnsb + 128, cvW + 16384, cvb + 128, B3, spA);  // a2 -> B3; spA = stats(a2)
  conv(spB, NBLK, bnsw, bnsb, cvW, cvb, B2, spB);                            // c2 -> B2; spB = stats(c2)
  // a3 = step(a2, bn2/W2) -> branches 1 & 3
  spmm(B3);
  conv(spA, NBLK, bnsw + 256, bnsb + 256, cvW + 32768, cvb + 256, B0, spA);  // a3 -> B0
  k_pool<<<1024, 128, 0, stream>>>(B0, gptr, gbuf);
  // c3 = step(c2, bn1/W1)
  spmm(B2);
  conv(spB, NBLK, bnsw + 128, bnsb + 128, cvW + 16384, cvb + 128, B1, spB);  // c3 -> B1
  // c4 = step(c3, bn1/W1)
  spmm(B1);
  conv(spB, NBLK, bnsw + 128, bnsb + 128, cvW + 16384, cvb + 128, B2, spB);  // c4 -> B2
  // c5 = step(c4, bn2/W2)
  spmm(B2);
  conv(spB, NBLK, bnsw + 256, bnsb + 256, cvW + 32768, cvb + 256, B1, spB);  // c5 -> B1
  // c6 = step(c5, bn2/W2) -> branch 2
  spmm(B1);
  conv(spB, NBLK, bnsw + 256, bnsb + 256, cvW + 32768, cvb + 256, B3, spB);  // c6 -> B3
  k_pool<<<1024, 128, 0, stream>>>(B3, gptr, gbuf + 16384);

  k_head<<<4, 256, 0, stream>>>(gbuf, fcw, fcb, Wfc, bfc, bhw, bhb, Wcl, bcl, out);
}

// Round 5
// 2084.854 us; speedup vs baseline: 2.8160x; 2.8160x over previous
//
#include <hip/hip_runtime.h>

#define N_NODES 100000
#define NPAD    100032      // multiple of 64 for unguarded GEMM tiles
#define NBLK    1563        // NPAD/64
#define NEDGE   800000
#define NGRP    128
#define EPS     1e-5f

typedef unsigned int   u32;
typedef unsigned short u16;
typedef short bf16x8 __attribute__((ext_vector_type(8)));
typedef float f32x4  __attribute__((ext_vector_type(4)));

__device__ __forceinline__ float bf2f(u32 u){ return __uint_as_float(u << 16); }
__device__ __forceinline__ u16 f2bf(float f){
  u32 x = __float_as_uint(f);
  x += 0x7fffu + ((x >> 16) & 1u);      // round-to-nearest-even
  return (u16)(x >> 16);
}

// ---------------- x (f32) -> bf16 staging buffer ----------------
__global__ void k_cvt(const float* __restrict__ x, u32* __restrict__ dst){
  int i = blockIdx.x * 256 + threadIdx.x;        // grid covers N_NODES*64 pairs exactly
  float2 v = ((const float2*)x)[i];
  dst[i] = (u32)f2bf(v.x) | ((u32)f2bf(v.y) << 16);
}

// ---------------- preprocessing ----------------
__global__ void k_init(float* deg, int* cnt, int* fill, float* gbuf){
  int i = blockIdx.x * 256 + threadIdx.x;
  if (i < NPAD){ deg[i] = 1.0f; cnt[i] = 0; fill[i] = 0; }   // deg starts at 1 (self-loop)
  if (i < 4 * NGRP * 128) gbuf[i] = 0.f;
}

__global__ void k_deg(const int* __restrict__ col, const float* __restrict__ ew,
                      float* __restrict__ deg, int* __restrict__ cnt){
  int e = blockIdx.x * 256 + threadIdx.x;
  if (e < NEDGE){
    int c = col[e];
    atomicAdd(&deg[c], ew[e]);
    atomicAdd(&cnt[c], 1);
  }
}

__global__ void k_dinv(const float* __restrict__ deg, float* __restrict__ dinv, float* __restrict__ srow){
  int i = blockIdx.x * 256 + threadIdx.x;
  if (i < N_NODES){
    float d = deg[i];
    float v = d > 0.f ? rsqrtf(fmaxf(d, EPS)) : 0.f;
    dinv[i] = v; srow[i] = v * v;       // srow starts with self-loop norm
  }
}

__global__ void k_srow(const int* __restrict__ row, const int* __restrict__ col,
                       const float* __restrict__ ew, const float* __restrict__ dinv,
                       float* __restrict__ srow){
  int e = blockIdx.x * 256 + threadIdx.x;
  if (e < NEDGE){
    int r = row[e], c = col[e];
    atomicAdd(&srow[c], dinv[r] * ew[e] * dinv[c]);
  }
}

__global__ __launch_bounds__(256) void k_chunksum(const int* __restrict__ cnt, int* __restrict__ csum){
  int b = blockIdx.x, t = threadIdx.x;
  int s = 0;
  for (int i = t; i < 1024; i += 256){ int idx = b * 1024 + i; if (idx < N_NODES) s += cnt[idx]; }
  __shared__ int red[256];
  red[t] = s; __syncthreads();
  for (int o = 128; o > 0; o >>= 1){ if (t < o) red[t] += red[t + o]; __syncthreads(); }
  if (t == 0) csum[b] = red[0];
}

__global__ __launch_bounds__(128) void k_chunkscan(const int* __restrict__ csum, int* __restrict__ coff,
                                                   int* __restrict__ ptrA){
  int t = threadIdx.x;
  __shared__ int s[128];
  int v = (t < 98) ? csum[t] : 0;
  s[t] = v; __syncthreads();
  for (int o = 1; o < 128; o <<= 1){
    int x = (t >= o) ? s[t - o] : 0;
    __syncthreads(); s[t] += x; __syncthreads();
  }
  if (t < 98) coff[t] = s[t] - v;       // exclusive chunk offsets
  if (t == 0) ptrA[N_NODES] = NEDGE;
}

__global__ __launch_bounds__(256) void k_scan2(const int* __restrict__ cnt, const int* __restrict__ coff,
                                               int* __restrict__ ptrA){
  int b = blockIdx.x, t = threadIdx.x;
  int base = b * 1024 + t * 4;
  int v[4], tot = 0;
  #pragma unroll
  for (int k = 0; k < 4; k++){ int idx = base + k; v[k] = (idx < N_NODES) ? cnt[idx] : 0; tot += v[k]; }
  __shared__ int sc[256];
  sc[t] = tot; __syncthreads();
  for (int o = 1; o < 256; o <<= 1){
    int x = (t >= o) ? sc[t - o] : 0;
    __syncthreads(); sc[t] += x; __syncthreads();
  }
  int off = coff[b] + sc[t] - tot;
  #pragma unroll
  for (int k = 0; k < 4; k++){ int idx = base + k; if (idx < N_NODES) ptrA[idx] = off; off += v[k]; }
}

__global__ void k_fill(const int* __restrict__ row, const int* __restrict__ col,
                       const float* __restrict__ ew, const float* __restrict__ dinv,
                       const int* __restrict__ ptrA, int* __restrict__ fill, int2* __restrict__ adj){
  int e = blockIdx.x * 256 + threadIdx.x;
  if (e < NEDGE){
    int r = row[e], c = col[e];
    float w = dinv[r] * ew[e] * dinv[c];
    int pos = ptrA[c] + atomicAdd(&fill[c], 1);
    adj[pos] = make_int2(r, __float_as_int(w));
  }
}

// per-block LDS histogram -> partials (no global atomics)
__global__ __launch_bounds__(256) void k_bhist(const int* __restrict__ batch, int* __restrict__ bpart){
  __shared__ int loc[128];
  int t = threadIdx.x;
  if (t < 128) loc[t] = 0;
  __syncthreads();
  int i = blockIdx.x * 256 + t;
  if (i < N_NODES) atomicAdd(&loc[batch[i]], 1);
  __syncthreads();
  if (t < 128) bpart[blockIdx.x * 128 + t] = loc[t];
}

__global__ __launch_bounds__(128) void k_bscan(const int* __restrict__ bpart, int* __restrict__ gptr){
  int t = threadIdx.x;
  int v = 0;
  for (int p = 0; p < 391; p++) v += bpart[p * 128 + t];
  __shared__ int s[128];
  s[t] = v; __syncthreads();
  for (int o = 1; o < 128; o <<= 1){
    int x = (t >= o) ? s[t - o] : 0;
    __syncthreads(); s[t] += x; __syncthreads();
  }
  gptr[t + 1] = s[t];
  if (t == 0) gptr[0] = 0;
}

// ---------------- column stats of f32 x -> atomic accumulate into sums[256] ----------------
__global__ __launch_bounds__(256) void k_statsx(const float* __restrict__ x, float* __restrict__ sums){
  int t = threadIdx.x, col = t & 127, half = t >> 7;
  int r0 = blockIdx.x * 512;
  int rend = min(r0 + 512, N_NODES);
  float s = 0.f, q = 0.f;
  for (int r = r0 + half; r < rend; r += 2){
    float v = x[(size_t)r * 128 + col];
    s += v; q += v * v;
  }
  __shared__ float ls[256], lq[256];
  ls[t] = s; lq[t] = q;
  __syncthreads();
  if (half == 0){
    atomicAdd(&sums[col],       s + ls[t + 128]);
    atomicAdd(&sums[128 + col], q + lq[t + 128]);
  }
}

// ---------------- fold BN into GEMM weights (hi/lo split); sums read directly ----------------
__global__ __launch_bounds__(256) void k_fold(const float* __restrict__ sums,
    const float* __restrict__ bw, const float* __restrict__ bb,
    const float* __restrict__ W, const float* __restrict__ bias,
    u16* __restrict__ Wh, u16* __restrict__ Wl, float* __restrict__ rb){
  __shared__ float scl[128], shf[128], redp[256];
  int t = threadIdx.x;
  if (t < 128){
    float mu  = sums[t] * (1.f / N_NODES);
    float var = sums[128 + t] * (1.f / N_NODES) - mu * mu;
    float sc  = bw[t] * rsqrtf(var + EPS);
    scl[t] = sc; shf[t] = bb[t] - mu * sc;
  }
  __syncthreads();
  int j = t & 127, hf = (t >> 7) * 64;
  float acc = 0.f;
  for (int f0 = 0; f0 < 64; f0++){
    int f = hf + f0;
    float wv = W[f * 128 + j];
    acc += shf[f] * wv;
    float x = scl[f] * wv;
    u16 hh = f2bf(x);
    Wh[j * 128 + f] = hh;
    Wl[j * 128 + f] = f2bf(x - bf2f(hh));
  }
  redp[t] = acc;
  __syncthreads();
  if (t < 128){
    rb[t] = redp[t] + redp[t + 128];
    rb[128 + t] = bias[t];
  }
}

// ---------------- SpMM: z = S @ h (bf16 gather, f32 out, 4-way unrolled) ----------------
__global__ __launch_bounds__(256) void k_spmm(const u16* __restrict__ h,
    const int* __restrict__ ptrA, const int2* __restrict__ adj,
    const float* __restrict__ dinv, float* __restrict__ z){
  int lane = threadIdx.x & 63;
  int i = blockIdx.x * 4 + (threadIdx.x >> 6);
  if (i >= N_NODES) return;
  float di = dinv[i], sw = di * di;
  u32 hv = *(const u32*)(h + (size_t)i * 128 + lane * 2);
  float a0 = sw * bf2f(hv & 0xffffu), a1 = sw * bf2f(hv >> 16);
  float b0 = 0.f, b1 = 0.f, c0 = 0.f, c1 = 0.f, d0 = 0.f, d1 = 0.f;
  int b = ptrA[i], e = ptrA[i + 1];
  int k = b;
  for (; k + 4 <= e; k += 4){
    int2 w0 = adj[k], w1 = adj[k + 1], w2 = adj[k + 2], w3 = adj[k + 3];
    u32 v0 = *(const u32*)(h + (size_t)w0.x * 128 + lane * 2);
    u32 v1 = *(const u32*)(h + (size_t)w1.x * 128 + lane * 2);
    u32 v2 = *(const u32*)(h + (size_t)w2.x * 128 + lane * 2);
    u32 v3 = *(const u32*)(h + (size_t)w3.x * 128 + lane * 2);
    float f0 = __int_as_float(w0.y), f1 = __int_as_float(w1.y);
    float f2 = __int_as_float(w2.y), f3 = __int_as_float(w3.y);
    a0 += f0 * bf2f(v0 & 0xffffu); a1 += f0 * bf2f(v0 >> 16);
    b0 += f1 * bf2f(v1 & 0xffffu); b1 += f1 * bf2f(v1 >> 16);
    c0 += f2 * bf2f(v2 & 0xffffu); c1 += f2 * bf2f(v2 >> 16);
    d0 += f3 * bf2f(v3 & 0xffffu); d1 += f3 * bf2f(v3 >> 16);
  }
  for (; k < e; k++){
    int2 aw = adj[k];
    float w = __int_as_float(aw.y);
    u32 v = *(const u32*)(h + (size_t)aw.x * 128 + lane * 2);
    a0 += w * bf2f(v & 0xffffu); a1 += w * bf2f(v >> 16);
  }
  a0 = (a0 + b0) + (c0 + d0);
  a1 = (a1 + b1) + (c1 + d1);
  *(float2*)(z + (size_t)i * 128 + lane * 2) = make_float2(a0, a1);
}

// ---------------- GEMM: hout = relu(z @ W' + srow*r + bias), hi/lo bf16 MFMA; stats -> atomic ----------------
__global__ __launch_bounds__(256) void k_gemm(const float* __restrict__ z,
    const u16* __restrict__ Wh_g, const u16* __restrict__ Wl_g,
    const float* __restrict__ srow, const float* __restrict__ rb,
    u16* __restrict__ hout, float* __restrict__ sums_out){
  __shared__ alignas(16) u16 WL[32768];   // [0:16384) hi frags, [16384:32768) lo frags; 64 KB
  int t = threadIdx.x;
  for (int idx = t; idx < 2048; idx += 256){
    int lane_ = idx & 63, slot = idx >> 6;        // slot = nt*4 + ks
    int nt = slot >> 2, ks = slot & 3;
    int n_ = nt * 16 + (lane_ & 15);
    int kb = ks * 32 + (lane_ >> 4) * 8;
    *(uint4*)&WL[idx * 8]         = *(const uint4*)(Wh_g + n_ * 128 + kb);
    *(uint4*)&WL[16384 + idx * 8] = *(const uint4*)(Wl_g + n_ * 128 + kb);
  }
  __syncthreads();
  int wave = t >> 6, lane = t & 63, m = lane & 15, q = lane >> 4;
  int row0 = blockIdx.x * 64 + wave * 16;
  const float* zr = z + (size_t)(row0 + m) * 128;
  f32x4 acc[8];
  #pragma unroll
  for (int i = 0; i < 8; i++) acc[i] = f32x4{0.f, 0.f, 0.f, 0.f};
  #pragma unroll
  for (int ks = 0; ks < 4; ks++){
    float4 z0 = *(const float4*)(zr + ks * 32 + q * 8);
    float4 z1 = *(const float4*)(zr + ks * 32 + q * 8 + 4);
    float zz[8] = {z0.x, z0.y, z0.z, z0.w, z1.x, z1.y, z1.z, z1.w};
    bf16x8 ah, al;
    #pragma unroll
    for (int j = 0; j < 8; j++){
      u16 hh = f2bf(zz[j]);
      ah[j] = (short)hh;
      al[j] = (short)f2bf(zz[j] - bf2f(hh));
    }
    #pragma unroll
    for (int nt = 0; nt < 8; nt++){
      bf16x8 bh = *(const bf16x8*)&WL[((nt * 4 + ks) * 64 + lane) * 8];
      bf16x8 bl = *(const bf16x8*)&WL[16384 + ((nt * 4 + ks) * 64 + lane) * 8];
      acc[nt] = __builtin_amdgcn_mfma_f32_16x16x32_bf16(ah, bh, acc[nt], 0, 0, 0);
      acc[nt] = __builtin_amdgcn_mfma_f32_16x16x32_bf16(al, bh, acc[nt], 0, 0, 0);
      acc[nt] = __builtin_amdgcn_mfma_f32_16x16x32_bf16(ah, bl, acc[nt], 0, 0, 0);
    }
  }
  __syncthreads();                 // done with W frags; reuse LDS for stats
  float* sred = (float*)WL;        // 256 floats: [0:128) col sums, [128:256) col sumsq
  sred[t] = 0.f;
  __syncthreads();
  #pragma unroll
  for (int nt = 0; nt < 8; nt++){
    int colc = nt * 16 + m;
    float rv = rb[colc], bv = rb[128 + colc];
    float s = 0.f, qq = 0.f;
    #pragma unroll
    for (int r = 0; r < 4; r++){
      int rown = row0 + q * 4 + r;                // C/D: col=lane&15, row=quad*4+reg
      float v = acc[nt][r] + srow[rown] * rv + bv;
      v = fmaxf(v, 0.f);
      u16 sv = f2bf(v);
      hout[(size_t)rown * 128 + colc] = sv;
      if (rown < N_NODES){ float vv = bf2f(sv); s += vv; qq += vv * vv; }
    }
    atomicAdd(&sred[colc], s);
    atomicAdd(&sred[128 + colc], qq);
  }
  __syncthreads();
  atomicAdd(&sums_out[t], sred[t]);
}

// ---------------- branch-4 elementwise: out = relu(bn(h)); stats -> atomic ----------------
__global__ __launch_bounds__(256) void k_normrelu(const u16* __restrict__ h, const float* __restrict__ sums,
    const float* __restrict__ bw, const float* __restrict__ bb, u16* __restrict__ o,
    float* __restrict__ sums_out){
  __shared__ float scl[128], shf[128], R[1024];
  int t = threadIdx.x;
  if (t < 128){
    float mu  = sums[t] * (1.f / N_NODES);
    float var = sums[128 + t] * (1.f / N_NODES) - mu * mu;
    float sc  = bw[t] * rsqrtf(var + EPS);
    scl[t] = sc; shf[t] = bb[t] - mu * sc;
  }
  __syncthreads();
  int c0 = (t & 63) * 2;
  float sc0 = scl[c0], sh0 = shf[c0], sc1 = scl[c0 + 1], sh1 = shf[c0 + 1];
  float s0 = 0.f, q0 = 0.f, s1 = 0.f, q1 = 0.f;
  size_t base = (size_t)blockIdx.x * 4096 + t;
  #pragma unroll
  for (int it = 0; it < 16; it++){
    size_t idx = base + (size_t)it * 256;
    if (idx < (size_t)N_NODES * 64){
      u32 v = ((const u32*)h)[idx];
      float x0 = fmaxf(bf2f(v & 0xffffu) * sc0 + sh0, 0.f);
      float x1 = fmaxf(bf2f(v >> 16) * sc1 + sh1, 0.f);
      u16 r0 = f2bf(x0), r1 = f2bf(x1);
      ((u32*)o)[idx] = (u32)r0 | ((u32)r1 << 16);
      float y0 = bf2f(r0), y1 = bf2f(r1);
      s0 += y0; q0 += y0 * y0; s1 += y1; q1 += y1 * y1;
    }
  }
  R[t] = s0; R[256 + t] = q0; R[512 + t] = s1; R[768 + t] = q1;
  __syncthreads();
  if (t < 64){
    float S0 = 0.f, Q0 = 0.f, S1 = 0.f, Q1 = 0.f;
    #pragma unroll
    for (int g = 0; g < 4; g++){
      S0 += R[g * 64 + t];       Q0 += R[256 + g * 64 + t];
      S1 += R[512 + g * 64 + t]; Q1 += R[768 + g * 64 + t];
    }
    atomicAdd(&sums_out[2 * t], S0);
    atomicAdd(&sums_out[2 * t + 1], S1);
    atomicAdd(&sums_out[128 + 2 * t], Q0);
    atomicAdd(&sums_out[128 + 2 * t + 1], Q1);
  }
}

// ---------------- global_add_pool ----------------
__global__ __launch_bounds__(128) void k_pool(const u16* __restrict__ h, const int* __restrict__ gptr,
                                              float* __restrict__ gdst){
  int g = blockIdx.x >> 3, s = blockIdx.x & 7, t = threadIdx.x;
  int b = gptr[g], e = gptr[g + 1];
  int len = e - b, per = (len + 7) >> 3;
  int r0 = b + s * per, r1 = min(r0 + per, e);
  float acc = 0.f;
  for (int r = r0; r < r1; r++) acc += bf2f(h[(size_t)r * 128 + t]);
  atomicAdd(&gdst[g * 128 + t], acc);
}

// ---------------- head: all-f32, LDS-staged, static acc indexing, f32 output ----------------
__global__ __launch_bounds__(256) void k_head(const float* __restrict__ gbuf,
    const float* __restrict__ fcw, const float* __restrict__ fcb,
    const float* __restrict__ Wfc, const float* __restrict__ bfc,
    const float* __restrict__ bhw, const float* __restrict__ bhb,
    const float* __restrict__ Wcl, const float* __restrict__ bcl,
    float* __restrict__ out){
  __shared__ float Gs[128 * 66];          // stride 66: float2-aligned
  __shared__ float scl[128], shf[128], reds[256], redq[256];
  __shared__ float scl2[128], shf2[128];
  int t = threadIdx.x, br = blockIdx.x;
  int slot = (br == 1) ? 1 : (br == 3 ? 3 : 0);   // branch3 == branch1 (slot 0)
  const float* G = gbuf + slot * 16384;
  if (t < 128){
    float s = 0.f, q = 0.f;
    for (int g = 0; g < 128; g++){ float v = G[g * 128 + t]; s += v; q += v * v; }
    float mu = s * (1.f / 128), var = q * (1.f / 128) - mu * mu;
    float sc = fcw[t] * rsqrtf(var + EPS);
    scl[t] = sc; shf[t] = fcb[t] - mu * sc;
  }
  __syncthreads();
  int jo = t & 127, ih = (t >> 7) * 64;
  float acc[64];
  #pragma unroll
  for (int k = 0; k < 64; k++) acc[k] = 0.f;
  for (int half = 0; half < 2; half++){
    for (int idx = t; idx < 8192; idx += 256){
      int r = idx >> 6, fj = idx & 63, f = half * 64 + fj;
      Gs[r * 66 + fj] = G[r * 128 + f] * scl[f] + shf[f];
    }
    __syncthreads();
    for (int fj2 = 0; fj2 < 32; fj2++){
      int f = half * 64 + fj2 * 2;
      float w0 = Wfc[f * 128 + jo];
      float w1 = Wfc[(f + 1) * 128 + jo];
      #pragma unroll
      for (int k = 0; k < 64; k++){
        float2 g2 = *(const float2*)&Gs[(ih + k) * 66 + fj2 * 2];
        acc[k] += g2.x * w0 + g2.y * w1;
      }
    }
    __syncthreads();
  }
  {
    float bb = bfc[jo];
    float s = 0.f, q = 0.f;
    #pragma unroll
    for (int k = 0; k < 64; k++){ acc[k] = fmaxf(acc[k] + bb, 0.f); s += acc[k]; q += acc[k] * acc[k]; }
    reds[t] = s; redq[t] = q;
  }
  __syncthreads();
  if (t < 128){
    float s = reds[t] + reds[t + 128], q = redq[t] + redq[t + 128];
    float mu = s * (1.f / 128), var = q * (1.f / 128) - mu * mu;
    float sc = bhw[t] * rsqrtf(var + EPS);
    scl2[t] = sc; shf2[t] = bhb[t] - mu * sc;
  }
  __syncthreads();
  float l[10];
  #pragma unroll
  for (int c = 0; c < 10; c++) l[c] = bcl[c];
  float sc2 = scl2[jo], sh2 = shf2[jo];
  for (int p = 0; p < 2; p++){
    if ((jo >> 6) == p){
      int cj = jo & 63;
      #pragma unroll
      for (int k = 0; k < 64; k++) Gs[(ih + k) * 66 + cj] = acc[k] * sc2 + sh2;
    }
    __syncthreads();
    if (t < 128){
      for (int f02 = 0; f02 < 32; f02++){
        float2 g2 = *(const float2*)&Gs[t * 66 + f02 * 2];
        int f = p * 64 + f02 * 2;
        #pragma unroll
        for (int c = 0; c < 10; c++)
          l[c] += g2.x * Wcl[f * 10 + c] + g2.y * Wcl[(f + 1) * 10 + c];
      }
    }
    __syncthreads();
  }
  if (t < 128){
    float m = l[0];
    #pragma unroll
    for (int c = 1; c < 10; c++) m = fmaxf(m, l[c]);
    float se = 0.f;
    #pragma unroll
    for (int c = 0; c < 10; c++) se += expf(l[c] - m);
    float lse = m + logf(se);
    #pragma unroll
    for (int c = 0; c < 10; c++) out[br * 1280 + t * 10 + c] = l[c] - lse;
  }
}

extern "C" void kernel_launch(void* const* d_in, const int* in_sizes, int n_in,
                              void* d_out, int out_size, void* d_ws, size_t ws_size,
                              hipStream_t stream){
  const float* x    = (const float*)d_in[0];
  const int*  ei    = (const int*)d_in[1];      // [2,E]: rows then cols
  const int*  batch = (const int*)d_in[2];
  const float* ew   = (const float*)d_in[3];
  const float* bnfw = (const float*)d_in[4];
  const float* bnfb = (const float*)d_in[5];
  const float* cfW  = (const float*)d_in[6];
  const float* cfb  = (const float*)d_in[7];
  const float* bnsw = (const float*)d_in[8];
  const float* bnsb = (const float*)d_in[9];
  const float* cvW  = (const float*)d_in[10];
  const float* cvb  = (const float*)d_in[11];
  const float* fcw  = (const float*)d_in[12];
  const float* fcb  = (const float*)d_in[13];
  const float* Wfc  = (const float*)d_in[14];
  const float* bfc  = (const float*)d_in[15];
  const float* bhw  = (const float*)d_in[16];
  const float* bhb  = (const float*)d_in[17];
  const float* Wcl  = (const float*)d_in[18];
  const float* bcl  = (const float*)d_in[19];
  float* out = (float*)d_out;

  char* p = (char*)d_ws;
  auto carve = [&](size_t bytes)->void*{ void* r = (void*)p; p += (bytes + 255) & ~(size_t)255; return r; };
  float* deg  = (float*)carve((size_t)NPAD * 4);
  float* dinv = (float*)carve((size_t)NPAD * 4);
  float* srow = (float*)carve((size_t)NPAD * 4);
  int*   cnt  = (int*)carve((size_t)NPAD * 4);
  int*   fill = (int*)carve((size_t)NPAD * 4);
  int*   ptrA = (int*)carve((size_t)(NPAD + 1) * 4);
  int*   bpart= (int*)carve((size_t)391 * 128 * 4);
  int*   csum = (int*)carve(512);
  int*   coff = (int*)carve(512);
  int*   gptr = (int*)carve(1024);
  float* S    = (float*)carve(16384);        // 13 x 256-float stat accumulators (atomic targets)
  float* rb   = (float*)carve(1024);
  u16*   Wh   = (u16*)carve(128 * 128 * 2);
  u16*   Wl   = (u16*)carve(128 * 128 * 2);
  float* gbuf = (float*)carve(4 * 128 * 128 * 4);
  float* z    = (float*)carve((size_t)NPAD * 128 * 4);
  u16*   B0   = (u16*)carve((size_t)NPAD * 256);
  u16*   B1   = (u16*)carve((size_t)NPAD * 256);
  u16*   B2   = (u16*)carve((size_t)NPAD * 256);
  u16*   B3   = (u16*)carve((size_t)NPAD * 256);
  int2*  adj  = (int2*)carve((size_t)NEDGE * 8);
  u16*   Xb   = B3;   // bf16 x staging; B3's first real write (d2) is after layer-0 spmm consumes Xb
  auto Sb = [&](int i){ return S + i * 256; };

  (void)hipMemsetAsync(S, 0, 13 * 1024, stream);

  // preprocessing: degrees, norms, CSR, group offsets
  k_init<<<392, 256, 0, stream>>>(deg, cnt, fill, gbuf);
  k_deg<<<3125, 256, 0, stream>>>(ei + NEDGE, ew, deg, cnt);
  k_dinv<<<391, 256, 0, stream>>>(deg, dinv, srow);
  k_srow<<<3125, 256, 0, stream>>>(ei, ei + NEDGE, ew, dinv, srow);
  k_chunksum<<<98, 256, 0, stream>>>(cnt, csum);
  k_chunkscan<<<1, 128, 0, stream>>>(csum, coff, ptrA);
  k_scan2<<<98, 256, 0, stream>>>(cnt, coff, ptrA);
  k_fill<<<3125, 256, 0, stream>>>(ei, ei + NEDGE, ew, dinv, ptrA, fill, adj);
  k_bhist<<<391, 256, 0, stream>>>(batch, bpart);
  k_bscan<<<1, 128, 0, stream>>>(bpart, gptr);
  k_cvt<<<25000, 256, 0, stream>>>(x, (u32*)Xb);
  k_statsx<<<196, 256, 0, stream>>>(x, Sb(0));

  auto spmm = [&](const u16* hin){ k_spmm<<<25000, 256, 0, stream>>>(hin, ptrA, adj, dinv, z); };
  auto conv = [&](const float* Sin, const float* bw, const float* bb,
                  const float* W, const float* bias, u16* hout, float* Sout){
    k_fold<<<1, 256, 0, stream>>>(Sin, bw, bb, W, bias, Wh, Wl, rb);
    k_gemm<<<NBLK, 256, 0, stream>>>(z, Wh, Wl, srow, rb, hout, Sout);
  };

  // layer 0: h_init = relu(conv(bn_feat(x)))
  spmm(Xb);
  conv(Sb(0), bnfw, bnfb, cfW, cfb, B0, Sb(1));            // B0 = h_init; S1 = stats(h_init)
  // a1 = step(h_init, bn0/W0)  (== branch2 c1)
  spmm(B0);
  conv(Sb(1), bnsw, bnsb, cvW, cvb, B1, Sb(2));            // B1 = a1; S2 = stats(a1)
  // branch 4: d1,d2,d3 (d1 uses stats(h_init))
  k_normrelu<<<NBLK, 256, 0, stream>>>(B0, Sb(1), bnsw,       bnsb,       B2, Sb(3));   // d1 -> B2
  k_normrelu<<<NBLK, 256, 0, stream>>>(B2, Sb(3), bnsw + 128, bnsb + 128, B3, Sb(4));   // d2 -> B3
  k_normrelu<<<NBLK, 256, 0, stream>>>(B3, Sb(4), bnsw + 256, bnsb + 256, B2, Sb(12));  // d3 -> B2
  k_pool<<<1024, 128, 0, stream>>>(B2, gptr, gbuf + 3 * 16384);
  // z = S@a1 serves a2 AND c2
  spmm(B1);
  conv(Sb(2), bnsw + 128, bnsb + 128, cvW + 16384, cvb + 128, B3, Sb(5));  // a2 -> B3; S5 = stats(a2)
  conv(Sb(2), bnsw, bnsb, cvW, cvb, B2, Sb(6));                            // c2 -> B2; S6 = stats(c2)
  // a3 = step(a2, bn2/W2) -> branches 1 & 3
  spmm(B3);
  conv(Sb(5), bnsw + 256, bnsb + 256, cvW + 32768, cvb + 256, B0, Sb(10)); // a3 -> B0
  k_pool<<<1024, 128, 0, stream>>>(B0, gptr, gbuf);
  // c3 = step(c2, bn1/W1)
  spmm(B2);
  conv(Sb(6), bnsw + 128, bnsb + 128, cvW + 16384, cvb + 128, B1, Sb(7));  // c3 -> B1
  // c4 = step(c3, bn1/W1)
  spmm(B1);
  conv(Sb(7), bnsw + 128, bnsb + 128, cvW + 16384, cvb + 128, B2, Sb(8));  // c4 -> B2
  // c5 = step(c4, bn2/W2)
  spmm(B2);
  conv(Sb(8), bnsw + 256, bnsb + 256, cvW + 32768, cvb + 256, B1, Sb(9));  // c5 -> B1
  // c6 = step(c5, bn2/W2) -> branch 2
  spmm(B1);
  conv(Sb(9), bnsw + 256, bnsb + 256, cvW + 32768, cvb + 256, B3, Sb(11)); // c6 -> B3
  k_pool<<<1024, 128, 0, stream>>>(B3, gptr, gbuf + 16384);

  k_head<<<4, 256, 0, stream>>>(gbuf, fcw, fcb, Wfc, bfc, bhw, bhb, Wcl, bcl, out);
}

// Round 6
// 1940.759 us; speedup vs baseline: 3.0250x; 1.0742x over previous
//
#include <hip/hip_runtime.h>

#define N_NODES 100000
#define NPAD    100032      // multiple of 64 for unguarded GEMM tiles
#define NBLK    1563        // NPAD/64
#define NEDGE   800000
#define NGRP    128
#define EPS     1e-5f

typedef unsigned int   u32;
typedef unsigned short u16;
typedef short bf16x8 __attribute__((ext_vector_type(8)));
typedef float f32x4  __attribute__((ext_vector_type(4)));

__device__ __forceinline__ float bf2f(u32 u){ return __uint_as_float(u << 16); }
__device__ __forceinline__ u16 f2bf(float f){
  u32 x = __float_as_uint(f);
  x += 0x7fffu + ((x >> 16) & 1u);      // round-to-nearest-even
  return (u16)(x >> 16);
}

// ---------------- x (f32) -> bf16 staging buffer ----------------
__global__ void k_cvt(const float* __restrict__ x, u32* __restrict__ dst){
  int i = blockIdx.x * 256 + threadIdx.x;        // grid covers N_NODES*64 pairs exactly
  float2 v = ((const float2*)x)[i];
  dst[i] = (u32)f2bf(v.x) | ((u32)f2bf(v.y) << 16);
}

// ---------------- preprocessing ----------------
__global__ void k_init(float* deg, int* cnt, int* fill, float* gbuf){
  int i = blockIdx.x * 256 + threadIdx.x;
  if (i < NPAD){ deg[i] = 1.0f; cnt[i] = 0; fill[i] = 0; }   // deg starts at 1 (self-loop)
  if (i < 4 * NGRP * 128) gbuf[i] = 0.f;
}

__global__ void k_deg(const int* __restrict__ col, const float* __restrict__ ew,
                      float* __restrict__ deg, int* __restrict__ cnt){
  int e = blockIdx.x * 256 + threadIdx.x;
  if (e < NEDGE){
    int c = col[e];
    atomicAdd(&deg[c], ew[e]);
    atomicAdd(&cnt[c], 1);
  }
}

__global__ void k_dinv(const float* __restrict__ deg, float* __restrict__ dinv, float* __restrict__ srow){
  int i = blockIdx.x * 256 + threadIdx.x;
  if (i < N_NODES){
    float d = deg[i];
    float v = d > 0.f ? rsqrtf(fmaxf(d, EPS)) : 0.f;
    dinv[i] = v; srow[i] = v * v;       // srow starts with self-loop norm
  }
}

__global__ __launch_bounds__(256) void k_chunksum(const int* __restrict__ cnt, int* __restrict__ csum){
  int b = blockIdx.x, t = threadIdx.x;
  int s = 0;
  for (int i = t; i < 1024; i += 256){ int idx = b * 1024 + i; if (idx < N_NODES) s += cnt[idx]; }
  __shared__ int red[256];
  red[t] = s; __syncthreads();
  for (int o = 128; o > 0; o >>= 1){ if (t < o) red[t] += red[t + o]; __syncthreads(); }
  if (t == 0) csum[b] = red[0];
}

__global__ __launch_bounds__(128) void k_chunkscan(const int* __restrict__ csum, int* __restrict__ coff,
                                                   int* __restrict__ ptrA){
  int t = threadIdx.x;
  __shared__ int s[128];
  int v = (t < 98) ? csum[t] : 0;
  s[t] = v; __syncthreads();
  for (int o = 1; o < 128; o <<= 1){
    int x = (t >= o) ? s[t - o] : 0;
    __syncthreads(); s[t] += x; __syncthreads();
  }
  if (t < 98) coff[t] = s[t] - v;       // exclusive chunk offsets
  if (t == 0) ptrA[N_NODES] = NEDGE;
}

__global__ __launch_bounds__(256) void k_scan2(const int* __restrict__ cnt, const int* __restrict__ coff,
                                               int* __restrict__ ptrA){
  int b = blockIdx.x, t = threadIdx.x;
  int base = b * 1024 + t * 4;
  int v[4], tot = 0;
  #pragma unroll
  for (int k = 0; k < 4; k++){ int idx = base + k; v[k] = (idx < N_NODES) ? cnt[idx] : 0; tot += v[k]; }
  __shared__ int sc[256];
  sc[t] = tot; __syncthreads();
  for (int o = 1; o < 256; o <<= 1){
    int x = (t >= o) ? sc[t - o] : 0;
    __syncthreads(); sc[t] += x; __syncthreads();
  }
  int off = coff[b] + sc[t] - tot;
  #pragma unroll
  for (int k = 0; k < 4; k++){ int idx = base + k; if (idx < N_NODES) ptrA[idx] = off; off += v[k]; }
}

// fill CSR + accumulate srow (merged, one edge pass)
__global__ void k_fill(const int* __restrict__ row, const int* __restrict__ col,
                       const float* __restrict__ ew, const float* __restrict__ dinv,
                       const int* __restrict__ ptrA, int* __restrict__ fill, int2* __restrict__ adj,
                       float* __restrict__ srow){
  int e = blockIdx.x * 256 + threadIdx.x;
  if (e < NEDGE){
    int r = row[e], c = col[e];
    float w = dinv[r] * ew[e] * dinv[c];
    int pos = ptrA[c] + atomicAdd(&fill[c], 1);
    adj[pos] = make_int2(r, __float_as_int(w));
    atomicAdd(&srow[c], w);
  }
}

// per-block LDS histogram -> partials (no global atomics)
__global__ __launch_bounds__(256) void k_bhist(const int* __restrict__ batch, int* __restrict__ bpart){
  __shared__ int loc[128];
  int t = threadIdx.x;
  if (t < 128) loc[t] = 0;
  __syncthreads();
  int i = blockIdx.x * 256 + t;
  if (i < N_NODES) atomicAdd(&loc[batch[i]], 1);
  __syncthreads();
  if (t < 128) bpart[blockIdx.x * 128 + t] = loc[t];
}

__global__ __launch_bounds__(128) void k_bscan(const int* __restrict__ bpart, int* __restrict__ gptr){
  int t = threadIdx.x;
  int v = 0;
  for (int p = 0; p < 391; p++) v += bpart[p * 128 + t];
  __shared__ int s[128];
  s[t] = v; __syncthreads();
  for (int o = 1; o < 128; o <<= 1){
    int x = (t >= o) ? s[t - o] : 0;
    __syncthreads(); s[t] += x; __syncthreads();
  }
  gptr[t + 1] = s[t];
  if (t == 0) gptr[0] = 0;
}

// ---------------- column stats of f32 x -> atomic accumulate into sums[256] ----------------
__global__ __launch_bounds__(256) void k_statsx(const float* __restrict__ x, float* __restrict__ sums){
  int t = threadIdx.x, col = t & 127, half = t >> 7;
  int r0 = blockIdx.x * 512;
  int rend = min(r0 + 512, N_NODES);
  float s = 0.f, q = 0.f;
  for (int r = r0 + half; r < rend; r += 2){
    float v = x[(size_t)r * 128 + col];
    s += v; q += v * v;
  }
  __shared__ float ls[256], lq[256];
  ls[t] = s; lq[t] = q;
  __syncthreads();
  if (half == 0){
    atomicAdd(&sums[col],       s + ls[t + 128]);
    atomicAdd(&sums[128 + col], q + lq[t + 128]);
  }
}

// ---------------- fold BN into GEMM weights (hi/lo split); sums read directly ----------------
__global__ __launch_bounds__(256) void k_fold(const float* __restrict__ sums,
    const float* __restrict__ bw, const float* __restrict__ bb,
    const float* __restrict__ W, const float* __restrict__ bias,
    u16* __restrict__ Wh, u16* __restrict__ Wl, float* __restrict__ rb){
  __shared__ float scl[128], shf[128], redp[256];
  int t = threadIdx.x;
  if (t < 128){
    float mu  = sums[t] * (1.f / N_NODES);
    float var = sums[128 + t] * (1.f / N_NODES) - mu * mu;
    float sc  = bw[t] * rsqrtf(var + EPS);
    scl[t] = sc; shf[t] = bb[t] - mu * sc;
  }
  __syncthreads();
  int j = t & 127, hf = (t >> 7) * 64;
  float acc = 0.f;
  for (int f0 = 0; f0 < 64; f0++){
    int f = hf + f0;
    float wv = W[f * 128 + j];
    acc += shf[f] * wv;
    float x = scl[f] * wv;
    u16 hh = f2bf(x);
    Wh[j * 128 + f] = hh;
    Wl[j * 128 + f] = f2bf(x - bf2f(hh));
  }
  redp[t] = acc;
  __syncthreads();
  if (t < 128){
    rb[t] = redp[t] + redp[t + 128];
    rb[128 + t] = bias[t];
  }
}

// ---------------- SpMM v2: 4 nodes/wave, 16 lanes x 16B per row, 4-deep unroll ----------------
__global__ __launch_bounds__(256) void k_spmm(const u16* __restrict__ h,
    const int* __restrict__ ptrA, const int2* __restrict__ adj,
    const float* __restrict__ dinv, float* __restrict__ z){
  int t = threadIdx.x;
  int sub = t & 15;
  int i = blockIdx.x * 16 + (t >> 4);
  if (i >= N_NODES) return;
  float di = dinv[i], sw = di * di;
  const u16* hp = h + sub * 8;
  float acc[8];
  {
    uint4 v = *(const uint4*)(hp + (size_t)i * 128);
    acc[0] = sw * __uint_as_float(v.x << 16);          acc[1] = sw * __uint_as_float(v.x & 0xffff0000u);
    acc[2] = sw * __uint_as_float(v.y << 16);          acc[3] = sw * __uint_as_float(v.y & 0xffff0000u);
    acc[4] = sw * __uint_as_float(v.z << 16);          acc[5] = sw * __uint_as_float(v.z & 0xffff0000u);
    acc[6] = sw * __uint_as_float(v.w << 16);          acc[7] = sw * __uint_as_float(v.w & 0xffff0000u);
  }
  int b = ptrA[i], e = ptrA[i + 1];
  int k = b;
  #define FMA8(V, W) \
    acc[0] += (W) * __uint_as_float((V).x << 16);          acc[1] += (W) * __uint_as_float((V).x & 0xffff0000u); \
    acc[2] += (W) * __uint_as_float((V).y << 16);          acc[3] += (W) * __uint_as_float((V).y & 0xffff0000u); \
    acc[4] += (W) * __uint_as_float((V).z << 16);          acc[5] += (W) * __uint_as_float((V).z & 0xffff0000u); \
    acc[6] += (W) * __uint_as_float((V).w << 16);          acc[7] += (W) * __uint_as_float((V).w & 0xffff0000u);
  for (; k + 4 <= e; k += 4){
    int2 a0 = adj[k], a1 = adj[k + 1], a2 = adj[k + 2], a3 = adj[k + 3];
    uint4 v0 = *(const uint4*)(hp + (size_t)a0.x * 128);
    uint4 v1 = *(const uint4*)(hp + (size_t)a1.x * 128);
    uint4 v2 = *(const uint4*)(hp + (size_t)a2.x * 128);
    uint4 v3 = *(const uint4*)(hp + (size_t)a3.x * 128);
    float w0 = __int_as_float(a0.y), w1 = __int_as_float(a1.y);
    float w2 = __int_as_float(a2.y), w3 = __int_as_float(a3.y);
    FMA8(v0, w0); FMA8(v1, w1); FMA8(v2, w2); FMA8(v3, w3);
  }
  for (; k < e; k++){
    int2 a0 = adj[k];
    uint4 v0 = *(const uint4*)(hp + (size_t)a0.x * 128);
    float w0 = __int_as_float(a0.y);
    FMA8(v0, w0);
  }
  #undef FMA8
  float* zp = z + (size_t)i * 128 + sub * 8;
  *(float4*)zp       = make_float4(acc[0], acc[1], acc[2], acc[3]);
  *(float4*)(zp + 4) = make_float4(acc[4], acc[5], acc[6], acc[7]);
}

// ---------------- GEMM: hout = relu(z @ W' + srow*r + bias), hi/lo bf16 MFMA; stats -> atomic ----------------
__global__ __launch_bounds__(256) void k_gemm(const float* __restrict__ z,
    const u16* __restrict__ Wh_g, const u16* __restrict__ Wl_g,
    const float* __restrict__ srow, const float* __restrict__ rb,
    u16* __restrict__ hout, float* __restrict__ sums_out){
  __shared__ alignas(16) u16 WL[32768];   // [0:16384) hi frags, [16384:32768) lo frags; 64 KB
  int t = threadIdx.x;
  for (int idx = t; idx < 2048; idx += 256){
    int lane_ = idx & 63, slot = idx >> 6;        // slot = nt*4 + ks
    int nt = slot >> 2, ks = slot & 3;
    int n_ = nt * 16 + (lane_ & 15);
    int kb = ks * 32 + (lane_ >> 4) * 8;
    *(uint4*)&WL[idx * 8]         = *(const uint4*)(Wh_g + n_ * 128 + kb);
    *(uint4*)&WL[16384 + idx * 8] = *(const uint4*)(Wl_g + n_ * 128 + kb);
  }
  __syncthreads();
  int wave = t >> 6, lane = t & 63, m = lane & 15, q = lane >> 4;
  int row0 = blockIdx.x * 64 + wave * 16;
  const float* zr = z + (size_t)(row0 + m) * 128;
  f32x4 acc[8];
  #pragma unroll
  for (int i = 0; i < 8; i++) acc[i] = f32x4{0.f, 0.f, 0.f, 0.f};
  #pragma unroll
  for (int ks = 0; ks < 4; ks++){
    float4 z0 = *(const float4*)(zr + ks * 32 + q * 8);
    float4 z1 = *(const float4*)(zr + ks * 32 + q * 8 + 4);
    float zz[8] = {z0.x, z0.y, z0.z, z0.w, z1.x, z1.y, z1.z, z1.w};
    bf16x8 ah, al;
    #pragma unroll
    for (int j = 0; j < 8; j++){
      u16 hh = f2bf(zz[j]);
      ah[j] = (short)hh;
      al[j] = (short)f2bf(zz[j] - bf2f(hh));
    }
    #pragma unroll
    for (int nt = 0; nt < 8; nt++){
      bf16x8 bh = *(const bf16x8*)&WL[((nt * 4 + ks) * 64 + lane) * 8];
      bf16x8 bl = *(const bf16x8*)&WL[16384 + ((nt * 4 + ks) * 64 + lane) * 8];
      acc[nt] = __builtin_amdgcn_mfma_f32_16x16x32_bf16(ah, bh, acc[nt], 0, 0, 0);
      acc[nt] = __builtin_amdgcn_mfma_f32_16x16x32_bf16(al, bh, acc[nt], 0, 0, 0);
      acc[nt] = __builtin_amdgcn_mfma_f32_16x16x32_bf16(ah, bl, acc[nt], 0, 0, 0);
    }
  }
  __syncthreads();                 // done with W frags; reuse LDS for stats
  float* sred = (float*)WL;        // 256 floats: [0:128) col sums, [128:256) col sumsq
  sred[t] = 0.f;
  __syncthreads();
  #pragma unroll
  for (int nt = 0; nt < 8; nt++){
    int colc = nt * 16 + m;
    float rv = rb[colc], bv = rb[128 + colc];
    float s = 0.f, qq = 0.f;
    #pragma unroll
    for (int r = 0; r < 4; r++){
      int rown = row0 + q * 4 + r;                // C/D: col=lane&15, row=quad*4+reg
      float v = acc[nt][r] + srow[rown] * rv + bv;
      v = fmaxf(v, 0.f);
      u16 sv = f2bf(v);
      hout[(size_t)rown * 128 + colc] = sv;
      if (rown < N_NODES){ float vv = bf2f(sv); s += vv; qq += vv * vv; }
    }
    atomicAdd(&sred[colc], s);
    atomicAdd(&sred[128 + colc], qq);
  }
  __syncthreads();
  atomicAdd(&sums_out[t], sred[t]);
}

// ---------------- branch-4 elementwise: out = relu(bn(h)); stats -> atomic ----------------
__global__ __launch_bounds__(256) void k_normrelu(const u16* __restrict__ h, const float* __restrict__ sums,
    const float* __restrict__ bw, const float* __restrict__ bb, u16* __restrict__ o,
    float* __restrict__ sums_out){
  __shared__ float scl[128], shf[128], R[1024];
  int t = threadIdx.x;
  if (t < 128){
    float mu  = sums[t] * (1.f / N_NODES);
    float var = sums[128 + t] * (1.f / N_NODES) - mu * mu;
    float sc  = bw[t] * rsqrtf(var + EPS);
    scl[t] = sc; shf[t] = bb[t] - mu * sc;
  }
  __syncthreads();
  int c0 = (t & 63) * 2;
  float sc0 = scl[c0], sh0 = shf[c0], sc1 = scl[c0 + 1], sh1 = shf[c0 + 1];
  float s0 = 0.f, q0 = 0.f, s1 = 0.f, q1 = 0.f;
  size_t base = (size_t)blockIdx.x * 4096 + t;
  #pragma unroll
  for (int it = 0; it < 16; it++){
    size_t idx = base + (size_t)it * 256;
    if (idx < (size_t)N_NODES * 64){
      u32 v = ((const u32*)h)[idx];
      float x0 = fmaxf(bf2f(v & 0xffffu) * sc0 + sh0, 0.f);
      float x1 = fmaxf(bf2f(v >> 16) * sc1 + sh1, 0.f);
      u16 r0 = f2bf(x0), r1 = f2bf(x1);
      ((u32*)o)[idx] = (u32)r0 | ((u32)r1 << 16);
      float y0 = bf2f(r0), y1 = bf2f(r1);
      s0 += y0; q0 += y0 * y0; s1 += y1; q1 += y1 * y1;
    }
  }
  R[t] = s0; R[256 + t] = q0; R[512 + t] = s1; R[768 + t] = q1;
  __syncthreads();
  if (t < 64){
    float S0 = 0.f, Q0 = 0.f, S1 = 0.f, Q1 = 0.f;
    #pragma unroll
    for (int g = 0; g < 4; g++){
      S0 += R[g * 64 + t];       Q0 += R[256 + g * 64 + t];
      S1 += R[512 + g * 64 + t]; Q1 += R[768 + g * 64 + t];
    }
    atomicAdd(&sums_out[2 * t], S0);
    atomicAdd(&sums_out[2 * t + 1], S1);
    atomicAdd(&sums_out[128 + 2 * t], Q0);
    atomicAdd(&sums_out[128 + 2 * t + 1], Q1);
  }
}

// ---------------- global_add_pool ----------------
__global__ __launch_bounds__(128) void k_pool(const u16* __restrict__ h, const int* __restrict__ gptr,
                                              float* __restrict__ gdst){
  int g = blockIdx.x >> 3, s = blockIdx.x & 7, t = threadIdx.x;
  int b = gptr[g], e = gptr[g + 1];
  int len = e - b, per = (len + 7) >> 3;
  int r0 = b + s * per, r1 = min(r0 + per, e);
  float acc = 0.f;
  for (int r = r0; r < r1; r++) acc += bf2f(h[(size_t)r * 128 + t]);
  atomicAdd(&gdst[g * 128 + t], acc);
}

// ---------------- head v2: 8x8 register-tile FC, shfl-reduced classifier ----------------
__global__ __launch_bounds__(256) void k_head(const float* __restrict__ gbuf,
    const float* __restrict__ fcw, const float* __restrict__ fcb,
    const float* __restrict__ Wfc, const float* __restrict__ bfc,
    const float* __restrict__ bhw, const float* __restrict__ bhb,
    const float* __restrict__ Wcl, const float* __restrict__ bcl,
    float* __restrict__ out){
  __shared__ float GS[128 * 65];           // Gbn k-half staging (33 KB)
  __shared__ float ls[256], lq[256];
  __shared__ float scl[128], shf[128], scl2[128], shf2[128];
  __shared__ float sumT[128], sumQ[128];
  __shared__ float WclT[1280], Lrow[1280];
  int t = threadIdx.x, br = blockIdx.x;
  int slot = (br == 1) ? 1 : (br == 3 ? 3 : 0);   // branch3 == branch1 (slot 0)
  const float* G = gbuf + slot * 16384;
  { // stats of G
    int col = t & 127, hf2 = t >> 7;
    float s = 0.f, q = 0.f;
    for (int g = hf2 * 64; g < hf2 * 64 + 64; g++){ float v = G[g * 128 + col]; s += v; q += v * v; }
    ls[t] = s; lq[t] = q;
  }
  for (int idx = t; idx < 1280; idx += 256){     // WclT[cc][c] = Wcl[c][cc]
    int cc = idx >> 7, c = idx & 127;
    WclT[idx] = Wcl[c * 10 + cc];
  }
  if (t < 128){ sumT[t] = 0.f; sumQ[t] = 0.f; }
  __syncthreads();
  if (t < 128){
    float s = ls[t] + ls[t + 128], q = lq[t] + lq[t + 128];
    float mu = s * (1.f / 128), var = q * (1.f / 128) - mu * mu;
    float sc = fcw[t] * rsqrtf(var + EPS);
    scl[t] = sc; shf[t] = fcb[t] - mu * sc;
  }
  __syncthreads();
  int tr = t >> 4, tc = t & 15, r0 = tr * 8, c0 = tc * 8;
  float acc[8][8];
  #pragma unroll
  for (int a = 0; a < 8; a++)
    #pragma unroll
    for (int b = 0; b < 8; b++) acc[a][b] = 0.f;
  for (int kh = 0; kh < 2; kh++){
    for (int idx = t; idx < 8192; idx += 256){
      int r = idx >> 6, kk = idx & 63, f = kh * 64 + kk;
      GS[r * 65 + kk] = G[r * 128 + f] * scl[f] + shf[f];
    }
    __syncthreads();
    #pragma unroll 2
    for (int k = 0; k < 64; k++){
      float a[8];
      #pragma unroll
      for (int ri = 0; ri < 8; ri++) a[ri] = GS[(r0 + ri) * 65 + k];
      float4 b0 = *(const float4*)&Wfc[(kh * 64 + k) * 128 + c0];
      float4 b1 = *(const float4*)&Wfc[(kh * 64 + k) * 128 + c0 + 4];
      float bb[8] = {b0.x, b0.y, b0.z, b0.w, b1.x, b1.y, b1.z, b1.w};
      #pragma unroll
      for (int ri = 0; ri < 8; ri++)
        #pragma unroll
        for (int ci = 0; ci < 8; ci++) acc[ri][ci] += a[ri] * bb[ci];
    }
    __syncthreads();
  }
  // bias + relu + column stats for bn_hidden
  #pragma unroll
  for (int ci = 0; ci < 8; ci++){
    float bb = bfc[c0 + ci];
    float s = 0.f, q = 0.f;
    #pragma unroll
    for (int ri = 0; ri < 8; ri++){
      float v = fmaxf(acc[ri][ci] + bb, 0.f);
      acc[ri][ci] = v; s += v; q += v * v;
    }
    atomicAdd(&sumT[c0 + ci], s);
    atomicAdd(&sumQ[c0 + ci], q);
  }
  __syncthreads();
  if (t < 128){
    float mu = sumT[t] * (1.f / 128), var = sumQ[t] * (1.f / 128) - mu * mu;
    float sc = bhw[t] * rsqrtf(var + EPS);
    scl2[t] = sc; shf2[t] = bhb[t] - mu * sc;
  }
  __syncthreads();
  #pragma unroll
  for (int ci = 0; ci < 8; ci++){
    float sc = scl2[c0 + ci], sh = shf2[c0 + ci];
    #pragma unroll
    for (int ri = 0; ri < 8; ri++) acc[ri][ci] = acc[ri][ci] * sc + sh;
  }
  // classifier: per-thread partials over its 8 cols, shfl-reduce over tc
  #pragma unroll
  for (int ri = 0; ri < 8; ri++){
    float pl[10];
    #pragma unroll
    for (int cc = 0; cc < 10; cc++) pl[cc] = 0.f;
    #pragma unroll
    for (int ci = 0; ci < 8; ci++){
      float v = acc[ri][ci];
      #pragma unroll
      for (int cc = 0; cc < 10; cc++) pl[cc] += v * WclT[cc * 128 + c0 + ci];
    }
    #pragma unroll
    for (int msk = 1; msk < 16; msk <<= 1)
      #pragma unroll
      for (int cc = 0; cc < 10; cc++) pl[cc] += __shfl_xor(pl[cc], msk, 64);
    if (tc == 0)
      #pragma unroll
      for (int cc = 0; cc < 10; cc++) Lrow[(r0 + ri) * 10 + cc] = pl[cc];
  }
  __syncthreads();
  if (t < 128){
    float l[10];
    #pragma unroll
    for (int cc = 0; cc < 10; cc++) l[cc] = Lrow[t * 10 + cc] + bcl[cc];
    float m = l[0];
    #pragma unroll
    for (int cc = 1; cc < 10; cc++) m = fmaxf(m, l[cc]);
    float se = 0.f;
    #pragma unroll
    for (int cc = 0; cc < 10; cc++) se += expf(l[cc] - m);
    float lse = m + logf(se);
    #pragma unroll
    for (int cc = 0; cc < 10; cc++) out[br * 1280 + t * 10 + cc] = l[cc] - lse;
  }
}

extern "C" void kernel_launch(void* const* d_in, const int* in_sizes, int n_in,
                              void* d_out, int out_size, void* d_ws, size_t ws_size,
                              hipStream_t stream){
  const float* x    = (const float*)d_in[0];
  const int*  ei    = (const int*)d_in[1];      // [2,E]: rows then cols
  const int*  batch = (const int*)d_in[2];
  const float* ew   = (const float*)d_in[3];
  const float* bnfw = (const float*)d_in[4];
  const float* bnfb = (const float*)d_in[5];
  const float* cfW  = (const float*)d_in[6];
  const float* cfb  = (const float*)d_in[7];
  const float* bnsw = (const float*)d_in[8];
  const float* bnsb = (const float*)d_in[9];
  const float* cvW  = (const float*)d_in[10];
  const float* cvb  = (const float*)d_in[11];
  const float* fcw  = (const float*)d_in[12];
  const float* fcb  = (const float*)d_in[13];
  const float* Wfc  = (const float*)d_in[14];
  const float* bfc  = (const float*)d_in[15];
  const float* bhw  = (const float*)d_in[16];
  const float* bhb  = (const float*)d_in[17];
  const float* Wcl  = (const float*)d_in[18];
  const float* bcl  = (const float*)d_in[19];
  float* out = (float*)d_out;

  char* p = (char*)d_ws;
  auto carve = [&](size_t bytes)->void*{ void* r = (void*)p; p += (bytes + 255) & ~(size_t)255; return r; };
  float* deg  = (float*)carve((size_t)NPAD * 4);
  float* dinv = (float*)carve((size_t)NPAD * 4);
  float* srow = (float*)carve((size_t)NPAD * 4);
  int*   cnt  = (int*)carve((size_t)NPAD * 4);
  int*   fill = (int*)carve((size_t)NPAD * 4);
  int*   ptrA = (int*)carve((size_t)(NPAD + 1) * 4);
  int*   bpart= (int*)carve((size_t)391 * 128 * 4);
  int*   csum = (int*)carve(512);
  int*   coff = (int*)carve(512);
  int*   gptr = (int*)carve(1024);
  float* S    = (float*)carve(16384);        // 13 x 256-float stat accumulators (atomic targets)
  float* rb   = (float*)carve(1024);
  u16*   Wh   = (u16*)carve(128 * 128 * 2);
  u16*   Wl   = (u16*)carve(128 * 128 * 2);
  float* gbuf = (float*)carve(4 * 128 * 128 * 4);
  float* z    = (float*)carve((size_t)NPAD * 128 * 4);
  u16*   B0   = (u16*)carve((size_t)NPAD * 256);
  u16*   B1   = (u16*)carve((size_t)NPAD * 256);
  u16*   B2   = (u16*)carve((size_t)NPAD * 256);
  u16*   B3   = (u16*)carve((size_t)NPAD * 256);
  int2*  adj  = (int2*)carve((size_t)NEDGE * 8);
  u16*   Xb   = B3;   // bf16 x staging; B3's first real write (d2) is after layer-0 spmm consumes Xb
  auto Sb = [&](int i){ return S + i * 256; };

  (void)hipMemsetAsync(S, 0, 13 * 1024, stream);

  // preprocessing: degrees, norms, CSR, group offsets
  k_init<<<392, 256, 0, stream>>>(deg, cnt, fill, gbuf);
  k_deg<<<3125, 256, 0, stream>>>(ei + NEDGE, ew, deg, cnt);
  k_dinv<<<391, 256, 0, stream>>>(deg, dinv, srow);
  k_chunksum<<<98, 256, 0, stream>>>(cnt, csum);
  k_chunkscan<<<1, 128, 0, stream>>>(csum, coff, ptrA);
  k_scan2<<<98, 256, 0, stream>>>(cnt, coff, ptrA);
  k_fill<<<3125, 256, 0, stream>>>(ei, ei + NEDGE, ew, dinv, ptrA, fill, adj, srow);
  k_bhist<<<391, 256, 0, stream>>>(batch, bpart);
  k_bscan<<<1, 128, 0, stream>>>(bpart, gptr);
  k_cvt<<<25000, 256, 0, stream>>>(x, (u32*)Xb);
  k_statsx<<<196, 256, 0, stream>>>(x, Sb(0));

  auto spmm = [&](const u16* hin){ k_spmm<<<6250, 256, 0, stream>>>(hin, ptrA, adj, dinv, z); };
  auto conv = [&](const float* Sin, const float* bw, const float* bb,
                  const float* W, const float* bias, u16* hout, float* Sout){
    k_fold<<<1, 256, 0, stream>>>(Sin, bw, bb, W, bias, Wh, Wl, rb);
    k_gemm<<<NBLK, 256, 0, stream>>>(z, Wh, Wl, srow, rb, hout, Sout);
  };

  // layer 0: h_init = relu(conv(bn_feat(x)))
  spmm(Xb);
  conv(Sb(0), bnfw, bnfb, cfW, cfb, B0, Sb(1));            // B0 = h_init; S1 = stats(h_init)
  // a1 = step(h_init, bn0/W0)  (== branch2 c1)
  spmm(B0);
  conv(Sb(1), bnsw, bnsb, cvW, cvb, B1, Sb(2));            // B1 = a1; S2 = stats(a1)
  // branch 4: d1,d2,d3 (d1 uses stats(h_init))
  k_normrelu<<<NBLK, 256, 0, stream>>>(B0, Sb(1), bnsw,       bnsb,       B2, Sb(3));   // d1 -> B2
  k_normrelu<<<NBLK, 256, 0, stream>>>(B2, Sb(3), bnsw + 128, bnsb + 128, B3, Sb(4));   // d2 -> B3
  k_normrelu<<<NBLK, 256, 0, stream>>>(B3, Sb(4), bnsw + 256, bnsb + 256, B2, Sb(12));  // d3 -> B2
  k_pool<<<1024, 128, 0, stream>>>(B2, gptr, gbuf + 3 * 16384);
  // z = S@a1 serves a2 AND c2
  spmm(B1);
  conv(Sb(2), bnsw + 128, bnsb + 128, cvW + 16384, cvb + 128, B3, Sb(5));  // a2 -> B3; S5 = stats(a2)
  conv(Sb(2), bnsw, bnsb, cvW, cvb, B2, Sb(6));                            // c2 -> B2; S6 = stats(c2)
  // a3 = step(a2, bn2/W2) -> branches 1 & 3
  spmm(B3);
  conv(Sb(5), bnsw + 256, bnsb + 256, cvW + 32768, cvb + 256, B0, Sb(10)); // a3 -> B0
  k_pool<<<1024, 128, 0, stream>>>(B0, gptr, gbuf);
  // c3 = step(c2, bn1/W1)
  spmm(B2);
  conv(Sb(6), bnsw + 128, bnsb + 128, cvW + 16384, cvb + 128, B1, Sb(7));  // c3 -> B1
  // c4 = step(c3, bn1/W1)
  spmm(B1);
  conv(Sb(7), bnsw + 128, bnsb + 128, cvW + 16384, cvb + 128, B2, Sb(8));  // c4 -> B2
  // c5 = step(c4, bn2/W2)
  spmm(B2);
  conv(Sb(8), bnsw + 256, bnsb + 256, cvW + 32768, cvb + 256, B1, Sb(9));  // c5 -> B1
  // c6 = step(c5, bn2/W2) -> branch 2
  spmm(B1);
  conv(Sb(9), bnsw + 256, bnsb + 256, cvW + 32768, cvb + 256, B3, Sb(11)); // c6 -> B3
  k_pool<<<1024, 128, 0, stream>>>(B3, gptr, gbuf + 16384);

  k_head<<<4, 256, 0, stream>>>(gbuf, fcw, fcb, Wfc, bfc, bhw, bhb, Wcl, bcl, out);
}

// Round 7
// 1702.569 us; speedup vs baseline: 3.4482x; 1.1399x over previous
//
#include <hip/hip_runtime.h>

#define N_NODES 100000
#define NPAD    100032      // multiple of 64 for unguarded GEMM tiles
#define NBLK    1563        // NPAD/64
#define NEDGE   800000
#define NGRP    128
#define NSLOT   32          // mirrored stat-accumulator slots (atomic contention /32)
#define EPS     1e-5f

typedef unsigned int   u32;
typedef unsigned short u16;
typedef short bf16x8 __attribute__((ext_vector_type(8)));
typedef float f32x4  __attribute__((ext_vector_type(4)));

__device__ __forceinline__ float bf2f(u32 u){ return __uint_as_float(u << 16); }
__device__ __forceinline__ u16 f2bf(float f){
  u32 x = __float_as_uint(f);
  x += 0x7fffu + ((x >> 16) & 1u);      // round-to-nearest-even
  return (u16)(x >> 16);
}

// ---------------- x (f32) -> bf16 staging buffer ----------------
__global__ void k_cvt(const float* __restrict__ x, u32* __restrict__ dst){
  int i = blockIdx.x * 256 + threadIdx.x;        // grid covers N_NODES*64 pairs exactly
  float2 v = ((const float2*)x)[i];
  dst[i] = (u32)f2bf(v.x) | ((u32)f2bf(v.y) << 16);
}

// ---------------- preprocessing ----------------
__global__ void k_init(float* deg, int* cnt, int* fill, float* gbuf){
  int i = blockIdx.x * 256 + threadIdx.x;
  if (i < NPAD){ deg[i] = 1.0f; cnt[i] = 0; fill[i] = 0; }   // deg starts at 1 (self-loop)
  if (i < 4 * NGRP * 128) gbuf[i] = 0.f;
}

__global__ void k_deg(const int* __restrict__ col, const float* __restrict__ ew,
                      float* __restrict__ deg, int* __restrict__ cnt){
  int e = blockIdx.x * 256 + threadIdx.x;
  if (e < NEDGE){
    int c = col[e];
    atomicAdd(&deg[c], ew[e]);
    atomicAdd(&cnt[c], 1);
  }
}

__global__ void k_dinv(const float* __restrict__ deg, float* __restrict__ dinv, float* __restrict__ srow){
  int i = blockIdx.x * 256 + threadIdx.x;
  if (i < N_NODES){
    float d = deg[i];
    float v = d > 0.f ? rsqrtf(fmaxf(d, EPS)) : 0.f;
    dinv[i] = v; srow[i] = v * v;       // srow starts with self-loop norm
  }
}

__global__ __launch_bounds__(256) void k_chunksum(const int* __restrict__ cnt, int* __restrict__ csum){
  int b = blockIdx.x, t = threadIdx.x;
  int s = 0;
  for (int i = t; i < 1024; i += 256){ int idx = b * 1024 + i; if (idx < N_NODES) s += cnt[idx]; }
  __shared__ int red[256];
  red[t] = s; __syncthreads();
  for (int o = 128; o > 0; o >>= 1){ if (t < o) red[t] += red[t + o]; __syncthreads(); }
  if (t == 0) csum[b] = red[0];
}

__global__ __launch_bounds__(128) void k_chunkscan(const int* __restrict__ csum, int* __restrict__ coff,
                                                   int* __restrict__ ptrA){
  int t = threadIdx.x;
  __shared__ int s[128];
  int v = (t < 98) ? csum[t] : 0;
  s[t] = v; __syncthreads();
  for (int o = 1; o < 128; o <<= 1){
    int x = (t >= o) ? s[t - o] : 0;
    __syncthreads(); s[t] += x; __syncthreads();
  }
  if (t < 98) coff[t] = s[t] - v;       // exclusive chunk offsets
  if (t == 0) ptrA[N_NODES] = NEDGE;
}

__global__ __launch_bounds__(256) void k_scan2(const int* __restrict__ cnt, const int* __restrict__ coff,
                                               int* __restrict__ ptrA){
  int b = blockIdx.x, t = threadIdx.x;
  int base = b * 1024 + t * 4;
  int v[4], tot = 0;
  #pragma unroll
  for (int k = 0; k < 4; k++){ int idx = base + k; v[k] = (idx < N_NODES) ? cnt[idx] : 0; tot += v[k]; }
  __shared__ int sc[256];
  sc[t] = tot; __syncthreads();
  for (int o = 1; o < 256; o <<= 1){
    int x = (t >= o) ? sc[t - o] : 0;
    __syncthreads(); sc[t] += x; __syncthreads();
  }
  int off = coff[b] + sc[t] - tot;
  #pragma unroll
  for (int k = 0; k < 4; k++){ int idx = base + k; if (idx < N_NODES) ptrA[idx] = off; off += v[k]; }
}

// fill CSR + accumulate srow (merged, one edge pass)
__global__ void k_fill(const int* __restrict__ row, const int* __restrict__ col,
                       const float* __restrict__ ew, const float* __restrict__ dinv,
                       const int* __restrict__ ptrA, int* __restrict__ fill, int2* __restrict__ adj,
                       float* __restrict__ srow){
  int e = blockIdx.x * 256 + threadIdx.x;
  if (e < NEDGE){
    int r = row[e], c = col[e];
    float w = dinv[r] * ew[e] * dinv[c];
    int pos = ptrA[c] + atomicAdd(&fill[c], 1);
    adj[pos] = make_int2(r, __float_as_int(w));
    atomicAdd(&srow[c], w);
  }
}

// per-block LDS histogram -> partials (no global atomics)
__global__ __launch_bounds__(256) void k_bhist(const int* __restrict__ batch, int* __restrict__ bpart){
  __shared__ int loc[128];
  int t = threadIdx.x;
  if (t < 128) loc[t] = 0;
  __syncthreads();
  int i = blockIdx.x * 256 + t;
  if (i < N_NODES) atomicAdd(&loc[batch[i]], 1);
  __syncthreads();
  if (t < 128) bpart[blockIdx.x * 128 + t] = loc[t];
}

__global__ __launch_bounds__(128) void k_bscan(const int* __restrict__ bpart, int* __restrict__ gptr){
  int t = threadIdx.x;
  int v = 0;
  for (int p = 0; p < 391; p++) v += bpart[p * 128 + t];
  __shared__ int s[128];
  s[t] = v; __syncthreads();
  for (int o = 1; o < 128; o <<= 1){
    int x = (t >= o) ? s[t - o] : 0;
    __syncthreads(); s[t] += x; __syncthreads();
  }
  gptr[t + 1] = s[t];
  if (t == 0) gptr[0] = 0;
}

// ---------------- column stats of f32 x -> slotted atomic accumulate ----------------
__global__ __launch_bounds__(256) void k_statsx(const float* __restrict__ x, float* __restrict__ sums){
  int t = threadIdx.x, col = t & 127, half = t >> 7;
  int r0 = blockIdx.x * 512;
  int rend = min(r0 + 512, N_NODES);
  float s = 0.f, q = 0.f;
  for (int r = r0 + half; r < rend; r += 2){
    float v = x[(size_t)r * 128 + col];
    s += v; q += v * v;
  }
  __shared__ float ls[256], lq[256];
  ls[t] = s; lq[t] = q;
  __syncthreads();
  if (half == 0){
    int slot = (blockIdx.x & (NSLOT - 1)) * 256;
    atomicAdd(&sums[slot + col],       s + ls[t + 128]);
    atomicAdd(&sums[slot + 128 + col], q + lq[t + 128]);
  }
}

// ---------------- fold BN into GEMM weights (hi/lo split); sums = NSLOT x 256 slots ----------------
__global__ __launch_bounds__(256) void k_fold(const float* __restrict__ sums,
    const float* __restrict__ bw, const float* __restrict__ bb,
    const float* __restrict__ W, const float* __restrict__ bias,
    u16* __restrict__ Wh, u16* __restrict__ Wl, float* __restrict__ rb){
  __shared__ float scl[128], shf[128], redp[256], stot[256];
  int t = threadIdx.x;
  {
    float s = 0.f;
    #pragma unroll 4
    for (int sl = 0; sl < NSLOT; sl++) s += sums[sl * 256 + t];
    stot[t] = s;
  }
  __syncthreads();
  if (t < 128){
    float mu  = stot[t] * (1.f / N_NODES);
    float var = stot[128 + t] * (1.f / N_NODES) - mu * mu;
    float sc  = bw[t] * rsqrtf(var + EPS);
    scl[t] = sc; shf[t] = bb[t] - mu * sc;
  }
  __syncthreads();
  int j = t & 127, hf = (t >> 7) * 64;
  float acc = 0.f;
  for (int f0 = 0; f0 < 64; f0++){
    int f = hf + f0;
    float wv = W[f * 128 + j];
    acc += shf[f] * wv;
    float x = scl[f] * wv;
    u16 hh = f2bf(x);
    Wh[j * 128 + f] = hh;
    Wl[j * 128 + f] = f2bf(x - bf2f(hh));
  }
  redp[t] = acc;
  __syncthreads();
  if (t < 128){
    rb[t] = redp[t] + redp[t + 128];
    rb[128 + t] = bias[t];
  }
}

// ---------------- SpMM v2: 4 nodes/wave, 16 lanes x 16B per row, 4-deep unroll ----------------
__global__ __launch_bounds__(256) void k_spmm(const u16* __restrict__ h,
    const int* __restrict__ ptrA, const int2* __restrict__ adj,
    const float* __restrict__ dinv, float* __restrict__ z){
  int t = threadIdx.x;
  int sub = t & 15;
  int i = blockIdx.x * 16 + (t >> 4);
  if (i >= N_NODES) return;
  float di = dinv[i], sw = di * di;
  const u16* hp = h + sub * 8;
  float acc[8];
  {
    uint4 v = *(const uint4*)(hp + (size_t)i * 128);
    acc[0] = sw * __uint_as_float(v.x << 16);          acc[1] = sw * __uint_as_float(v.x & 0xffff0000u);
    acc[2] = sw * __uint_as_float(v.y << 16);          acc[3] = sw * __uint_as_float(v.y & 0xffff0000u);
    acc[4] = sw * __uint_as_float(v.z << 16);          acc[5] = sw * __uint_as_float(v.z & 0xffff0000u);
    acc[6] = sw * __uint_as_float(v.w << 16);          acc[7] = sw * __uint_as_float(v.w & 0xffff0000u);
  }
  int b = ptrA[i], e = ptrA[i + 1];
  int k = b;
  #define FMA8(V, W) \
    acc[0] += (W) * __uint_as_float((V).x << 16);          acc[1] += (W) * __uint_as_float((V).x & 0xffff0000u); \
    acc[2] += (W) * __uint_as_float((V).y << 16);          acc[3] += (W) * __uint_as_float((V).y & 0xffff0000u); \
    acc[4] += (W) * __uint_as_float((V).z << 16);          acc[5] += (W) * __uint_as_float((V).z & 0xffff0000u); \
    acc[6] += (W) * __uint_as_float((V).w << 16);          acc[7] += (W) * __uint_as_float((V).w & 0xffff0000u);
  for (; k + 4 <= e; k += 4){
    int2 a0 = adj[k], a1 = adj[k + 1], a2 = adj[k + 2], a3 = adj[k + 3];
    uint4 v0 = *(const uint4*)(hp + (size_t)a0.x * 128);
    uint4 v1 = *(const uint4*)(hp + (size_t)a1.x * 128);
    uint4 v2 = *(const uint4*)(hp + (size_t)a2.x * 128);
    uint4 v3 = *(const uint4*)(hp + (size_t)a3.x * 128);
    float w0 = __int_as_float(a0.y), w1 = __int_as_float(a1.y);
    float w2 = __int_as_float(a2.y), w3 = __int_as_float(a3.y);
    FMA8(v0, w0); FMA8(v1, w1); FMA8(v2, w2); FMA8(v3, w3);
  }
  for (; k < e; k++){
    int2 a0 = adj[k];
    uint4 v0 = *(const uint4*)(hp + (size_t)a0.x * 128);
    float w0 = __int_as_float(a0.y);
    FMA8(v0, w0);
  }
  #undef FMA8
  float* zp = z + (size_t)i * 128 + sub * 8;
  *(float4*)zp       = make_float4(acc[0], acc[1], acc[2], acc[3]);
  *(float4*)(zp + 4) = make_float4(acc[4], acc[5], acc[6], acc[7]);
}

// ---------------- GEMM: hout = relu(z @ W' + srow*r + bias), hi/lo bf16 MFMA; slotted stats ----------------
__global__ __launch_bounds__(256) void k_gemm(const float* __restrict__ z,
    const u16* __restrict__ Wh_g, const u16* __restrict__ Wl_g,
    const float* __restrict__ srow, const float* __restrict__ rb,
    u16* __restrict__ hout, float* __restrict__ sums_out){
  __shared__ alignas(16) u16 WL[32768];   // [0:16384) hi frags, [16384:32768) lo frags; 64 KB
  int t = threadIdx.x;
  for (int idx = t; idx < 2048; idx += 256){
    int lane_ = idx & 63, slot = idx >> 6;        // slot = nt*4 + ks
    int nt = slot >> 2, ks = slot & 3;
    int n_ = nt * 16 + (lane_ & 15);
    int kb = ks * 32 + (lane_ >> 4) * 8;
    *(uint4*)&WL[idx * 8]         = *(const uint4*)(Wh_g + n_ * 128 + kb);
    *(uint4*)&WL[16384 + idx * 8] = *(const uint4*)(Wl_g + n_ * 128 + kb);
  }
  __syncthreads();
  int wave = t >> 6, lane = t & 63, m = lane & 15, q = lane >> 4;
  int row0 = blockIdx.x * 64 + wave * 16;
  const float* zr = z + (size_t)(row0 + m) * 128;
  f32x4 acc[8];
  #pragma unroll
  for (int i = 0; i < 8; i++) acc[i] = f32x4{0.f, 0.f, 0.f, 0.f};
  #pragma unroll
  for (int ks = 0; ks < 4; ks++){
    float4 z0 = *(const float4*)(zr + ks * 32 + q * 8);
    float4 z1 = *(const float4*)(zr + ks * 32 + q * 8 + 4);
    float zz[8] = {z0.x, z0.y, z0.z, z0.w, z1.x, z1.y, z1.z, z1.w};
    bf16x8 ah, al;
    #pragma unroll
    for (int j = 0; j < 8; j++){
      u16 hh = f2bf(zz[j]);
      ah[j] = (short)hh;
      al[j] = (short)f2bf(zz[j] - bf2f(hh));
    }
    #pragma unroll
    for (int nt = 0; nt < 8; nt++){
      bf16x8 bh = *(const bf16x8*)&WL[((nt * 4 + ks) * 64 + lane) * 8];
      bf16x8 bl = *(const bf16x8*)&WL[16384 + ((nt * 4 + ks) * 64 + lane) * 8];
      acc[nt] = __builtin_amdgcn_mfma_f32_16x16x32_bf16(ah, bh, acc[nt], 0, 0, 0);
      acc[nt] = __builtin_amdgcn_mfma_f32_16x16x32_bf16(al, bh, acc[nt], 0, 0, 0);
      acc[nt] = __builtin_amdgcn_mfma_f32_16x16x32_bf16(ah, bl, acc[nt], 0, 0, 0);
    }
  }
  __syncthreads();                 // done with W frags; reuse LDS for stats
  float* sred = (float*)WL;        // 256 floats: [0:128) col sums, [128:256) col sumsq
  sred[t] = 0.f;
  __syncthreads();
  #pragma unroll
  for (int nt = 0; nt < 8; nt++){
    int colc = nt * 16 + m;
    float rv = rb[colc], bv = rb[128 + colc];
    float s = 0.f, qq = 0.f;
    #pragma unroll
    for (int r = 0; r < 4; r++){
      int rown = row0 + q * 4 + r;                // C/D: col=lane&15, row=quad*4+reg
      float v = acc[nt][r] + srow[rown] * rv + bv;
      v = fmaxf(v, 0.f);
      u16 sv = f2bf(v);
      hout[(size_t)rown * 128 + colc] = sv;
      if (rown < N_NODES){ float vv = bf2f(sv); s += vv; qq += vv * vv; }
    }
    atomicAdd(&sred[colc], s);
    atomicAdd(&sred[128 + colc], qq);
  }
  __syncthreads();
  atomicAdd(&sums_out[(blockIdx.x & (NSLOT - 1)) * 256 + t], sred[t]);
}

// ---------------- branch-4 elementwise: out = relu(bn(h)); slotted stats ----------------
__global__ __launch_bounds__(256) void k_normrelu(const u16* __restrict__ h, const float* __restrict__ sums,
    const float* __restrict__ bw, const float* __restrict__ bb, u16* __restrict__ o,
    float* __restrict__ sums_out){
  __shared__ float scl[128], shf[128], R[1024], stot[256];
  int t = threadIdx.x;
  {
    float s = 0.f;
    #pragma unroll 4
    for (int sl = 0; sl < NSLOT; sl++) s += sums[sl * 256 + t];
    stot[t] = s;
  }
  __syncthreads();
  if (t < 128){
    float mu  = stot[t] * (1.f / N_NODES);
    float var = stot[128 + t] * (1.f / N_NODES) - mu * mu;
    float sc  = bw[t] * rsqrtf(var + EPS);
    scl[t] = sc; shf[t] = bb[t] - mu * sc;
  }
  __syncthreads();
  int c0 = (t & 63) * 2;
  float sc0 = scl[c0], sh0 = shf[c0], sc1 = scl[c0 + 1], sh1 = shf[c0 + 1];
  float s0 = 0.f, q0 = 0.f, s1 = 0.f, q1 = 0.f;
  size_t base = (size_t)blockIdx.x * 4096 + t;
  #pragma unroll
  for (int it = 0; it < 16; it++){
    size_t idx = base + (size_t)it * 256;
    if (idx < (size_t)N_NODES * 64){
      u32 v = ((const u32*)h)[idx];
      float x0 = fmaxf(bf2f(v & 0xffffu) * sc0 + sh0, 0.f);
      float x1 = fmaxf(bf2f(v >> 16) * sc1 + sh1, 0.f);
      u16 r0 = f2bf(x0), r1 = f2bf(x1);
      ((u32*)o)[idx] = (u32)r0 | ((u32)r1 << 16);
      float y0 = bf2f(r0), y1 = bf2f(r1);
      s0 += y0; q0 += y0 * y0; s1 += y1; q1 += y1 * y1;
    }
  }
  R[t] = s0; R[256 + t] = q0; R[512 + t] = s1; R[768 + t] = q1;
  __syncthreads();
  if (t < 64){
    float S0 = 0.f, Q0 = 0.f, S1 = 0.f, Q1 = 0.f;
    #pragma unroll
    for (int g = 0; g < 4; g++){
      S0 += R[g * 64 + t];       Q0 += R[256 + g * 64 + t];
      S1 += R[512 + g * 64 + t]; Q1 += R[768 + g * 64 + t];
    }
    float* so = sums_out + (blockIdx.x & (NSLOT - 1)) * 256;
    atomicAdd(&so[2 * t], S0);
    atomicAdd(&so[2 * t + 1], S1);
    atomicAdd(&so[128 + 2 * t], Q0);
    atomicAdd(&so[128 + 2 * t + 1], Q1);
  }
}

// ---------------- global_add_pool ----------------
__global__ __launch_bounds__(128) void k_pool(const u16* __restrict__ h, const int* __restrict__ gptr,
                                              float* __restrict__ gdst){
  int g = blockIdx.x >> 3, s = blockIdx.x & 7, t = threadIdx.x;
  int b = gptr[g], e = gptr[g + 1];
  int len = e - b, per = (len + 7) >> 3;
  int r0 = b + s * per, r1 = min(r0 + per, e);
  float acc = 0.f;
  for (int r = r0; r < r1; r++) acc += bf2f(h[(size_t)r * 128 + t]);
  atomicAdd(&gdst[g * 128 + t], acc);
}

// ---------------- head v2: 8x8 register-tile FC, shfl-reduced classifier ----------------
__global__ __launch_bounds__(256) void k_head(const float* __restrict__ gbuf,
    const float* __restrict__ fcw, const float* __restrict__ fcb,
    const float* __restrict__ Wfc, const float* __restrict__ bfc,
    const float* __restrict__ bhw, const float* __restrict__ bhb,
    const float* __restrict__ Wcl, const float* __restrict__ bcl,
    float* __restrict__ out){
  __shared__ float GS[128 * 65];           // Gbn k-half staging (33 KB)
  __shared__ float ls[256], lq[256];
  __shared__ float scl[128], shf[128], scl2[128], shf2[128];
  __shared__ float sumT[128], sumQ[128];
  __shared__ float WclT[1280], Lrow[1280];
  int t = threadIdx.x, br = blockIdx.x;
  int slot = (br == 1) ? 1 : (br == 3 ? 3 : 0);   // branch3 == branch1 (slot 0)
  const float* G = gbuf + slot * 16384;
  { // stats of G
    int col = t & 127, hf2 = t >> 7;
    float s = 0.f, q = 0.f;
    for (int g = hf2 * 64; g < hf2 * 64 + 64; g++){ float v = G[g * 128 + col]; s += v; q += v * v; }
    ls[t] = s; lq[t] = q;
  }
  for (int idx = t; idx < 1280; idx += 256){     // WclT[cc][c] = Wcl[c][cc]
    int cc = idx >> 7, c = idx & 127;
    WclT[idx] = Wcl[c * 10 + cc];
  }
  if (t < 128){ sumT[t] = 0.f; sumQ[t] = 0.f; }
  __syncthreads();
  if (t < 128){
    float s = ls[t] + ls[t + 128], q = lq[t] + lq[t + 128];
    float mu = s * (1.f / 128), var = q * (1.f / 128) - mu * mu;
    float sc = fcw[t] * rsqrtf(var + EPS);
    scl[t] = sc; shf[t] = fcb[t] - mu * sc;
  }
  __syncthreads();
  int tr = t >> 4, tc = t & 15, r0 = tr * 8, c0 = tc * 8;
  float acc[8][8];
  #pragma unroll
  for (int a = 0; a < 8; a++)
    #pragma unroll
    for (int b = 0; b < 8; b++) acc[a][b] = 0.f;
  for (int kh = 0; kh < 2; kh++){
    for (int idx = t; idx < 8192; idx += 256){
      int r = idx >> 6, kk = idx & 63, f = kh * 64 + kk;
      GS[r * 65 + kk] = G[r * 128 + f] * scl[f] + shf[f];
    }
    __syncthreads();
    #pragma unroll 2
    for (int k = 0; k < 64; k++){
      float a[8];
      #pragma unroll
      for (int ri = 0; ri < 8; ri++) a[ri] = GS[(r0 + ri) * 65 + k];
      float4 b0 = *(const float4*)&Wfc[(kh * 64 + k) * 128 + c0];
      float4 b1 = *(const float4*)&Wfc[(kh * 64 + k) * 128 + c0 + 4];
      float bb[8] = {b0.x, b0.y, b0.z, b0.w, b1.x, b1.y, b1.z, b1.w};
      #pragma unroll
      for (int ri = 0; ri < 8; ri++)
        #pragma unroll
        for (int ci = 0; ci < 8; ci++) acc[ri][ci] += a[ri] * bb[ci];
    }
    __syncthreads();
  }
  // bias + relu + column stats for bn_hidden
  #pragma unroll
  for (int ci = 0; ci < 8; ci++){
    float bb = bfc[c0 + ci];
    float s = 0.f, q = 0.f;
    #pragma unroll
    for (int ri = 0; ri < 8; ri++){
      float v = fmaxf(acc[ri][ci] + bb, 0.f);
      acc[ri][ci] = v; s += v; q += v * v;
    }
    atomicAdd(&sumT[c0 + ci], s);
    atomicAdd(&sumQ[c0 + ci], q);
  }
  __syncthreads();
  if (t < 128){
    float mu = sumT[t] * (1.f / 128), var = sumQ[t] * (1.f / 128) - mu * mu;
    float sc = bhw[t] * rsqrtf(var + EPS);
    scl2[t] = sc; shf2[t] = bhb[t] - mu * sc;
  }
  __syncthreads();
  #pragma unroll
  for (int ci = 0; ci < 8; ci++){
    float sc = scl2[c0 + ci], sh = shf2[c0 + ci];
    #pragma unroll
    for (int ri = 0; ri < 8; ri++) acc[ri][ci] = acc[ri][ci] * sc + sh;
  }
  // classifier: per-thread partials over its 8 cols, shfl-reduce over tc
  #pragma unroll
  for (int ri = 0; ri < 8; ri++){
    float pl[10];
    #pragma unroll
    for (int cc = 0; cc < 10; cc++) pl[cc] = 0.f;
    #pragma unroll
    for (int ci = 0; ci < 8; ci++){
      float v = acc[ri][ci];
      #pragma unroll
      for (int cc = 0; cc < 10; cc++) pl[cc] += v * WclT[cc * 128 + c0 + ci];
    }
    #pragma unroll
    for (int msk = 1; msk < 16; msk <<= 1)
      #pragma unroll
      for (int cc = 0; cc < 10; cc++) pl[cc] += __shfl_xor(pl[cc], msk, 64);
    if (tc == 0)
      #pragma unroll
      for (int cc = 0; cc < 10; cc++) Lrow[(r0 + ri) * 10 + cc] = pl[cc];
  }
  __syncthreads();
  if (t < 128){
    float l[10];
    #pragma unroll
    for (int cc = 0; cc < 10; cc++) l[cc] = Lrow[t * 10 + cc] + bcl[cc];
    float m = l[0];
    #pragma unroll
    for (int cc = 1; cc < 10; cc++) m = fmaxf(m, l[cc]);
    float se = 0.f;
    #pragma unroll
    for (int cc = 0; cc < 10; cc++) se += expf(l[cc] - m);
    float lse = m + logf(se);
    #pragma unroll
    for (int cc = 0; cc < 10; cc++) out[br * 1280 + t * 10 + cc] = l[cc] - lse;
  }
}

extern "C" void kernel_launch(void* const* d_in, const int* in_sizes, int n_in,
                              void* d_out, int out_size, void* d_ws, size_t ws_size,
                              hipStream_t stream){
  const float* x    = (const float*)d_in[0];
  const int*  ei    = (const int*)d_in[1];      // [2,E]: rows then cols
  const int*  batch = (const int*)d_in[2];
  const float* ew   = (const float*)d_in[3];
  const float* bnfw = (const float*)d_in[4];
  const float* bnfb = (const float*)d_in[5];
  const float* cfW  = (const float*)d_in[6];
  const float* cfb  = (const float*)d_in[7];
  const float* bnsw = (const float*)d_in[8];
  const float* bnsb = (const float*)d_in[9];
  const float* cvW  = (const float*)d_in[10];
  const float* cvb  = (const float*)d_in[11];
  const float* fcw  = (const float*)d_in[12];
  const float* fcb  = (const float*)d_in[13];
  const float* Wfc  = (const float*)d_in[14];
  const float* bfc  = (const float*)d_in[15];
  const float* bhw  = (const float*)d_in[16];
  const float* bhb  = (const float*)d_in[17];
  const float* Wcl  = (const float*)d_in[18];
  const float* bcl  = (const float*)d_in[19];
  float* out = (float*)d_out;

  char* p = (char*)d_ws;
  auto carve = [&](size_t bytes)->void*{ void* r = (void*)p; p += (bytes + 255) & ~(size_t)255; return r; };
  float* deg  = (float*)carve((size_t)NPAD * 4);
  float* dinv = (float*)carve((size_t)NPAD * 4);
  float* srow = (float*)carve((size_t)NPAD * 4);
  int*   cnt  = (int*)carve((size_t)NPAD * 4);
  int*   fill = (int*)carve((size_t)NPAD * 4);
  int*   ptrA = (int*)carve((size_t)(NPAD + 1) * 4);
  int*   bpart= (int*)carve((size_t)391 * 128 * 4);
  int*   csum = (int*)carve(512);
  int*   coff = (int*)carve(512);
  int*   gptr = (int*)carve(1024);
  float* S    = (float*)carve((size_t)13 * NSLOT * 1024);   // 13 steps x NSLOT x 256 floats
  float* rb   = (float*)carve(1024);
  u16*   Wh   = (u16*)carve(128 * 128 * 2);
  u16*   Wl   = (u16*)carve(128 * 128 * 2);
  float* gbuf = (float*)carve(4 * 128 * 128 * 4);
  float* z    = (float*)carve((size_t)NPAD * 128 * 4);
  u16*   B0   = (u16*)carve((size_t)NPAD * 256);
  u16*   B1   = (u16*)carve((size_t)NPAD * 256);
  u16*   B2   = (u16*)carve((size_t)NPAD * 256);
  u16*   B3   = (u16*)carve((size_t)NPAD * 256);
  int2*  adj  = (int2*)carve((size_t)NEDGE * 8);
  u16*   Xb   = B3;   // bf16 x staging; B3's first real write (d2) is after layer-0 spmm consumes Xb
  auto Sb = [&](int i){ return S + (size_t)i * NSLOT * 256; };

  (void)hipMemsetAsync(S, 0, (size_t)13 * NSLOT * 1024, stream);

  // preprocessing: degrees, norms, CSR, group offsets
  k_init<<<392, 256, 0, stream>>>(deg, cnt, fill, gbuf);
  k_deg<<<3125, 256, 0, stream>>>(ei + NEDGE, ew, deg, cnt);
  k_dinv<<<391, 256, 0, stream>>>(deg, dinv, srow);
  k_chunksum<<<98, 256, 0, stream>>>(cnt, csum);
  k_chunkscan<<<1, 128, 0, stream>>>(csum, coff, ptrA);
  k_scan2<<<98, 256, 0, stream>>>(cnt, coff, ptrA);
  k_fill<<<3125, 256, 0, stream>>>(ei, ei + NEDGE, ew, dinv, ptrA, fill, adj, srow);
  k_bhist<<<391, 256, 0, stream>>>(batch, bpart);
  k_bscan<<<1, 128, 0, stream>>>(bpart, gptr);
  k_cvt<<<25000, 256, 0, stream>>>(x, (u32*)Xb);
  k_statsx<<<196, 256, 0, stream>>>(x, Sb(0));

  auto spmm = [&](const u16* hin){ k_spmm<<<6250, 256, 0, stream>>>(hin, ptrA, adj, dinv, z); };
  auto conv = [&](const float* Sin, const float* bw, const float* bb,
                  const float* W, const float* bias, u16* hout, float* Sout){
    k_fold<<<1, 256, 0, stream>>>(Sin, bw, bb, W, bias, Wh, Wl, rb);
    k_gemm<<<NBLK, 256, 0, stream>>>(z, Wh, Wl, srow, rb, hout, Sout);
  };

  // layer 0: h_init = relu(conv(bn_feat(x)))
  spmm(Xb);
  conv(Sb(0), bnfw, bnfb, cfW, cfb, B0, Sb(1));            // B0 = h_init; S1 = stats(h_init)
  // a1 = step(h_init, bn0/W0)  (== branch2 c1)
  spmm(B0);
  conv(Sb(1), bnsw, bnsb, cvW, cvb, B1, Sb(2));            // B1 = a1; S2 = stats(a1)
  // branch 4: d1,d2,d3 (d1 uses stats(h_init))
  k_normrelu<<<NBLK, 256, 0, stream>>>(B0, Sb(1), bnsw,       bnsb,       B2, Sb(3));   // d1 -> B2
  k_normrelu<<<NBLK, 256, 0, stream>>>(B2, Sb(3), bnsw + 128, bnsb + 128, B3, Sb(4));   // d2 -> B3
  k_normrelu<<<NBLK, 256, 0, stream>>>(B3, Sb(4), bnsw + 256, bnsb + 256, B2, Sb(12));  // d3 -> B2
  k_pool<<<1024, 128, 0, stream>>>(B2, gptr, gbuf + 3 * 16384);
  // z = S@a1 serves a2 AND c2
  spmm(B1);
  conv(Sb(2), bnsw + 128, bnsb + 128, cvW + 16384, cvb + 128, B3, Sb(5));  // a2 -> B3; S5 = stats(a2)
  conv(Sb(2), bnsw, bnsb, cvW, cvb, B2, Sb(6));                            // c2 -> B2; S6 = stats(c2)
  // a3 = step(a2, bn2/W2) -> branches 1 & 3
  spmm(B3);
  conv(Sb(5), bnsw + 256, bnsb + 256, cvW + 32768, cvb + 256, B0, Sb(10)); // a3 -> B0
  k_pool<<<1024, 128, 0, stream>>>(B0, gptr, gbuf);
  // c3 = step(c2, bn1/W1)
  spmm(B2);
  conv(Sb(6), bnsw + 128, bnsb + 128, cvW + 16384, cvb + 128, B1, Sb(7));  // c3 -> B1
  // c4 = step(c3, bn1/W1)
  spmm(B1);
  conv(Sb(7), bnsw + 128, bnsb + 128, cvW + 16384, cvb + 128, B2, Sb(8));  // c4 -> B2
  // c5 = step(c4, bn2/W2)
  spmm(B2);
  conv(Sb(8), bnsw + 256, bnsb + 256, cvW + 32768, cvb + 256, B1, Sb(9));  // c5 -> B1
  // c6 = step(c5, bn2/W2) -> branch 2
  spmm(B1);
  conv(Sb(9), bnsw + 256, bnsb + 256, cvW + 32768, cvb + 256, B3, Sb(11)); // c6 -> B3
  k_pool<<<1024, 128, 0, stream>>>(B3, gptr, gbuf + 16384);

  k_head<<<4, 256, 0, stream>>>(gbuf, fcw, fcb, Wfc, bfc, bhw, bhb, Wcl, bcl, out);
}

// Round 8
// 1518.541 us; speedup vs baseline: 3.8661x; 1.1212x over previous
//
#include <hip/hip_runtime.h>

#define N_NODES 100000
#define NPAD    100032      // multiple of 64 for unguarded GEMM tiles
#define NBLK    1563        // NPAD/64
#define NEDGE   800000
#define NGRP    128
#define NSLOT   32          // mirrored stat-accumulator slots (atomic contention /32)
#define EPS     1e-5f

typedef unsigned int   u32;
typedef unsigned short u16;
typedef short bf16x8 __attribute__((ext_vector_type(8)));
typedef float f32x4  __attribute__((ext_vector_type(4)));

__device__ __forceinline__ float bf2f(u32 u){ return __uint_as_float(u << 16); }
__device__ __forceinline__ u16 f2bf(float f){
  u32 x = __float_as_uint(f);
  x += 0x7fffu + ((x >> 16) & 1u);      // round-to-nearest-even
  return (u16)(x >> 16);
}

// ---------------- preprocessing ----------------
__global__ void k_init(float* deg, int* cnt, int* fill, float* gbuf){
  int i = blockIdx.x * 256 + threadIdx.x;
  if (i < NPAD){ deg[i] = 1.0f; cnt[i] = 0; fill[i] = 0; }   // deg starts at 1 (self-loop)
  if (i < 4 * NGRP * 128) gbuf[i] = 0.f;
}

__global__ void k_deg(const int* __restrict__ col, const float* __restrict__ ew,
                      float* __restrict__ deg, int* __restrict__ cnt){
  int e = blockIdx.x * 256 + threadIdx.x;
  if (e < NEDGE){
    int c = col[e];
    atomicAdd(&deg[c], ew[e]);
    atomicAdd(&cnt[c], 1);
  }
}

__global__ void k_dinv(const float* __restrict__ deg, float* __restrict__ dinv, float* __restrict__ srow){
  int i = blockIdx.x * 256 + threadIdx.x;
  if (i < N_NODES){
    float d = deg[i];
    float v = d > 0.f ? rsqrtf(fmaxf(d, EPS)) : 0.f;
    dinv[i] = v; srow[i] = v * v;       // srow starts with self-loop norm
  }
}

__global__ __launch_bounds__(256) void k_chunksum(const int* __restrict__ cnt, int* __restrict__ csum){
  int b = blockIdx.x, t = threadIdx.x;
  int s = 0;
  for (int i = t; i < 1024; i += 256){ int idx = b * 1024 + i; if (idx < N_NODES) s += cnt[idx]; }
  __shared__ int red[256];
  red[t] = s; __syncthreads();
  for (int o = 128; o > 0; o >>= 1){ if (t < o) red[t] += red[t + o]; __syncthreads(); }
  if (t == 0) csum[b] = red[0];
}

__global__ __launch_bounds__(128) void k_chunkscan(const int* __restrict__ csum, int* __restrict__ coff,
                                                   int* __restrict__ ptrA){
  int t = threadIdx.x;
  __shared__ int s[128];
  int v = (t < 98) ? csum[t] : 0;
  s[t] = v; __syncthreads();
  for (int o = 1; o < 128; o <<= 1){
    int x = (t >= o) ? s[t - o] : 0;
    __syncthreads(); s[t] += x; __syncthreads();
  }
  if (t < 98) coff[t] = s[t] - v;       // exclusive chunk offsets
  if (t == 0) ptrA[N_NODES] = NEDGE;
}

__global__ __launch_bounds__(256) void k_scan2(const int* __restrict__ cnt, const int* __restrict__ coff,
                                               int* __restrict__ ptrA){
  int b = blockIdx.x, t = threadIdx.x;
  int base = b * 1024 + t * 4;
  int v[4], tot = 0;
  #pragma unroll
  for (int k = 0; k < 4; k++){ int idx = base + k; v[k] = (idx < N_NODES) ? cnt[idx] : 0; tot += v[k]; }
  __shared__ int sc[256];
  sc[t] = tot; __syncthreads();
  for (int o = 1; o < 256; o <<= 1){
    int x = (t >= o) ? sc[t - o] : 0;
    __syncthreads(); sc[t] += x; __syncthreads();
  }
  int off = coff[b] + sc[t] - tot;
  #pragma unroll
  for (int k = 0; k < 4; k++){ int idx = base + k; if (idx < N_NODES) ptrA[idx] = off; off += v[k]; }
}

// fill CSR + accumulate srow (merged, one edge pass)
__global__ void k_fill(const int* __restrict__ row, const int* __restrict__ col,
                       const float* __restrict__ ew, const float* __restrict__ dinv,
                       const int* __restrict__ ptrA, int* __restrict__ fill, int2* __restrict__ adj,
                       float* __restrict__ srow){
  int e = blockIdx.x * 256 + threadIdx.x;
  if (e < NEDGE){
    int r = row[e], c = col[e];
    float w = dinv[r] * ew[e] * dinv[c];
    int pos = ptrA[c] + atomicAdd(&fill[c], 1);
    adj[pos] = make_int2(r, __float_as_int(w));
    atomicAdd(&srow[c], w);
  }
}

// per-block LDS histogram -> partials (no global atomics)
__global__ __launch_bounds__(256) void k_bhist(const int* __restrict__ batch, int* __restrict__ bpart){
  __shared__ int loc[128];
  int t = threadIdx.x;
  if (t < 128) loc[t] = 0;
  __syncthreads();
  int i = blockIdx.x * 256 + t;
  if (i < N_NODES) atomicAdd(&loc[batch[i]], 1);
  __syncthreads();
  if (t < 128) bpart[blockIdx.x * 128 + t] = loc[t];
}

__global__ __launch_bounds__(128) void k_bscan(const int* __restrict__ bpart, int* __restrict__ gptr){
  int t = threadIdx.x;
  int v = 0;
  for (int p = 0; p < 391; p++) v += bpart[p * 128 + t];
  __shared__ int s[128];
  s[t] = v; __syncthreads();
  for (int o = 1; o < 128; o <<= 1){
    int x = (t >= o) ? s[t - o] : 0;
    __syncthreads(); s[t] += x; __syncthreads();
  }
  gptr[t + 1] = s[t];
  if (t == 0) gptr[0] = 0;
}

// ---------------- x (f32) -> bf16 staging + column stats (fused, one pass) ----------------
__global__ __launch_bounds__(256) void k_cvtstats(const float* __restrict__ x, u32* __restrict__ dst,
                                                  float* __restrict__ sums_out){
  __shared__ float R[1024];
  int t = threadIdx.x;
  float s0 = 0.f, q0 = 0.f, s1 = 0.f, q1 = 0.f;
  size_t base = (size_t)blockIdx.x * 4096 + t;
  #pragma unroll
  for (int it = 0; it < 16; it++){
    size_t idx = base + (size_t)it * 256;
    if (idx < (size_t)N_NODES * 64){
      float2 v = ((const float2*)x)[idx];
      dst[idx] = (u32)f2bf(v.x) | ((u32)f2bf(v.y) << 16);
      s0 += v.x; q0 += v.x * v.x; s1 += v.y; q1 += v.y * v.y;
    }
  }
  R[t] = s0; R[256 + t] = q0; R[512 + t] = s1; R[768 + t] = q1;
  __syncthreads();
  if (t < 64){
    float S0 = 0.f, Q0 = 0.f, S1 = 0.f, Q1 = 0.f;
    #pragma unroll
    for (int g = 0; g < 4; g++){
      S0 += R[g * 64 + t];       Q0 += R[256 + g * 64 + t];
      S1 += R[512 + g * 64 + t]; Q1 += R[768 + g * 64 + t];
    }
    float* so = sums_out + (blockIdx.x & (NSLOT - 1)) * 256;
    atomicAdd(&so[2 * t], S0);
    atomicAdd(&so[2 * t + 1], S1);
    atomicAdd(&so[128 + 2 * t], Q0);
    atomicAdd(&so[128 + 2 * t + 1], Q1);
  }
}

// ---------------- shared prologue macro: BN-fold W into fragment-ordered hi/lo LDS + rank-one ----------------
// Uses: sums (NSLOT x 256 slots), bw, bb, W (f32 [128][128]); fills WL (hi/lo frags), scl/shf, rbs.
#define FOLD_PROLOGUE()                                                        \
  {                                                                            \
    float s = 0.f;                                                             \
    _Pragma("unroll 4")                                                        \
    for (int sl = 0; sl < NSLOT; sl++) s += sums[sl * 256 + t];                \
    stot[t] = s;                                                               \
  }                                                                            \
  if (t < 128) rbs[t] = 0.f;                                                   \
  __syncthreads();                                                             \
  if (t < 128){                                                                \
    float mu  = stot[t] * (1.f / N_NODES);                                     \
    float var = stot[128 + t] * (1.f / N_NODES) - mu * mu;                     \
    float sc  = bw[t] * rsqrtf(var + EPS);                                     \
    scl[t] = sc; shf[t] = bb[t] - mu * sc;                                     \
  }                                                                            \
  __syncthreads();                                                             \
  _Pragma("unroll")                                                            \
  for (int s4 = 0; s4 < 8; s4++){                                              \
    int idx = s4 * 256 + t;                                                    \
    int lane_ = idx & 63, sl = idx >> 6;                                       \
    int nt_ = sl >> 2, ks_ = sl & 3;                                           \
    int n_ = nt_ * 16 + (lane_ & 15);                                          \
    int kb = ks_ * 32 + (lane_ >> 4) * 8;                                      \
    float rp = 0.f;                                                            \
    u16 hi8[8], lo8[8];                                                        \
    _Pragma("unroll")                                                          \
    for (int j = 0; j < 8; j++){                                               \
      float wv = W[(kb + j) * 128 + n_];                                       \
      rp += shf[kb + j] * wv;                                                  \
      float xv = scl[kb + j] * wv;                                             \
      u16 hh = f2bf(xv);                                                       \
      hi8[j] = hh; lo8[j] = f2bf(xv - bf2f(hh));                               \
    }                                                                          \
    uint4 ph, pl;                                                              \
    ph.x = (u32)hi8[0] | ((u32)hi8[1] << 16); ph.y = (u32)hi8[2] | ((u32)hi8[3] << 16); \
    ph.z = (u32)hi8[4] | ((u32)hi8[5] << 16); ph.w = (u32)hi8[6] | ((u32)hi8[7] << 16); \
    pl.x = (u32)lo8[0] | ((u32)lo8[1] << 16); pl.y = (u32)lo8[2] | ((u32)lo8[3] << 16); \
    pl.z = (u32)lo8[4] | ((u32)lo8[5] << 16); pl.w = (u32)lo8[6] | ((u32)lo8[7] << 16); \
    *(uint4*)&WL[idx * 8]         = ph;                                        \
    *(uint4*)&WL[16384 + idx * 8] = pl;                                        \
    atomicAdd(&rbs[n_], rp);                                                   \
  }

// ---------------- shared epilogue macro: bias + rank-one + relu + store + slotted stats ----------------
#define CONV_EPILOGUE()                                                        \
  __syncthreads();                                                             \
  { float* sred = (float*)WL;                                                  \
    sred[t] = 0.f;                                                             \
    __syncthreads();                                                           \
    _Pragma("unroll")                                                          \
    for (int nt = 0; nt < 8; nt++){                                            \
      int colc = nt * 16 + m;                                                  \
      float rv = rbs[colc], bv = bias[colc];                                   \
      float s = 0.f, qq = 0.f;                                                 \
      _Pragma("unroll")                                                        \
      for (int r = 0; r < 4; r++){                                             \
        int rown = row0 + q * 4 + r;                                           \
        float v = C[nt][r] + srow[rown] * rv + bv;                             \
        v = fmaxf(v, 0.f);                                                     \
        u16 sv = f2bf(v);                                                      \
        hout[(size_t)rown * 128 + colc] = sv;                                  \
        if (rown < N_NODES){ float vv = bf2f(sv); s += vv; qq += vv * vv; }    \
      }                                                                        \
      atomicAdd(&sred[colc], s);                                               \
      atomicAdd(&sred[128 + colc], qq);                                        \
    }                                                                          \
    __syncthreads();                                                           \
    atomicAdd(&sums_out[(blockIdx.x & (NSLOT - 1)) * 256 + t], sred[t]);       \
  }

// ---------------- fused conv: fold + gather(S@h into A-frag registers) + MFMA + stats ----------------
__global__ __launch_bounds__(256) void k_conv(
    const u16* __restrict__ h, const int* __restrict__ ptrA, const int2* __restrict__ adj,
    const float* __restrict__ dinv, const float* __restrict__ srow,
    const float* __restrict__ sums, const float* __restrict__ bw, const float* __restrict__ bb,
    const float* __restrict__ W, const float* __restrict__ bias,
    u16* __restrict__ hout, float* __restrict__ sums_out){
  __shared__ alignas(16) u16 WL[32768];
  __shared__ float stot[256], scl[128], shf[128], rbs[128];
  int t = threadIdx.x;
  FOLD_PROLOGUE()
  // gather phase: lane (m,q) owns row i = row0+m, cols {ks*32 + q*8 + j}
  int wave = t >> 6, lane = t & 63, m = lane & 15, q = lane >> 4;
  int row0 = blockIdx.x * 64 + wave * 16;
  int i = row0 + m;
  float acc[4][8];
  #pragma unroll
  for (int ks = 0; ks < 4; ks++)
    #pragma unroll
    for (int j = 0; j < 8; j++) acc[ks][j] = 0.f;
  if (i < N_NODES){
    const u16* hq = h + q * 8;
    float di = dinv[i], sw = di * di;
    #pragma unroll
    for (int ks = 0; ks < 4; ks++){
      uint4 v = *(const uint4*)(hq + (size_t)i * 128 + ks * 32);
      acc[ks][0] = sw * __uint_as_float(v.x << 16); acc[ks][1] = sw * __uint_as_float(v.x & 0xffff0000u);
      acc[ks][2] = sw * __uint_as_float(v.y << 16); acc[ks][3] = sw * __uint_as_float(v.y & 0xffff0000u);
      acc[ks][4] = sw * __uint_as_float(v.z << 16); acc[ks][5] = sw * __uint_as_float(v.z & 0xffff0000u);
      acc[ks][6] = sw * __uint_as_float(v.w << 16); acc[ks][7] = sw * __uint_as_float(v.w & 0xffff0000u);
    }
    #define FMA_KS(KS, V, WT) \
      acc[KS][0] += (WT) * __uint_as_float((V).x << 16); acc[KS][1] += (WT) * __uint_as_float((V).x & 0xffff0000u); \
      acc[KS][2] += (WT) * __uint_as_float((V).y << 16); acc[KS][3] += (WT) * __uint_as_float((V).y & 0xffff0000u); \
      acc[KS][4] += (WT) * __uint_as_float((V).z << 16); acc[KS][5] += (WT) * __uint_as_float((V).z & 0xffff0000u); \
      acc[KS][6] += (WT) * __uint_as_float((V).w << 16); acc[KS][7] += (WT) * __uint_as_float((V).w & 0xffff0000u);
    int b = ptrA[i], e = ptrA[i + 1];
    int k = b;
    for (; k + 2 <= e; k += 2){
      int2 a0 = adj[k], a1 = adj[k + 1];
      const u16* r0p = hq + (size_t)a0.x * 128;
      const u16* r1p = hq + (size_t)a1.x * 128;
      uint4 u0 = *(const uint4*)(r0p);
      uint4 u1 = *(const uint4*)(r0p + 32);
      uint4 u2 = *(const uint4*)(r0p + 64);
      uint4 u3 = *(const uint4*)(r0p + 96);
      uint4 w0 = *(const uint4*)(r1p);
      uint4 w1 = *(const uint4*)(r1p + 32);
      uint4 w2 = *(const uint4*)(r1p + 64);
      uint4 w3 = *(const uint4*)(r1p + 96);
      float f0 = __int_as_float(a0.y), f1 = __int_as_float(a1.y);
      FMA_KS(0, u0, f0) FMA_KS(1, u1, f0) FMA_KS(2, u2, f0) FMA_KS(3, u3, f0)
      FMA_KS(0, w0, f1) FMA_KS(1, w1, f1) FMA_KS(2, w2, f1) FMA_KS(3, w3, f1)
    }
    for (; k < e; k++){
      int2 a0 = adj[k];
      const u16* r0p = hq + (size_t)a0.x * 128;
      uint4 u0 = *(const uint4*)(r0p);
      uint4 u1 = *(const uint4*)(r0p + 32);
      uint4 u2 = *(const uint4*)(r0p + 64);
      uint4 u3 = *(const uint4*)(r0p + 96);
      float f0 = __int_as_float(a0.y);
      FMA_KS(0, u0, f0) FMA_KS(1, u1, f0) FMA_KS(2, u2, f0) FMA_KS(3, u3, f0)
    }
    #undef FMA_KS
  }
  __syncthreads();           // WL frags ready; gather done
  f32x4 C[8];
  #pragma unroll
  for (int nt = 0; nt < 8; nt++) C[nt] = f32x4{0.f, 0.f, 0.f, 0.f};
  #pragma unroll
  for (int ks = 0; ks < 4; ks++){
    bf16x8 ah, al;
    #pragma unroll
    for (int j = 0; j < 8; j++){
      u16 hh = f2bf(acc[ks][j]);
      ah[j] = (short)hh;
      al[j] = (short)f2bf(acc[ks][j] - bf2f(hh));
    }
    #pragma unroll
    for (int nt = 0; nt < 8; nt++){
      bf16x8 bh = *(const bf16x8*)&WL[((nt * 4 + ks) * 64 + lane) * 8];
      bf16x8 bl = *(const bf16x8*)&WL[16384 + ((nt * 4 + ks) * 64 + lane) * 8];
      C[nt] = __builtin_amdgcn_mfma_f32_16x16x32_bf16(ah, bh, C[nt], 0, 0, 0);
      C[nt] = __builtin_amdgcn_mfma_f32_16x16x32_bf16(al, bh, C[nt], 0, 0, 0);
      C[nt] = __builtin_amdgcn_mfma_f32_16x16x32_bf16(ah, bl, C[nt], 0, 0, 0);
    }
  }
  CONV_EPILOGUE()
}

// ---------------- z-reading GEMM with fold prologue (for the shared-z a2/c2 pair) ----------------
__global__ __launch_bounds__(256) void k_gemmz(
    const float* __restrict__ z, const float* __restrict__ srow,
    const float* __restrict__ sums, const float* __restrict__ bw, const float* __restrict__ bb,
    const float* __restrict__ W, const float* __restrict__ bias,
    u16* __restrict__ hout, float* __restrict__ sums_out){
  __shared__ alignas(16) u16 WL[32768];
  __shared__ float stot[256], scl[128], shf[128], rbs[128];
  int t = threadIdx.x;
  FOLD_PROLOGUE()
  __syncthreads();
  int wave = t >> 6, lane = t & 63, m = lane & 15, q = lane >> 4;
  int row0 = blockIdx.x * 64 + wave * 16;
  const float* zr = z + (size_t)(row0 + m) * 128;
  f32x4 C[8];
  #pragma unroll
  for (int nt = 0; nt < 8; nt++) C[nt] = f32x4{0.f, 0.f, 0.f, 0.f};
  #pragma unroll
  for (int ks = 0; ks < 4; ks++){
    float4 z0 = *(const float4*)(zr + ks * 32 + q * 8);
    float4 z1 = *(const float4*)(zr + ks * 32 + q * 8 + 4);
    float zz[8] = {z0.x, z0.y, z0.z, z0.w, z1.x, z1.y, z1.z, z1.w};
    bf16x8 ah, al;
    #pragma unroll
    for (int j = 0; j < 8; j++){
      u16 hh = f2bf(zz[j]);
      ah[j] = (short)hh;
      al[j] = (short)f2bf(zz[j] - bf2f(hh));
    }
    #pragma unroll
    for (int nt = 0; nt < 8; nt++){
      bf16x8 bh = *(const bf16x8*)&WL[((nt * 4 + ks) * 64 + lane) * 8];
      bf16x8 bl = *(const bf16x8*)&WL[16384 + ((nt * 4 + ks) * 64 + lane) * 8];
      C[nt] = __builtin_amdgcn_mfma_f32_16x16x32_bf16(ah, bh, C[nt], 0, 0, 0);
      C[nt] = __builtin_amdgcn_mfma_f32_16x16x32_bf16(al, bh, C[nt], 0, 0, 0);
      C[nt] = __builtin_amdgcn_mfma_f32_16x16x32_bf16(ah, bl, C[nt], 0, 0, 0);
    }
  }
  CONV_EPILOGUE()
}

// ---------------- SpMM v2 (split path): 16 lanes x 16B per row ----------------
__global__ __launch_bounds__(256) void k_spmm(const u16* __restrict__ h,
    const int* __restrict__ ptrA, const int2* __restrict__ adj,
    const float* __restrict__ dinv, float* __restrict__ z){
  int t = threadIdx.x;
  int sub = t & 15;
  int i = blockIdx.x * 16 + (t >> 4);
  if (i >= N_NODES) return;
  float di = dinv[i], sw = di * di;
  const u16* hp = h + sub * 8;
  float acc[8];
  {
    uint4 v = *(const uint4*)(hp + (size_t)i * 128);
    acc[0] = sw * __uint_as_float(v.x << 16);          acc[1] = sw * __uint_as_float(v.x & 0xffff0000u);
    acc[2] = sw * __uint_as_float(v.y << 16);          acc[3] = sw * __uint_as_float(v.y & 0xffff0000u);
    acc[4] = sw * __uint_as_float(v.z << 16);          acc[5] = sw * __uint_as_float(v.z & 0xffff0000u);
    acc[6] = sw * __uint_as_float(v.w << 16);          acc[7] = sw * __uint_as_float(v.w & 0xffff0000u);
  }
  int b = ptrA[i], e = ptrA[i + 1];
  int k = b;
  #define FMA8(V, W) \
    acc[0] += (W) * __uint_as_float((V).x << 16);          acc[1] += (W) * __uint_as_float((V).x & 0xffff0000u); \
    acc[2] += (W) * __uint_as_float((V).y << 16);          acc[3] += (W) * __uint_as_float((V).y & 0xffff0000u); \
    acc[4] += (W) * __uint_as_float((V).z << 16);          acc[5] += (W) * __uint_as_float((V).z & 0xffff0000u); \
    acc[6] += (W) * __uint_as_float((V).w << 16);          acc[7] += (W) * __uint_as_float((V).w & 0xffff0000u);
  for (; k + 4 <= e; k += 4){
    int2 a0 = adj[k], a1 = adj[k + 1], a2 = adj[k + 2], a3 = adj[k + 3];
    uint4 v0 = *(const uint4*)(hp + (size_t)a0.x * 128);
    uint4 v1 = *(const uint4*)(hp + (size_t)a1.x * 128);
    uint4 v2 = *(const uint4*)(hp + (size_t)a2.x * 128);
    uint4 v3 = *(const uint4*)(hp + (size_t)a3.x * 128);
    float w0 = __int_as_float(a0.y), w1 = __int_as_float(a1.y);
    float w2 = __int_as_float(a2.y), w3 = __int_as_float(a3.y);
    FMA8(v0, w0); FMA8(v1, w1); FMA8(v2, w2); FMA8(v3, w3);
  }
  for (; k < e; k++){
    int2 a0 = adj[k];
    uint4 v0 = *(const uint4*)(hp + (size_t)a0.x * 128);
    float w0 = __int_as_float(a0.y);
    FMA8(v0, w0);
  }
  #undef FMA8
  float* zp = z + (size_t)i * 128 + sub * 8;
  *(float4*)zp       = make_float4(acc[0], acc[1], acc[2], acc[3]);
  *(float4*)(zp + 4) = make_float4(acc[4], acc[5], acc[6], acc[7]);
}

// ---------------- branch-4 elementwise: out = relu(bn(h)); slotted stats ----------------
__global__ __launch_bounds__(256) void k_normrelu(const u16* __restrict__ h, const float* __restrict__ sums,
    const float* __restrict__ bw, const float* __restrict__ bb, u16* __restrict__ o,
    float* __restrict__ sums_out){
  __shared__ float scl[128], shf[128], R[1024], stot[256];
  int t = threadIdx.x;
  {
    float s = 0.f;
    #pragma unroll 4
    for (int sl = 0; sl < NSLOT; sl++) s += sums[sl * 256 + t];
    stot[t] = s;
  }
  __syncthreads();
  if (t < 128){
    float mu  = stot[t] * (1.f / N_NODES);
    float var = stot[128 + t] * (1.f / N_NODES) - mu * mu;
    float sc  = bw[t] * rsqrtf(var + EPS);
    scl[t] = sc; shf[t] = bb[t] - mu * sc;
  }
  __syncthreads();
  int c0 = (t & 63) * 2;
  float sc0 = scl[c0], sh0 = shf[c0], sc1 = scl[c0 + 1], sh1 = shf[c0 + 1];
  float s0 = 0.f, q0 = 0.f, s1 = 0.f, q1 = 0.f;
  size_t base = (size_t)blockIdx.x * 4096 + t;
  #pragma unroll
  for (int it = 0; it < 16; it++){
    size_t idx = base + (size_t)it * 256;
    if (idx < (size_t)N_NODES * 64){
      u32 v = ((const u32*)h)[idx];
      float x0 = fmaxf(bf2f(v & 0xffffu) * sc0 + sh0, 0.f);
      float x1 = fmaxf(bf2f(v >> 16) * sc1 + sh1, 0.f);
      u16 r0 = f2bf(x0), r1 = f2bf(x1);
      ((u32*)o)[idx] = (u32)r0 | ((u32)r1 << 16);
      float y0 = bf2f(r0), y1 = bf2f(r1);
      s0 += y0; q0 += y0 * y0; s1 += y1; q1 += y1 * y1;
    }
  }
  R[t] = s0; R[256 + t] = q0; R[512 + t] = s1; R[768 + t] = q1;
  __syncthreads();
  if (t < 64){
    float S0 = 0.f, Q0 = 0.f, S1 = 0.f, Q1 = 0.f;
    #pragma unroll
    for (int g = 0; g < 4; g++){
      S0 += R[g * 64 + t];       Q0 += R[256 + g * 64 + t];
      S1 += R[512 + g * 64 + t]; Q1 += R[768 + g * 64 + t];
    }
    float* so = sums_out + (blockIdx.x & (NSLOT - 1)) * 256;
    atomicAdd(&so[2 * t], S0);
    atomicAdd(&so[2 * t + 1], S1);
    atomicAdd(&so[128 + 2 * t], Q0);
    atomicAdd(&so[128 + 2 * t + 1], Q1);
  }
}

// ---------------- global_add_pool ----------------
__global__ __launch_bounds__(128) void k_pool(const u16* __restrict__ h, const int* __restrict__ gptr,
                                              float* __restrict__ gdst){
  int g = blockIdx.x >> 3, s = blockIdx.x & 7, t = threadIdx.x;
  int b = gptr[g], e = gptr[g + 1];
  int len = e - b, per = (len + 7) >> 3;
  int r0 = b + s * per, r1 = min(r0 + per, e);
  float acc = 0.f;
  for (int r = r0; r < r1; r++) acc += bf2f(h[(size_t)r * 128 + t]);
  atomicAdd(&gdst[g * 128 + t], acc);
}

// ---------------- head: 8x8 register-tile FC, shfl-reduced classifier ----------------
__global__ __launch_bounds__(256) void k_head(const float* __restrict__ gbuf,
    const float* __restrict__ fcw, const float* __restrict__ fcb,
    const float* __restrict__ Wfc, const float* __restrict__ bfc,
    const float* __restrict__ bhw, const float* __restrict__ bhb,
    const float* __restrict__ Wcl, const float* __restrict__ bcl,
    float* __restrict__ out){
  __shared__ float GS[128 * 65];           // Gbn k-half staging (33 KB)
  __shared__ float ls[256], lq[256];
  __shared__ float scl[128], shf[128], scl2[128], shf2[128];
  __shared__ float sumT[128], sumQ[128];
  __shared__ float WclT[1280], Lrow[1280];
  int t = threadIdx.x, br = blockIdx.x;
  int slot = (br == 1) ? 1 : (br == 3 ? 3 : 0);   // branch3 == branch1 (slot 0)
  const float* G = gbuf + slot * 16384;
  { // stats of G
    int col = t & 127, hf2 = t >> 7;
    float s = 0.f, q = 0.f;
    for (int g = hf2 * 64; g < hf2 * 64 + 64; g++){ float v = G[g * 128 + col]; s += v; q += v * v; }
    ls[t] = s; lq[t] = q;
  }
  for (int idx = t; idx < 1280; idx += 256){     // WclT[cc][c] = Wcl[c][cc]
    int cc = idx >> 7, c = idx & 127;
    WclT[idx] = Wcl[c * 10 + cc];
  }
  if (t < 128){ sumT[t] = 0.f; sumQ[t] = 0.f; }
  __syncthreads();
  if (t < 128){
    float s = ls[t] + ls[t + 128], q = lq[t] + lq[t + 128];
    float mu = s * (1.f / 128), var = q * (1.f / 128) - mu * mu;
    float sc = fcw[t] * rsqrtf(var + EPS);
    scl[t] = sc; shf[t] = fcb[t] - mu * sc;
  }
  __syncthreads();
  int tr = t >> 4, tc = t & 15, r0 = tr * 8, c0 = tc * 8;
  float acc[8][8];
  #pragma unroll
  for (int a = 0; a < 8; a++)
    #pragma unroll
    for (int b = 0; b < 8; b++) acc[a][b] = 0.f;
  for (int kh = 0; kh < 2; kh++){
    for (int idx = t; idx < 8192; idx += 256){
      int r = idx >> 6, kk = idx & 63, f = kh * 64 + kk;
      GS[r * 65 + kk] = G[r * 128 + f] * scl[f] + shf[f];
    }
    __syncthreads();
    #pragma unroll 2
    for (int k = 0; k < 64; k++){
      float a[8];
      #pragma unroll
      for (int ri = 0; ri < 8; ri++) a[ri] = GS[(r0 + ri) * 65 + k];
      float4 b0 = *(const float4*)&Wfc[(kh * 64 + k) * 128 + c0];
      float4 b1 = *(const float4*)&Wfc[(kh * 64 + k) * 128 + c0 + 4];
      float bb[8] = {b0.x, b0.y, b0.z, b0.w, b1.x, b1.y, b1.z, b1.w};
      #pragma unroll
      for (int ri = 0; ri < 8; ri++)
        #pragma unroll
        for (int ci = 0; ci < 8; ci++) acc[ri][ci] += a[ri] * bb[ci];
    }
    __syncthreads();
  }
  // bias + relu + column stats for bn_hidden
  #pragma unroll
  for (int ci = 0; ci < 8; ci++){
    float bb = bfc[c0 + ci];
    float s = 0.f, q = 0.f;
    #pragma unroll
    for (int ri = 0; ri < 8; ri++){
      float v = fmaxf(acc[ri][ci] + bb, 0.f);
      acc[ri][ci] = v; s += v; q += v * v;
    }
    atomicAdd(&sumT[c0 + ci], s);
    atomicAdd(&sumQ[c0 + ci], q);
  }
  __syncthreads();
  if (t < 128){
    float mu = sumT[t] * (1.f / 128), var = sumQ[t] * (1.f / 128) - mu * mu;
    float sc = bhw[t] * rsqrtf(var + EPS);
    scl2[t] = sc; shf2[t] = bhb[t] - mu * sc;
  }
  __syncthreads();
  #pragma unroll
  for (int ci = 0; ci < 8; ci++){
    float sc = scl2[c0 + ci], sh = shf2[c0 + ci];
    #pragma unroll
    for (int ri = 0; ri < 8; ri++) acc[ri][ci] = acc[ri][ci] * sc + sh;
  }
  // classifier: per-thread partials over its 8 cols, shfl-reduce over tc
  #pragma unroll
  for (int ri = 0; ri < 8; ri++){
    float pl[10];
    #pragma unroll
    for (int cc = 0; cc < 10; cc++) pl[cc] = 0.f;
    #pragma unroll
    for (int ci = 0; ci < 8; ci++){
      float v = acc[ri][ci];
      #pragma unroll
      for (int cc = 0; cc < 10; cc++) pl[cc] += v * WclT[cc * 128 + c0 + ci];
    }
    #pragma unroll
    for (int msk = 1; msk < 16; msk <<= 1)
      #pragma unroll
      for (int cc = 0; cc < 10; cc++) pl[cc] += __shfl_xor(pl[cc], msk, 64);
    if (tc == 0)
      #pragma unroll
      for (int cc = 0; cc < 10; cc++) Lrow[(r0 + ri) * 10 + cc] = pl[cc];
  }
  __syncthreads();
  if (t < 128){
    float l[10];
    #pragma unroll
    for (int cc = 0; cc < 10; cc++) l[cc] = Lrow[t * 10 + cc] + bcl[cc];
    float m = l[0];
    #pragma unroll
    for (int cc = 1; cc < 10; cc++) m = fmaxf(m, l[cc]);
    float se = 0.f;
    #pragma unroll
    for (int cc = 0; cc < 10; cc++) se += expf(l[cc] - m);
    float lse = m + logf(se);
    #pragma unroll
    for (int cc = 0; cc < 10; cc++) out[br * 1280 + t * 10 + cc] = l[cc] - lse;
  }
}

extern "C" void kernel_launch(void* const* d_in, const int* in_sizes, int n_in,
                              void* d_out, int out_size, void* d_ws, size_t ws_size,
                              hipStream_t stream){
  const float* x    = (const float*)d_in[0];
  const int*  ei    = (const int*)d_in[1];      // [2,E]: rows then cols
  const int*  batch = (const int*)d_in[2];
  const float* ew   = (const float*)d_in[3];
  const float* bnfw = (const float*)d_in[4];
  const float* bnfb = (const float*)d_in[5];
  const float* cfW  = (const float*)d_in[6];
  const float* cfb  = (const float*)d_in[7];
  const float* bnsw = (const float*)d_in[8];
  const float* bnsb = (const float*)d_in[9];
  const float* cvW  = (const float*)d_in[10];
  const float* cvb  = (const float*)d_in[11];
  const float* fcw  = (const float*)d_in[12];
  const float* fcb  = (const float*)d_in[13];
  const float* Wfc  = (const float*)d_in[14];
  const float* bfc  = (const float*)d_in[15];
  const float* bhw  = (const float*)d_in[16];
  const float* bhb  = (const float*)d_in[17];
  const float* Wcl  = (const float*)d_in[18];
  const float* bcl  = (const float*)d_in[19];
  float* out = (float*)d_out;

  char* p = (char*)d_ws;
  auto carve = [&](size_t bytes)->void*{ void* r = (void*)p; p += (bytes + 255) & ~(size_t)255; return r; };
  float* deg  = (float*)carve((size_t)NPAD * 4);
  float* dinv = (float*)carve((size_t)NPAD * 4);
  float* srow = (float*)carve((size_t)NPAD * 4);
  int*   cnt  = (int*)carve((size_t)NPAD * 4);
  int*   fill = (int*)carve((size_t)NPAD * 4);
  int*   ptrA = (int*)carve((size_t)(NPAD + 1) * 4);
  int*   bpart= (int*)carve((size_t)391 * 128 * 4);
  int*   csum = (int*)carve(512);
  int*   coff = (int*)carve(512);
  int*   gptr = (int*)carve(1024);
  float* S    = (float*)carve((size_t)13 * NSLOT * 1024);   // 13 steps x NSLOT x 256 floats
  float* gbuf = (float*)carve(4 * 128 * 128 * 4);
  float* z    = (float*)carve((size_t)NPAD * 128 * 4);
  u16*   B0   = (u16*)carve((size_t)NPAD * 256);
  u16*   B1   = (u16*)carve((size_t)NPAD * 256);
  u16*   B2   = (u16*)carve((size_t)NPAD * 256);
  u16*   B3   = (u16*)carve((size_t)NPAD * 256);
  int2*  adj  = (int2*)carve((size_t)NEDGE * 8);
  u16*   Xb   = B3;   // bf16 x staging; B3's first real write (d2) is after L0 conv consumes Xb
  auto Sb = [&](int i){ return S + (size_t)i * NSLOT * 256; };

  (void)hipMemsetAsync(S, 0, (size_t)13 * NSLOT * 1024, stream);

  // preprocessing: degrees, norms, CSR, group offsets
  k_init<<<392, 256, 0, stream>>>(deg, cnt, fill, gbuf);
  k_deg<<<3125, 256, 0, stream>>>(ei + NEDGE, ew, deg, cnt);
  k_dinv<<<391, 256, 0, stream>>>(deg, dinv, srow);
  k_chunksum<<<98, 256, 0, stream>>>(cnt, csum);
  k_chunkscan<<<1, 128, 0, stream>>>(csum, coff, ptrA);
  k_scan2<<<98, 256, 0, stream>>>(cnt, coff, ptrA);
  k_fill<<<3125, 256, 0, stream>>>(ei, ei + NEDGE, ew, dinv, ptrA, fill, adj, srow);
  k_bhist<<<391, 256, 0, stream>>>(batch, bpart);
  k_bscan<<<1, 128, 0, stream>>>(bpart, gptr);
  k_cvtstats<<<NBLK, 256, 0, stream>>>(x, (u32*)Xb, Sb(0));

  auto conv = [&](const u16* hin, const float* Sin, const float* bw, const float* bb,
                  const float* W, const float* bias, u16* hout, float* Sout){
    k_conv<<<NBLK, 256, 0, stream>>>(hin, ptrA, adj, dinv, srow, Sin, bw, bb, W, bias, hout, Sout);
  };
  auto gemmz = [&](const float* Sin, const float* bw, const float* bb,
                   const float* W, const float* bias, u16* hout, float* Sout){
    k_gemmz<<<NBLK, 256, 0, stream>>>(z, srow, Sin, bw, bb, W, bias, hout, Sout);
  };

  // L0: h_init = relu(conv(bn_feat(x)))
  conv(Xb, Sb(0), bnfw, bnfb, cfW, cfb, B0, Sb(1));                           // B0 = h_init
  // a1 = step(h_init, bn0/W0)  (== branch2 c1)
  conv(B0, Sb(1), bnsw, bnsb, cvW, cvb, B1, Sb(2));                           // B1 = a1
  // branch 4: d1,d2,d3 (d1 uses stats(h_init))
  k_normrelu<<<NBLK, 256, 0, stream>>>(B0, Sb(1), bnsw,       bnsb,       B2, Sb(3));   // d1 -> B2
  k_normrelu<<<NBLK, 256, 0, stream>>>(B2, Sb(3), bnsw + 128, bnsb + 128, B3, Sb(4));   // d2 -> B3
  k_normrelu<<<NBLK, 256, 0, stream>>>(B3, Sb(4), bnsw + 256, bnsb + 256, B2, Sb(12));  // d3 -> B2
  k_pool<<<1024, 128, 0, stream>>>(B2, gptr, gbuf + 3 * 16384);
  // shared z = S@a1 serves a2 AND c2 (split path)
  k_spmm<<<6250, 256, 0, stream>>>(B1, ptrA, adj, dinv, z);
  gemmz(Sb(2), bnsw + 128, bnsb + 128, cvW + 16384, cvb + 128, B3, Sb(5));    // a2 -> B3
  gemmz(Sb(2), bnsw,       bnsb,       cvW,         cvb,       B2, Sb(6));    // c2 -> B2
  // a3 = step(a2, bn2/W2) -> branches 1 & 3
  conv(B3, Sb(5), bnsw + 256, bnsb + 256, cvW + 32768, cvb + 256, B0, Sb(10)); // a3 -> B0
  k_pool<<<1024, 128, 0, stream>>>(B0, gptr, gbuf);
  // c3 = step(c2, bn1/W1)
  conv(B2, Sb(6), bnsw + 128, bnsb + 128, cvW + 16384, cvb + 128, B1, Sb(7));  // c3 -> B1
  // c4 = step(c3, bn1/W1)
  conv(B1, Sb(7), bnsw + 128, bnsb + 128, cvW + 16384, cvb + 128, B2, Sb(8));  // c4 -> B2
  // c5 = step(c4, bn2/W2)
  conv(B2, Sb(8), bnsw + 256, bnsb + 256, cvW + 32768, cvb + 256, B1, Sb(9));  // c5 -> B1
  // c6 = step(c5, bn2/W2) -> branch 2
  conv(B1, Sb(9), bnsw + 256, bnsb + 256, cvW + 32768, cvb + 256, B3, Sb(11)); // c6 -> B3
  k_pool<<<1024, 128, 0, stream>>>(B3, gptr, gbuf + 16384);

  k_head<<<4, 256, 0, stream>>>(gbuf, fcw, fcb, Wfc, bfc, bhw, bhb, Wcl, bcl, out);
}

// Round 9
// 1196.752 us; speedup vs baseline: 4.9057x; 1.2689x over previous
//
#include <hip/hip_runtime.h>

#define N_NODES 100000
#define NPAD    100032      // multiple of 64 for unguarded GEMM tiles
#define NBLK    1563        // NPAD/64
#define NEDGE   800000
#define NGRP    128
#define NSLOT   32          // mirrored stat-accumulator slots (atomic contention /32)
#define EPS     1e-5f

typedef unsigned int   u32;
typedef unsigned short u16;
typedef short bf16x8 __attribute__((ext_vector_type(8)));
typedef float f32x4  __attribute__((ext_vector_type(4)));

__device__ __forceinline__ float bf2f(u32 u){ return __uint_as_float(u << 16); }
__device__ __forceinline__ u16 f2bf(float f){
  u32 x = __float_as_uint(f);
  x += 0x7fffu + ((x >> 16) & 1u);      // round-to-nearest-even
  return (u16)(x >> 16);
}

// ---------------- preprocessing ----------------
__global__ void k_init(float* deg, int* cnt, int* fill, float* gbuf){
  int i = blockIdx.x * 256 + threadIdx.x;
  if (i < NPAD){ deg[i] = 1.0f; cnt[i] = 0; fill[i] = 0; }   // deg starts at 1 (self-loop)
  if (i < 4 * NGRP * 128) gbuf[i] = 0.f;
}

__global__ void k_deg(const int* __restrict__ col, const float* __restrict__ ew,
                      float* __restrict__ deg, int* __restrict__ cnt){
  int e = blockIdx.x * 256 + threadIdx.x;
  if (e < NEDGE){
    int c = col[e];
    atomicAdd(&deg[c], ew[e]);
    atomicAdd(&cnt[c], 1);
  }
}

__global__ void k_dinv(const float* __restrict__ deg, float* __restrict__ dinv, float* __restrict__ srow){
  int i = blockIdx.x * 256 + threadIdx.x;
  if (i < N_NODES){
    float d = deg[i];
    float v = d > 0.f ? rsqrtf(fmaxf(d, EPS)) : 0.f;
    dinv[i] = v; srow[i] = v * v;       // srow starts with self-loop norm
  }
}

__global__ __launch_bounds__(256) void k_chunksum(const int* __restrict__ cnt, int* __restrict__ csum){
  int b = blockIdx.x, t = threadIdx.x;
  int s = 0;
  for (int i = t; i < 1024; i += 256){ int idx = b * 1024 + i; if (idx < N_NODES) s += cnt[idx]; }
  __shared__ int red[256];
  red[t] = s; __syncthreads();
  for (int o = 128; o > 0; o >>= 1){ if (t < o) red[t] += red[t + o]; __syncthreads(); }
  if (t == 0) csum[b] = red[0];
}

__global__ __launch_bounds__(128) void k_chunkscan(const int* __restrict__ csum, int* __restrict__ coff,
                                                   int* __restrict__ ptrA){
  int t = threadIdx.x;
  __shared__ int s[128];
  int v = (t < 98) ? csum[t] : 0;
  s[t] = v; __syncthreads();
  for (int o = 1; o < 128; o <<= 1){
    int x = (t >= o) ? s[t - o] : 0;
    __syncthreads(); s[t] += x; __syncthreads();
  }
  if (t < 98) coff[t] = s[t] - v;       // exclusive chunk offsets
  if (t == 0) ptrA[N_NODES] = NEDGE;
}

__global__ __launch_bounds__(256) void k_scan2(const int* __restrict__ cnt, const int* __restrict__ coff,
                                               int* __restrict__ ptrA){
  int b = blockIdx.x, t = threadIdx.x;
  int base = b * 1024 + t * 4;
  int v[4], tot = 0;
  #pragma unroll
  for (int k = 0; k < 4; k++){ int idx = base + k; v[k] = (idx < N_NODES) ? cnt[idx] : 0; tot += v[k]; }
  __shared__ int sc[256];
  sc[t] = tot; __syncthreads();
  for (int o = 1; o < 256; o <<= 1){
    int x = (t >= o) ? sc[t - o] : 0;
    __syncthreads(); sc[t] += x; __syncthreads();
  }
  int off = coff[b] + sc[t] - tot;
  #pragma unroll
  for (int k = 0; k < 4; k++){ int idx = base + k; if (idx < N_NODES) ptrA[idx] = off; off += v[k]; }
}

// fill CSR + accumulate srow (merged, one edge pass)
__global__ void k_fill(const int* __restrict__ row, const int* __restrict__ col,
                       const float* __restrict__ ew, const float* __restrict__ dinv,
                       const int* __restrict__ ptrA, int* __restrict__ fill, int2* __restrict__ adj,
                       float* __restrict__ srow){
  int e = blockIdx.x * 256 + threadIdx.x;
  if (e < NEDGE){
    int r = row[e], c = col[e];
    float w = dinv[r] * ew[e] * dinv[c];
    int pos = ptrA[c] + atomicAdd(&fill[c], 1);
    adj[pos] = make_int2(r, __float_as_int(w));
    atomicAdd(&srow[c], w);
  }
}

// per-block LDS histogram -> partials (no global atomics)
__global__ __launch_bounds__(256) void k_bhist(const int* __restrict__ batch, int* __restrict__ bpart){
  __shared__ int loc[128];
  int t = threadIdx.x;
  if (t < 128) loc[t] = 0;
  __syncthreads();
  int i = blockIdx.x * 256 + t;
  if (i < N_NODES) atomicAdd(&loc[batch[i]], 1);
  __syncthreads();
  if (t < 128) bpart[blockIdx.x * 128 + t] = loc[t];
}

__global__ __launch_bounds__(128) void k_bscan(const int* __restrict__ bpart, int* __restrict__ gptr){
  int t = threadIdx.x;
  int v = 0;
  for (int p = 0; p < 391; p++) v += bpart[p * 128 + t];
  __shared__ int s[128];
  s[t] = v; __syncthreads();
  for (int o = 1; o < 128; o <<= 1){
    int x = (t >= o) ? s[t - o] : 0;
    __syncthreads(); s[t] += x; __syncthreads();
  }
  gptr[t + 1] = s[t];
  if (t == 0) gptr[0] = 0;
}

// ---------------- x (f32) -> bf16 staging + column stats (fused, one pass) ----------------
__global__ __launch_bounds__(256) void k_cvtstats(const float* __restrict__ x, u32* __restrict__ dst,
                                                  float* __restrict__ sums_out){
  __shared__ float R[1024];
  int t = threadIdx.x;
  float s0 = 0.f, q0 = 0.f, s1 = 0.f, q1 = 0.f;
  size_t base = (size_t)blockIdx.x * 4096 + t;
  #pragma unroll
  for (int it = 0; it < 16; it++){
    size_t idx = base + (size_t)it * 256;
    if (idx < (size_t)N_NODES * 64){
      float2 v = ((const float2*)x)[idx];
      dst[idx] = (u32)f2bf(v.x) | ((u32)f2bf(v.y) << 16);
      s0 += v.x; q0 += v.x * v.x; s1 += v.y; q1 += v.y * v.y;
    }
  }
  R[t] = s0; R[256 + t] = q0; R[512 + t] = s1; R[768 + t] = q1;
  __syncthreads();
  if (t < 64){
    float S0 = 0.f, Q0 = 0.f, S1 = 0.f, Q1 = 0.f;
    #pragma unroll
    for (int g = 0; g < 4; g++){
      S0 += R[g * 64 + t];       Q0 += R[256 + g * 64 + t];
      S1 += R[512 + g * 64 + t]; Q1 += R[768 + g * 64 + t];
    }
    float* so = sums_out + (blockIdx.x & (NSLOT - 1)) * 256;
    atomicAdd(&so[2 * t], S0);
    atomicAdd(&so[2 * t + 1], S1);
    atomicAdd(&so[128 + 2 * t], Q0);
    atomicAdd(&so[128 + 2 * t + 1], Q1);
  }
}

// ---------------- per-layer fold: BN into fragment-ordered hi/lo bf16 W (GLOBAL) + rank-one ----------------
__global__ __launch_bounds__(1024) void k_fold(const float* __restrict__ sums,
    const float* __restrict__ bw, const float* __restrict__ bb,
    const float* __restrict__ W, const float* __restrict__ bias,
    u16* __restrict__ Wh, u16* __restrict__ Wl, float* __restrict__ rb){
  __shared__ float scl[128], shf[128], rbs[128], stot[256];
  int t = threadIdx.x;
  if (t < 256){
    float s = 0.f;
    #pragma unroll 4
    for (int sl = 0; sl < NSLOT; sl++) s += sums[sl * 256 + t];
    stot[t] = s;
  } else if (t < 384) rbs[t - 256] = 0.f;
  __syncthreads();
  if (t < 128){
    float mu  = stot[t] * (1.f / N_NODES);
    float var = stot[128 + t] * (1.f / N_NODES) - mu * mu;
    float sc  = bw[t] * rsqrtf(var + EPS);
    scl[t] = sc; shf[t] = bb[t] - mu * sc;
  }
  __syncthreads();
  #pragma unroll
  for (int r = 0; r < 2; r++){
    int idx = r * 1024 + t;                // 2048 frag slots-lanes
    int lane_ = idx & 63, sl = idx >> 6;   // sl = nt*4 + ks
    int nt_ = sl >> 2, ks_ = sl & 3;
    int n_ = nt_ * 16 + (lane_ & 15);
    int kb = ks_ * 32 + (lane_ >> 4) * 8;
    float rp = 0.f;
    u16 hi8[8], lo8[8];
    #pragma unroll
    for (int j = 0; j < 8; j++){
      float wv = W[(kb + j) * 128 + n_];
      rp += shf[kb + j] * wv;
      float xv = scl[kb + j] * wv;
      u16 hh = f2bf(xv);
      hi8[j] = hh; lo8[j] = f2bf(xv - bf2f(hh));
    }
    uint4 ph, pl;
    ph.x = (u32)hi8[0] | ((u32)hi8[1] << 16); ph.y = (u32)hi8[2] | ((u32)hi8[3] << 16);
    ph.z = (u32)hi8[4] | ((u32)hi8[5] << 16); ph.w = (u32)hi8[6] | ((u32)hi8[7] << 16);
    pl.x = (u32)lo8[0] | ((u32)lo8[1] << 16); pl.y = (u32)lo8[2] | ((u32)lo8[3] << 16);
    pl.z = (u32)lo8[4] | ((u32)lo8[5] << 16); pl.w = (u32)lo8[6] | ((u32)lo8[7] << 16);
    *(uint4*)&Wh[idx * 8] = ph;
    *(uint4*)&Wl[idx * 8] = pl;
    atomicAdd(&rbs[n_], rp);
  }
  __syncthreads();
  if (t < 128){
    rb[t] = rbs[t];
    rb[128 + t] = bias[t];
  }
}

// ---------------- epilogue macro: bias + rank-one + relu + store + slotted stats ----------------
#define CONV_EPILOGUE(RB, HOUT, SOUT)                                          \
  __syncthreads();                                                             \
  sred[t] = 0.f;                                                               \
  __syncthreads();                                                             \
  _Pragma("unroll")                                                            \
  for (int nt = 0; nt < 8; nt++){                                              \
    int colc = nt * 16 + m;                                                    \
    float rv = RB[colc], bv = RB[128 + colc];                                  \
    float s = 0.f, qq = 0.f;                                                   \
    _Pragma("unroll")                                                          \
    for (int r = 0; r < 4; r++){                                               \
      int rown = row0 + q * 4 + r;                                             \
      float v = C[nt][r] + srow[rown] * rv + bv;                               \
      v = fmaxf(v, 0.f);                                                       \
      u16 sv = f2bf(v);                                                        \
      HOUT[(size_t)rown * 128 + colc] = sv;                                    \
      if (rown < N_NODES){ float vv = bf2f(sv); s += vv; qq += vv * vv; }      \
    }                                                                          \
    atomicAdd(&sred[colc], s);                                                 \
    atomicAdd(&sred[128 + colc], qq);                                          \
  }                                                                            \
  __syncthreads();                                                             \
  atomicAdd(&SOUT[(blockIdx.x & (NSLOT - 1)) * 256 + t], sred[t]);

// ---------------- gather macro: S@h rows into A-fragment registers acc[4][8] ----------------
#define GATHER_PHASE()                                                         \
  _Pragma("unroll")                                                            \
  for (int ks = 0; ks < 4; ks++)                                               \
    _Pragma("unroll")                                                          \
    for (int j = 0; j < 8; j++) acc[ks][j] = 0.f;                              \
  if (i < N_NODES){                                                            \
    const u16* hq = h + q * 8;                                                 \
    float di = dinv[i], sw = di * di;                                          \
    _Pragma("unroll")                                                          \
    for (int ks = 0; ks < 4; ks++){                                            \
      uint4 v = *(const uint4*)(hq + (size_t)i * 128 + ks * 32);               \
      acc[ks][0] = sw * __uint_as_float(v.x << 16); acc[ks][1] = sw * __uint_as_float(v.x & 0xffff0000u); \
      acc[ks][2] = sw * __uint_as_float(v.y << 16); acc[ks][3] = sw * __uint_as_float(v.y & 0xffff0000u); \
      acc[ks][4] = sw * __uint_as_float(v.z << 16); acc[ks][5] = sw * __uint_as_float(v.z & 0xffff0000u); \
      acc[ks][6] = sw * __uint_as_float(v.w << 16); acc[ks][7] = sw * __uint_as_float(v.w & 0xffff0000u); \
    }                                                                          \
    int b = ptrA[i], e = ptrA[i + 1];                                          \
    int k = b;                                                                 \
    for (; k + 2 <= e; k += 2){                                                \
      int2 a0 = adj[k], a1 = adj[k + 1];                                       \
      const u16* r0p = hq + (size_t)a0.x * 128;                                \
      const u16* r1p = hq + (size_t)a1.x * 128;                                \
      uint4 u0 = *(const uint4*)(r0p);                                         \
      uint4 u1 = *(const uint4*)(r0p + 32);                                    \
      uint4 u2 = *(const uint4*)(r0p + 64);                                    \
      uint4 u3 = *(const uint4*)(r0p + 96);                                    \
      uint4 w0 = *(const uint4*)(r1p);                                         \
      uint4 w1 = *(const uint4*)(r1p + 32);                                    \
      uint4 w2 = *(const uint4*)(r1p + 64);                                    \
      uint4 w3 = *(const uint4*)(r1p + 96);                                    \
      float f0 = __int_as_float(a0.y), f1 = __int_as_float(a1.y);              \
      FMA_KS(0, u0, f0) FMA_KS(1, u1, f0) FMA_KS(2, u2, f0) FMA_KS(3, u3, f0)  \
      FMA_KS(0, w0, f1) FMA_KS(1, w1, f1) FMA_KS(2, w2, f1) FMA_KS(3, w3, f1)  \
    }                                                                          \
    for (; k < e; k++){                                                        \
      int2 a0 = adj[k];                                                        \
      const u16* r0p = hq + (size_t)a0.x * 128;                                \
      uint4 u0 = *(const uint4*)(r0p);                                         \
      uint4 u1 = *(const uint4*)(r0p + 32);                                    \
      uint4 u2 = *(const uint4*)(r0p + 64);                                    \
      uint4 u3 = *(const uint4*)(r0p + 96);                                    \
      float f0 = __int_as_float(a0.y);                                         \
      FMA_KS(0, u0, f0) FMA_KS(1, u1, f0) FMA_KS(2, u2, f0) FMA_KS(3, u3, f0)  \
    }                                                                          \
  }

#define FMA_KS(KS, V, WT) \
  acc[KS][0] += (WT) * __uint_as_float((V).x << 16); acc[KS][1] += (WT) * __uint_as_float((V).x & 0xffff0000u); \
  acc[KS][2] += (WT) * __uint_as_float((V).y << 16); acc[KS][3] += (WT) * __uint_as_float((V).y & 0xffff0000u); \
  acc[KS][4] += (WT) * __uint_as_float((V).z << 16); acc[KS][5] += (WT) * __uint_as_float((V).z & 0xffff0000u); \
  acc[KS][6] += (WT) * __uint_as_float((V).w << 16); acc[KS][7] += (WT) * __uint_as_float((V).w & 0xffff0000u);

#define MFMA_3PASS(WH, WL_)                                                    \
  _Pragma("unroll")                                                            \
  for (int ks = 0; ks < 4; ks++){                                              \
    _Pragma("unroll")                                                          \
    for (int nt = 0; nt < 8; nt++){                                            \
      bf16x8 bh = ((const bf16x8*)WH)[(nt * 4 + ks) * 64 + lane];              \
      bf16x8 bl = ((const bf16x8*)WL_)[(nt * 4 + ks) * 64 + lane];             \
      C[nt] = __builtin_amdgcn_mfma_f32_16x16x32_bf16(AH[ks], bh, C[nt], 0, 0, 0); \
      C[nt] = __builtin_amdgcn_mfma_f32_16x16x32_bf16(AL[ks], bh, C[nt], 0, 0, 0); \
      C[nt] = __builtin_amdgcn_mfma_f32_16x16x32_bf16(AH[ks], bl, C[nt], 0, 0, 0); \
    }                                                                          \
  }

// ---------------- fused conv: gather(S@h) into regs + MFMA (b-frags from global) + stats ----------------
__global__ __launch_bounds__(256, 4) void k_conv(
    const u16* __restrict__ h, const int* __restrict__ ptrA, const int2* __restrict__ adj,
    const float* __restrict__ dinv, const float* __restrict__ srow,
    const u16* __restrict__ Wh, const u16* __restrict__ Wl, const float* __restrict__ rb,
    u16* __restrict__ hout, float* __restrict__ sums_out){
  __shared__ float sred[256];
  int t = threadIdx.x;
  int wave = t >> 6, lane = t & 63, m = lane & 15, q = lane >> 4;
  int row0 = blockIdx.x * 64 + wave * 16;
  int i = row0 + m;
  float acc[4][8];
  GATHER_PHASE()
  bf16x8 AH[4], AL[4];
  #pragma unroll
  for (int ks = 0; ks < 4; ks++)
    #pragma unroll
    for (int j = 0; j < 8; j++){
      u16 hh = f2bf(acc[ks][j]);
      AH[ks][j] = (short)hh;
      AL[ks][j] = (short)f2bf(acc[ks][j] - bf2f(hh));
    }
  f32x4 C[8];
  #pragma unroll
  for (int nt = 0; nt < 8; nt++) C[nt] = f32x4{0.f, 0.f, 0.f, 0.f};
  MFMA_3PASS(Wh, Wl)
  CONV_EPILOGUE(rb, hout, sums_out)
}

// ---------------- dual conv: one gather, two folded-W phases (a2 & c2 share S@a1) ----------------
__global__ __launch_bounds__(256, 4) void k_dualconv(
    const u16* __restrict__ h, const int* __restrict__ ptrA, const int2* __restrict__ adj,
    const float* __restrict__ dinv, const float* __restrict__ srow,
    const u16* __restrict__ Wh1, const u16* __restrict__ Wl1, const float* __restrict__ rb1,
    u16* __restrict__ hout1, float* __restrict__ sums1,
    const u16* __restrict__ Wh2, const u16* __restrict__ Wl2, const float* __restrict__ rb2,
    u16* __restrict__ hout2, float* __restrict__ sums2){
  __shared__ float sred[256];
  int t = threadIdx.x;
  int wave = t >> 6, lane = t & 63, m = lane & 15, q = lane >> 4;
  int row0 = blockIdx.x * 64 + wave * 16;
  int i = row0 + m;
  float acc[4][8];
  GATHER_PHASE()
  bf16x8 AH[4], AL[4];
  #pragma unroll
  for (int ks = 0; ks < 4; ks++)
    #pragma unroll
    for (int j = 0; j < 8; j++){
      u16 hh = f2bf(acc[ks][j]);
      AH[ks][j] = (short)hh;
      AL[ks][j] = (short)f2bf(acc[ks][j] - bf2f(hh));
    }
  f32x4 C[8];
  #pragma unroll
  for (int nt = 0; nt < 8; nt++) C[nt] = f32x4{0.f, 0.f, 0.f, 0.f};
  MFMA_3PASS(Wh1, Wl1)
  CONV_EPILOGUE(rb1, hout1, sums1)
  #pragma unroll
  for (int nt = 0; nt < 8; nt++) C[nt] = f32x4{0.f, 0.f, 0.f, 0.f};
  MFMA_3PASS(Wh2, Wl2)
  CONV_EPILOGUE(rb2, hout2, sums2)
}

// ---------------- branch-4 elementwise: out = relu(bn(h)); slotted stats ----------------
__global__ __launch_bounds__(256) void k_normrelu(const u16* __restrict__ h, const float* __restrict__ sums,
    const float* __restrict__ bw, const float* __restrict__ bb, u16* __restrict__ o,
    float* __restrict__ sums_out){
  __shared__ float scl[128], shf[128], R[1024], stot[256];
  int t = threadIdx.x;
  {
    float s = 0.f;
    #pragma unroll 4
    for (int sl = 0; sl < NSLOT; sl++) s += sums[sl * 256 + t];
    stot[t] = s;
  }
  __syncthreads();
  if (t < 128){
    float mu  = stot[t] * (1.f / N_NODES);
    float var = stot[128 + t] * (1.f / N_NODES) - mu * mu;
    float sc  = bw[t] * rsqrtf(var + EPS);
    scl[t] = sc; shf[t] = bb[t] - mu * sc;
  }
  __syncthreads();
  int c0 = (t & 63) * 2;
  float sc0 = scl[c0], sh0 = shf[c0], sc1 = scl[c0 + 1], sh1 = shf[c0 + 1];
  float s0 = 0.f, q0 = 0.f, s1 = 0.f, q1 = 0.f;
  size_t base = (size_t)blockIdx.x * 4096 + t;
  #pragma unroll
  for (int it = 0; it < 16; it++){
    size_t idx = base + (size_t)it * 256;
    if (idx < (size_t)N_NODES * 64){
      u32 v = ((const u32*)h)[idx];
      float x0 = fmaxf(bf2f(v & 0xffffu) * sc0 + sh0, 0.f);
      float x1 = fmaxf(bf2f(v >> 16) * sc1 + sh1, 0.f);
      u16 r0 = f2bf(x0), r1 = f2bf(x1);
      ((u32*)o)[idx] = (u32)r0 | ((u32)r1 << 16);
      float y0 = bf2f(r0), y1 = bf2f(r1);
      s0 += y0; q0 += y0 * y0; s1 += y1; q1 += y1 * y1;
    }
  }
  R[t] = s0; R[256 + t] = q0; R[512 + t] = s1; R[768 + t] = q1;
  __syncthreads();
  if (t < 64){
    float S0 = 0.f, Q0 = 0.f, S1 = 0.f, Q1 = 0.f;
    #pragma unroll
    for (int g = 0; g < 4; g++){
      S0 += R[g * 64 + t];       Q0 += R[256 + g * 64 + t];
      S1 += R[512 + g * 64 + t]; Q1 += R[768 + g * 64 + t];
    }
    float* so = sums_out + (blockIdx.x & (NSLOT - 1)) * 256;
    atomicAdd(&so[2 * t], S0);
    atomicAdd(&so[2 * t + 1], S1);
    atomicAdd(&so[128 + 2 * t], Q0);
    atomicAdd(&so[128 + 2 * t + 1], Q1);
  }
}

// ---------------- global_add_pool ----------------
__global__ __launch_bounds__(128) void k_pool(const u16* __restrict__ h, const int* __restrict__ gptr,
                                              float* __restrict__ gdst){
  int g = blockIdx.x >> 3, s = blockIdx.x & 7, t = threadIdx.x;
  int b = gptr[g], e = gptr[g + 1];
  int len = e - b, per = (len + 7) >> 3;
  int r0 = b + s * per, r1 = min(r0 + per, e);
  float acc = 0.f;
  for (int r = r0; r < r1; r++) acc += bf2f(h[(size_t)r * 128 + t]);
  atomicAdd(&gdst[g * 128 + t], acc);
}

// ---------------- head: 8x8 register-tile FC, shfl-reduced classifier ----------------
__global__ __launch_bounds__(256) void k_head(const float* __restrict__ gbuf,
    const float* __restrict__ fcw, const float* __restrict__ fcb,
    const float* __restrict__ Wfc, const float* __restrict__ bfc,
    const float* __restrict__ bhw, const float* __restrict__ bhb,
    const float* __restrict__ Wcl, const float* __restrict__ bcl,
    float* __restrict__ out){
  __shared__ float GS[128 * 65];           // Gbn k-half staging (33 KB)
  __shared__ float ls[256], lq[256];
  __shared__ float scl[128], shf[128], scl2[128], shf2[128];
  __shared__ float sumT[128], sumQ[128];
  __shared__ float WclT[1280], Lrow[1280];
  int t = threadIdx.x, br = blockIdx.x;
  int slot = (br == 1) ? 1 : (br == 3 ? 3 : 0);   // branch3 == branch1 (slot 0)
  const float* G = gbuf + slot * 16384;
  { // stats of G
    int col = t & 127, hf2 = t >> 7;
    float s = 0.f, q = 0.f;
    for (int g = hf2 * 64; g < hf2 * 64 + 64; g++){ float v = G[g * 128 + col]; s += v; q += v * v; }
    ls[t] = s; lq[t] = q;
  }
  for (int idx = t; idx < 1280; idx += 256){     // WclT[cc][c] = Wcl[c][cc]
    int cc = idx >> 7, c = idx & 127;
    WclT[idx] = Wcl[c * 10 + cc];
  }
  if (t < 128){ sumT[t] = 0.f; sumQ[t] = 0.f; }
  __syncthreads();
  if (t < 128){
    float s = ls[t] + ls[t + 128], q = lq[t] + lq[t + 128];
    float mu = s * (1.f / 128), var = q * (1.f / 128) - mu * mu;
    float sc = fcw[t] * rsqrtf(var + EPS);
    scl[t] = sc; shf[t] = fcb[t] - mu * sc;
  }
  __syncthreads();
  int tr = t >> 4, tc = t & 15, r0 = tr * 8, c0 = tc * 8;
  float acc[8][8];
  #pragma unroll
  for (int a = 0; a < 8; a++)
    #pragma unroll
    for (int b = 0; b < 8; b++) acc[a][b] = 0.f;
  for (int kh = 0; kh < 2; kh++){
    for (int idx = t; idx < 8192; idx += 256){
      int r = idx >> 6, kk = idx & 63, f = kh * 64 + kk;
      GS[r * 65 + kk] = G[r * 128 + f] * scl[f] + shf[f];
    }
    __syncthreads();
    #pragma unroll 2
    for (int k = 0; k < 64; k++){
      float a[8];
      #pragma unroll
      for (int ri = 0; ri < 8; ri++) a[ri] = GS[(r0 + ri) * 65 + k];
      float4 b0 = *(const float4*)&Wfc[(kh * 64 + k) * 128 + c0];
      float4 b1 = *(const float4*)&Wfc[(kh * 64 + k) * 128 + c0 + 4];
      float bb[8] = {b0.x, b0.y, b0.z, b0.w, b1.x, b1.y, b1.z, b1.w};
      #pragma unroll
      for (int ri = 0; ri < 8; ri++)
        #pragma unroll
        for (int ci = 0; ci < 8; ci++) acc[ri][ci] += a[ri] * bb[ci];
    }
    __syncthreads();
  }
  // bias + relu + column stats for bn_hidden
  #pragma unroll
  for (int ci = 0; ci < 8; ci++){
    float bb = bfc[c0 + ci];
    float s = 0.f, q = 0.f;
    #pragma unroll
    for (int ri = 0; ri < 8; ri++){
      float v = fmaxf(acc[ri][ci] + bb, 0.f);
      acc[ri][ci] = v; s += v; q += v * v;
    }
    atomicAdd(&sumT[c0 + ci], s);
    atomicAdd(&sumQ[c0 + ci], q);
  }
  __syncthreads();
  if (t < 128){
    float mu = sumT[t] * (1.f / 128), var = sumQ[t] * (1.f / 128) - mu * mu;
    float sc = bhw[t] * rsqrtf(var + EPS);
    scl2[t] = sc; shf2[t] = bhb[t] - mu * sc;
  }
  __syncthreads();
  #pragma unroll
  for (int ci = 0; ci < 8; ci++){
    float sc = scl2[c0 + ci], sh = shf2[c0 + ci];
    #pragma unroll
    for (int ri = 0; ri < 8; ri++) acc[ri][ci] = acc[ri][ci] * sc + sh;
  }
  // classifier: per-thread partials over its 8 cols, shfl-reduce over tc
  #pragma unroll
  for (int ri = 0; ri < 8; ri++){
    float pl[10];
    #pragma unroll
    for (int cc = 0; cc < 10; cc++) pl[cc] = 0.f;
    #pragma unroll
    for (int ci = 0; ci < 8; ci++){
      float v = acc[ri][ci];
      #pragma unroll
      for (int cc = 0; cc < 10; cc++) pl[cc] += v * WclT[cc * 128 + c0 + ci];
    }
    #pragma unroll
    for (int msk = 1; msk < 16; msk <<= 1)
      #pragma unroll
      for (int cc = 0; cc < 10; cc++) pl[cc] += __shfl_xor(pl[cc], msk, 64);
    if (tc == 0)
      #pragma unroll
      for (int cc = 0; cc < 10; cc++) Lrow[(r0 + ri) * 10 + cc] = pl[cc];
  }
  __syncthreads();
  if (t < 128){
    float l[10];
    #pragma unroll
    for (int cc = 0; cc < 10; cc++) l[cc] = Lrow[t * 10 + cc] + bcl[cc];
    float m = l[0];
    #pragma unroll
    for (int cc = 1; cc < 10; cc++) m = fmaxf(m, l[cc]);
    float se = 0.f;
    #pragma unroll
    for (int cc = 0; cc < 10; cc++) se += expf(l[cc] - m);
    float lse = m + logf(se);
    #pragma unroll
    for (int cc = 0; cc < 10; cc++) out[br * 1280 + t * 10 + cc] = l[cc] - lse;
  }
}

extern "C" void kernel_launch(void* const* d_in, const int* in_sizes, int n_in,
                              void* d_out, int out_size, void* d_ws, size_t ws_size,
                              hipStream_t stream){
  const float* x    = (const float*)d_in[0];
  const int*  ei    = (const int*)d_in[1];      // [2,E]: rows then cols
  const int*  batch = (const int*)d_in[2];
  const float* ew   = (const float*)d_in[3];
  const float* bnfw = (const float*)d_in[4];
  const float* bnfb = (const float*)d_in[5];
  const float* cfW  = (const float*)d_in[6];
  const float* cfb  = (const float*)d_in[7];
  const float* bnsw = (const float*)d_in[8];
  const float* bnsb = (const float*)d_in[9];
  const float* cvW  = (const float*)d_in[10];
  const float* cvb  = (const float*)d_in[11];
  const float* fcw  = (const float*)d_in[12];
  const float* fcb  = (const float*)d_in[13];
  const float* Wfc  = (const float*)d_in[14];
  const float* bfc  = (const float*)d_in[15];
  const float* bhw  = (const float*)d_in[16];
  const float* bhb  = (const float*)d_in[17];
  const float* Wcl  = (const float*)d_in[18];
  const float* bcl  = (const float*)d_in[19];
  float* out = (float*)d_out;

  char* p = (char*)d_ws;
  auto carve = [&](size_t bytes)->void*{ void* r = (void*)p; p += (bytes + 255) & ~(size_t)255; return r; };
  float* deg  = (float*)carve((size_t)NPAD * 4);
  float* dinv = (float*)carve((size_t)NPAD * 4);
  float* srow = (float*)carve((size_t)NPAD * 4);
  int*   cnt  = (int*)carve((size_t)NPAD * 4);
  int*   fill = (int*)carve((size_t)NPAD * 4);
  int*   ptrA = (int*)carve((size_t)(NPAD + 1) * 4);
  int*   bpart= (int*)carve((size_t)391 * 128 * 4);
  int*   csum = (int*)carve(512);
  int*   coff = (int*)carve(512);
  int*   gptr = (int*)carve(1024);
  float* S    = (float*)carve((size_t)13 * NSLOT * 1024);   // 13 steps x NSLOT x 256 floats
  float* gbuf = (float*)carve(4 * 128 * 128 * 4);
  u16*   F0h  = (u16*)carve(32768);  u16* F0l = (u16*)carve(32768);  float* F0r = (float*)carve(1024);
  u16*   F1h  = (u16*)carve(32768);  u16* F1l = (u16*)carve(32768);  float* F1r = (float*)carve(1024);
  u16*   F2h  = (u16*)carve(32768);  u16* F2l = (u16*)carve(32768);  float* F2r = (float*)carve(1024);
  u16*   B0   = (u16*)carve((size_t)NPAD * 256);
  u16*   B1   = (u16*)carve((size_t)NPAD * 256);
  u16*   B2   = (u16*)carve((size_t)NPAD * 256);
  u16*   B3   = (u16*)carve((size_t)NPAD * 256);
  int2*  adj  = (int2*)carve((size_t)NEDGE * 8);
  u16*   Xb   = B3;   // bf16 x staging; B3's first real write (d2) is after L0 conv consumes Xb
  auto Sb = [&](int i){ return S + (size_t)i * NSLOT * 256; };

  (void)hipMemsetAsync(S, 0, (size_t)13 * NSLOT * 1024, stream);

  // preprocessing: degrees, norms, CSR, group offsets
  k_init<<<392, 256, 0, stream>>>(deg, cnt, fill, gbuf);
  k_deg<<<3125, 256, 0, stream>>>(ei + NEDGE, ew, deg, cnt);
  k_dinv<<<391, 256, 0, stream>>>(deg, dinv, srow);
  k_chunksum<<<98, 256, 0, stream>>>(cnt, csum);
  k_chunkscan<<<1, 128, 0, stream>>>(csum, coff, ptrA);
  k_scan2<<<98, 256, 0, stream>>>(cnt, coff, ptrA);
  k_fill<<<3125, 256, 0, stream>>>(ei, ei + NEDGE, ew, dinv, ptrA, fill, adj, srow);
  k_bhist<<<391, 256, 0, stream>>>(batch, bpart);
  k_bscan<<<1, 128, 0, stream>>>(bpart, gptr);
  k_cvtstats<<<NBLK, 256, 0, stream>>>(x, (u32*)Xb, Sb(0));

  auto fold = [&](const float* Sin, const float* bw, const float* bb,
                  const float* W, const float* bias, u16* Fh, u16* Fl, float* Fr){
    k_fold<<<1, 1024, 0, stream>>>(Sin, bw, bb, W, bias, Fh, Fl, Fr);
  };
  auto conv = [&](const u16* hin, const u16* Fh, const u16* Fl, const float* Fr,
                  u16* hout, float* Sout){
    k_conv<<<NBLK, 256, 0, stream>>>(hin, ptrA, adj, dinv, srow, Fh, Fl, Fr, hout, Sout);
  };

  // L0: h_init = relu(conv(bn_feat(x)))
  fold(Sb(0), bnfw, bnfb, cfW, cfb, F0h, F0l, F0r);
  conv(Xb, F0h, F0l, F0r, B0, Sb(1));                                         // B0 = h_init
  // a1 = step(h_init, bn0/W0)  (== branch2 c1)
  fold(Sb(1), bnsw, bnsb, cvW, cvb, F1h, F1l, F1r);
  conv(B0, F1h, F1l, F1r, B1, Sb(2));                                         // B1 = a1
  // branch 4: d1,d2,d3 (d1 uses stats(h_init))
  k_normrelu<<<NBLK, 256, 0, stream>>>(B0, Sb(1), bnsw,       bnsb,       B2, Sb(3));   // d1 -> B2
  k_normrelu<<<NBLK, 256, 0, stream>>>(B2, Sb(3), bnsw + 128, bnsb + 128, B3, Sb(4));   // d2 -> B3
  k_normrelu<<<NBLK, 256, 0, stream>>>(B3, Sb(4), bnsw + 256, bnsb + 256, B2, Sb(12));  // d3 -> B2
  k_pool<<<1024, 128, 0, stream>>>(B2, gptr, gbuf + 3 * 16384);
  // dual: a2 = step(a1, bn1/W1), c2 = step(a1, bn0/W0) — one gather of S@a1
  fold(Sb(2), bnsw + 128, bnsb + 128, cvW + 16384, cvb + 128, F0h, F0l, F0r);
  fold(Sb(2), bnsw,       bnsb,       cvW,         cvb,       F1h, F1l, F1r);
  k_dualconv<<<NBLK, 256, 0, stream>>>(B1, ptrA, adj, dinv, srow,
      F0h, F0l, F0r, B3, Sb(5),       // a2 -> B3
      F1h, F1l, F1r, B2, Sb(6));      // c2 -> B2
  // a3 = step(a2, bn2/W2) -> branches 1 & 3
  fold(Sb(5), bnsw + 256, bnsb + 256, cvW + 32768, cvb + 256, F2h, F2l, F2r);
  conv(B3, F2h, F2l, F2r, B0, Sb(10));                                        // a3 -> B0
  k_pool<<<1024, 128, 0, stream>>>(B0, gptr, gbuf);
  // c3 = step(c2, bn1/W1)
  fold(Sb(6), bnsw + 128, bnsb + 128, cvW + 16384, cvb + 128, F0h, F0l, F0r);
  conv(B2, F0h, F0l, F0r, B1, Sb(7));                                         // c3 -> B1
  // c4 = step(c3, bn1/W1)
  fold(Sb(7), bnsw + 128, bnsb + 128, cvW + 16384, cvb + 128, F1h, F1l, F1r);
  conv(B1, F1h, F1l, F1r, B2, Sb(8));                                         // c4 -> B2
  // c5 = step(c4, bn2/W2)
  fold(Sb(8), bnsw + 256, bnsb + 256, cvW + 32768, cvb + 256, F2h, F2l, F2r);
  conv(B2, F2h, F2l, F2r, B1, Sb(9));                                         // c5 -> B1
  // c6 = step(c5, bn2/W2) -> branch 2
  fold(Sb(9), bnsw + 256, bnsb + 256, cvW + 32768, cvb + 256, F0h, F0l, F0r);
  conv(B1, F0h, F0l, F0r, B3, Sb(11));                                        // c6 -> B3
  k_pool<<<1024, 128, 0, stream>>>(B3, gptr, gbuf + 16384);

  k_head<<<4, 256, 0, stream>>>(gbuf, fcw, fcb, Wfc, bfc, bhw, bhb, Wcl, bcl, out);
}